// Round 1
// baseline (1136.179 us; speedup 1.0000x reference)
//
#include <hip/hip_runtime.h>
#include <hip/hip_bf16.h>
#include <float.h>

// ---------------------------------------------------------------------------
// GlobalFeatureGAT: feature-build+LN -> GAT(4 heads,128) -> ELU -> GAT(1,128)
// -> ELU -> per-graph max pool -> MLP(128->64->5).  All fp32.
// N=50000, E=500000 (+N self loops), G=64, IN_DIM=256, C=128, H1=4.
// ---------------------------------------------------------------------------

#define LEAKY(e) ((e) > 0.f ? (e) : 0.2f * (e))

// ---------------------- feature build + layernorm --------------------------
__global__ __launch_bounds__(256) void feats_kernel(
    const float* __restrict__ xs, const int* __restrict__ xo,
    const int* __restrict__ xsrc, const int* __restrict__ xsk,
    const int* __restrict__ xst, const int* __restrict__ xp,
    const float* __restrict__ eo, const float* __restrict__ es,
    const float* __restrict__ ek, const float* __restrict__ et,
    const float* __restrict__ ep, const float* __restrict__ lng,
    const float* __restrict__ lnb, float* __restrict__ feats, int n) {
  int i = blockIdx.x;
  int t = threadIdx.x;
  __shared__ int sidx[48];
  __shared__ float red[4];

  if (t < 48) {
    if (t < 16)      sidx[t] = xo[i * 16 + t];
    else if (t < 24) sidx[t] = xsrc[i * 8 + (t - 16)];
    else if (t < 32) sidx[t] = xsk[i * 8 + (t - 24)];
    else if (t < 40) sidx[t] = xst[i * 8 + (t - 32)];
    else             sidx[t] = xp[i * 8 + (t - 40)];
  }
  __syncthreads();

  float v;
  if (t < 96) {
    v = xs[(size_t)i * 96 + t];
  } else {
    int j = t - 96;
    int grp = j >> 5;
    int d = j & 31;
    const float* tab;
    int L, off;
    switch (grp) {
      case 0: tab = eo; L = 16; off = 0; break;
      case 1: tab = es; L = 8;  off = 16; break;
      case 2: tab = ek; L = 8;  off = 24; break;
      case 3: tab = et; L = 8;  off = 32; break;
      default: tab = ep; L = 8; off = 40; break;
    }
    float s = 0.f, c = 0.f;
    for (int l = 0; l < L; l++) {
      int id = sidx[off + l];
      if (id != 0) { s += tab[(size_t)id * 32 + d]; c += 1.f; }
    }
    v = s / (c + 1e-9f);
  }

  // block-wide mean
  float ws = v;
  for (int o = 32; o; o >>= 1) ws += __shfl_xor(ws, o);
  if ((t & 63) == 0) red[t >> 6] = ws;
  __syncthreads();
  float mu = (red[0] + red[1] + red[2] + red[3]) * (1.f / 256.f);
  __syncthreads();

  float diff = v - mu;
  float wq = diff * diff;
  for (int o = 32; o; o >>= 1) wq += __shfl_xor(wq, o);
  if ((t & 63) == 0) red[t >> 6] = wq;
  __syncthreads();
  float var = (red[0] + red[1] + red[2] + red[3]) * (1.f / 256.f);

  feats[(size_t)i * 256 + t] = diff * rsqrtf(var + 1e-5f) * lng[t] + lnb[t];
}

// ---------------------- generic fp32 tiled GEMM (64x64) --------------------
__global__ __launch_bounds__(256) void gemm_kernel(
    const float* __restrict__ A, const float* __restrict__ B,
    float* __restrict__ C, int M, int K, int Nn) {
  __shared__ float As[16][68];
  __shared__ float Bs[16][68];
  int n0 = blockIdx.x * 64;
  int m0 = blockIdx.y * 64;
  int tid = threadIdx.x;
  int tx = tid & 15, ty = tid >> 4;
  float acc[4][4] = {};

  for (int k0 = 0; k0 < K; k0 += 16) {
    int ka = tid & 15, ma = tid >> 4;
#pragma unroll
    for (int mm = ma; mm < 64; mm += 16) {
      int row = m0 + mm;
      As[ka][mm] = (row < M) ? A[(size_t)row * K + k0 + ka] : 0.f;
    }
    int nb = tid & 63, kb = tid >> 6;
#pragma unroll
    for (int kk = kb; kk < 16; kk += 4) {
      Bs[kk][nb] = B[(size_t)(k0 + kk) * Nn + n0 + nb];
    }
    __syncthreads();
#pragma unroll
    for (int k = 0; k < 16; k++) {
      float4 a = *(const float4*)&As[k][ty * 4];
      float4 b = *(const float4*)&Bs[k][tx * 4];
      acc[0][0] += a.x * b.x; acc[0][1] += a.x * b.y; acc[0][2] += a.x * b.z; acc[0][3] += a.x * b.w;
      acc[1][0] += a.y * b.x; acc[1][1] += a.y * b.y; acc[1][2] += a.y * b.z; acc[1][3] += a.y * b.w;
      acc[2][0] += a.z * b.x; acc[2][1] += a.z * b.y; acc[2][2] += a.z * b.z; acc[2][3] += a.z * b.w;
      acc[3][0] += a.w * b.x; acc[3][1] += a.w * b.y; acc[3][2] += a.w * b.z; acc[3][3] += a.w * b.w;
    }
    __syncthreads();
  }
#pragma unroll
  for (int i = 0; i < 4; i++) {
    int row = m0 + ty * 4 + i;
    if (row < M) {
#pragma unroll
      for (int j = 0; j < 4; j++)
        C[(size_t)row * Nn + n0 + tx * 4 + j] = acc[i][j];
    }
  }
}

// ---------------------- attention score dots --------------------------------
__global__ __launch_bounds__(256) void att1_kernel(
    const float* __restrict__ h1, const float* __restrict__ as,
    const float* __restrict__ ad, float* __restrict__ osrc,
    float* __restrict__ odst, int n) {
  int node = blockIdx.x * 4 + (threadIdx.x >> 6);
  if (node >= n) return;
  int l = threadIdx.x & 63;
  int hh = l >> 4;
  int cb = (l & 15) * 8;
  const float* hp = h1 + (size_t)node * 512 + l * 8;
  const float* ap = as + hh * 128 + cb;
  const float* dp = ad + hh * 128 + cb;
  float ssum = 0.f, dsum = 0.f;
#pragma unroll
  for (int j = 0; j < 8; j++) {
    float hv = hp[j];
    ssum += hv * ap[j];
    dsum += hv * dp[j];
  }
  for (int o = 1; o < 16; o <<= 1) {
    ssum += __shfl_xor(ssum, o);
    dsum += __shfl_xor(dsum, o);
  }
  if ((l & 15) == 0) {
    osrc[node * 4 + hh] = ssum;
    odst[node * 4 + hh] = dsum;
  }
}

__global__ __launch_bounds__(256) void att2_kernel(
    const float* __restrict__ h2, const float* __restrict__ as,
    const float* __restrict__ ad, float* __restrict__ osrc,
    float* __restrict__ odst, int n) {
  int node = blockIdx.x * 4 + (threadIdx.x >> 6);
  if (node >= n) return;
  int l = threadIdx.x & 63;
  const float* hp = h2 + (size_t)node * 128 + l * 2;
  float s = hp[0] * as[l * 2] + hp[1] * as[l * 2 + 1];
  float d = hp[0] * ad[l * 2] + hp[1] * ad[l * 2 + 1];
  for (int o = 1; o < 64; o <<= 1) {
    s += __shfl_xor(s, o);
    d += __shfl_xor(d, o);
  }
  if (l == 0) { osrc[node] = s; odst[node] = d; }
}

// ---------------------- CSR build -------------------------------------------
__global__ __launch_bounds__(256) void hist_kernel(const int* __restrict__ dst,
                                                   int* __restrict__ deg, int E) {
  int t = blockIdx.x * 256 + threadIdx.x;
  if (t < E) atomicAdd(&deg[dst[t]], 1);
}

__global__ __launch_bounds__(1024) void scan_kernel(const int* __restrict__ deg,
                                                    int* __restrict__ rowptr, int n) {
  __shared__ int part[1024];
  int t = threadIdx.x;
  int chunk = (n + 1023) / 1024;
  int s = t * chunk;
  int e = min(s + chunk, n);
  int sum = 0;
  for (int i = s; i < e; i++) sum += deg[i] + 1;
  part[t] = sum;
  __syncthreads();
  for (int off = 1; off < 1024; off <<= 1) {
    int v = (t >= off) ? part[t - off] : 0;
    __syncthreads();
    part[t] += v;
    __syncthreads();
  }
  int run = part[t] - sum;  // exclusive prefix
  for (int i = s; i < e; i++) {
    rowptr[i] = run;
    run += deg[i] + 1;
  }
  if (e == n && s < n) rowptr[n] = run;
}

__global__ __launch_bounds__(256) void fill_kernel(
    const int* __restrict__ src, const int* __restrict__ dst,
    const int* __restrict__ rowptr, int* __restrict__ cnt,
    int* __restrict__ csr_src, int E, int n) {
  int t = blockIdx.x * 256 + threadIdx.x;
  if (t < E) {
    int d = dst[t];
    int pos = rowptr[d] + atomicAdd(&cnt[d], 1);
    csr_src[pos] = src[t];
  } else if (t < E + n) {
    int i = t - E;
    csr_src[rowptr[i + 1] - 1] = i;  // self loop goes in the last slot
  }
}

// ---------------------- GAT aggregation (conv1: 4 heads x 128) --------------
__global__ __launch_bounds__(256) void gat1_agg(
    const float* __restrict__ h1, const float* __restrict__ asrc,
    const float* __restrict__ adst, const int* __restrict__ rowptr,
    const int* __restrict__ csr_src, const float* __restrict__ bias,
    float* __restrict__ out, int n) {
  int node = blockIdx.x * 4 + (threadIdx.x >> 6);
  if (node >= n) return;
  int l = threadIdx.x & 63;
  int r0 = rowptr[node];
  int deg = rowptr[node + 1] - r0;
  float4 ad4 = *(const float4*)(adst + node * 4);
  float adv[4] = {ad4.x, ad4.y, ad4.z, ad4.w};

  float m[4] = {-1e30f, -1e30f, -1e30f, -1e30f};
  for (int k = l; k < deg; k += 64) {
    int s = csr_src[r0 + k];
    float4 av = *(const float4*)(asrc + (size_t)s * 4);
    float e;
    e = LEAKY(av.x + adv[0]); m[0] = fmaxf(m[0], e);
    e = LEAKY(av.y + adv[1]); m[1] = fmaxf(m[1], e);
    e = LEAKY(av.z + adv[2]); m[2] = fmaxf(m[2], e);
    e = LEAKY(av.w + adv[3]); m[3] = fmaxf(m[3], e);
  }
  for (int o = 1; o < 64; o <<= 1) {
#pragma unroll
    for (int h = 0; h < 4; h++) m[h] = fmaxf(m[h], __shfl_xor(m[h], o));
  }

  float sum[4] = {0.f, 0.f, 0.f, 0.f};
  for (int k = l; k < deg; k += 64) {
    int s = csr_src[r0 + k];
    float4 av = *(const float4*)(asrc + (size_t)s * 4);
    float e;
    e = LEAKY(av.x + adv[0]); sum[0] += __expf(e - m[0]);
    e = LEAKY(av.y + adv[1]); sum[1] += __expf(e - m[1]);
    e = LEAKY(av.z + adv[2]); sum[2] += __expf(e - m[2]);
    e = LEAKY(av.w + adv[3]); sum[3] += __expf(e - m[3]);
  }
  for (int o = 1; o < 64; o <<= 1) {
#pragma unroll
    for (int h = 0; h < 4; h++) sum[h] += __shfl_xor(sum[h], o);
  }

  int hh = l >> 4;
  int cb = l * 8;
  float mm = m[hh];
  float sinv = 1.f / (sum[hh] + 1e-16f);
  float adm = adv[hh];

  float acc[8] = {};
  for (int k = 0; k < deg; k++) {
    int s = csr_src[r0 + k];
    float a = asrc[(size_t)s * 4 + hh];
    float e = LEAKY(a + adm);
    float w = __expf(e - mm) * sinv;
    const float* hp = h1 + (size_t)s * 512 + cb;
    float4 v0 = *(const float4*)hp;
    float4 v1 = *(const float4*)(hp + 4);
    acc[0] += w * v0.x; acc[1] += w * v0.y; acc[2] += w * v0.z; acc[3] += w * v0.w;
    acc[4] += w * v1.x; acc[5] += w * v1.y; acc[6] += w * v1.z; acc[7] += w * v1.w;
  }

  float* op = out + (size_t)node * 512 + cb;
  const float* bp = bias + cb;
#pragma unroll
  for (int j = 0; j < 8; j++) {
    float r = acc[j] + bp[j];
    op[j] = r > 0.f ? r : (__expf(r) - 1.f);  // ELU
  }
}

// ---------------------- GAT aggregation (conv2: 1 head x 128) ---------------
__global__ __launch_bounds__(256) void gat2_agg(
    const float* __restrict__ h2, const float* __restrict__ asrc,
    const float* __restrict__ adst, const int* __restrict__ rowptr,
    const int* __restrict__ csr_src, const float* __restrict__ bias,
    float* __restrict__ out, int n) {
  int node = blockIdx.x * 4 + (threadIdx.x >> 6);
  if (node >= n) return;
  int l = threadIdx.x & 63;
  int r0 = rowptr[node];
  int deg = rowptr[node + 1] - r0;
  float ad = adst[node];

  float m = -1e30f;
  for (int k = l; k < deg; k += 64) {
    int s = csr_src[r0 + k];
    float e = LEAKY(asrc[s] + ad);
    m = fmaxf(m, e);
  }
  for (int o = 1; o < 64; o <<= 1) m = fmaxf(m, __shfl_xor(m, o));

  float sum = 0.f;
  for (int k = l; k < deg; k += 64) {
    int s = csr_src[r0 + k];
    float e = LEAKY(asrc[s] + ad);
    sum += __expf(e - m);
  }
  for (int o = 1; o < 64; o <<= 1) sum += __shfl_xor(sum, o);
  float sinv = 1.f / (sum + 1e-16f);

  int cb = l * 2;
  float a0 = 0.f, a1 = 0.f;
  for (int k = 0; k < deg; k++) {
    int s = csr_src[r0 + k];
    float e = LEAKY(asrc[s] + ad);
    float w = __expf(e - m) * sinv;
    const float* hp = h2 + (size_t)s * 128 + cb;
    a0 += w * hp[0];
    a1 += w * hp[1];
  }
  float ra = a0 + bias[cb];
  float rb = a1 + bias[cb + 1];
  out[(size_t)node * 128 + cb]     = ra > 0.f ? ra : (__expf(ra) - 1.f);
  out[(size_t)node * 128 + cb + 1] = rb > 0.f ? rb : (__expf(rb) - 1.f);
}

// ---------------------- per-graph max pool ----------------------------------
__device__ inline int lower_bound_i(const int* a, int n, int v) {
  int lo = 0, hi = n;
  while (lo < hi) {
    int mid = (lo + hi) >> 1;
    if (a[mid] < v) lo = mid + 1; else hi = mid;
  }
  return lo;
}

__global__ __launch_bounds__(128) void pool_kernel(
    const float* __restrict__ x2, const int* __restrict__ batch,
    float* __restrict__ pool, int n) {
  int g = blockIdx.x;
  int t = threadIdx.x;
  int start = lower_bound_i(batch, n, g);
  int end = lower_bound_i(batch, n, g + 1);
  float m = -FLT_MAX;
  for (int i = start; i < end; i++) m = fmaxf(m, x2[(size_t)i * 128 + t]);
  pool[g * 128 + t] = m;
}

// ---------------------- classifier ------------------------------------------
__global__ __launch_bounds__(64) void classifier_kernel(
    const float* __restrict__ pool, const float* __restrict__ Wc1,
    const float* __restrict__ bc1, const float* __restrict__ Wc2,
    const float* __restrict__ bc2, float* __restrict__ out) {
  int g = blockIdx.x;
  int t = threadIdx.x;
  __shared__ float xp[128];
  __shared__ float hc[64];
  xp[t] = pool[g * 128 + t];
  xp[t + 64] = pool[g * 128 + 64 + t];
  __syncthreads();
  float s = bc1[t];
  for (int k = 0; k < 128; k++) s += xp[k] * Wc1[k * 64 + t];
  hc[t] = s > 0.f ? s : 0.f;
  __syncthreads();
  if (t < 5) {
    float o = bc2[t];
    for (int j = 0; j < 64; j++) o += hc[j] * Wc2[j * 5 + t];
    out[g * 5 + t] = o;
  }
}

// ---------------------------------------------------------------------------
extern "C" void kernel_launch(void* const* d_in, const int* in_sizes, int n_in,
                              void* d_out, int out_size, void* d_ws, size_t ws_size,
                              hipStream_t stream) {
  const float* x_scalar = (const float*)d_in[0];
  const int* x_opcode = (const int*)d_in[1];
  const int* x_source = (const int*)d_in[2];
  const int* x_sink = (const int*)d_in[3];
  const int* x_string = (const int*)d_in[4];
  const int* x_payload = (const int*)d_in[5];
  const int* edge_index = (const int*)d_in[6];
  const int* batch = (const int*)d_in[7];
  const float* emb_opcode = (const float*)d_in[8];
  const float* emb_source = (const float*)d_in[9];
  const float* emb_sink = (const float*)d_in[10];
  const float* emb_string = (const float*)d_in[11];
  const float* emb_payload = (const float*)d_in[12];
  const float* ln_g = (const float*)d_in[13];
  const float* ln_b = (const float*)d_in[14];
  const float* W1 = (const float*)d_in[15];
  const float* att_src1 = (const float*)d_in[16];
  const float* att_dst1 = (const float*)d_in[17];
  const float* b1 = (const float*)d_in[18];
  const float* W2 = (const float*)d_in[19];
  const float* att_src2 = (const float*)d_in[20];
  const float* att_dst2 = (const float*)d_in[21];
  const float* b2 = (const float*)d_in[22];
  const float* Wc1 = (const float*)d_in[23];
  const float* bc1 = (const float*)d_in[24];
  const float* Wc2 = (const float*)d_in[25];
  const float* bc2 = (const float*)d_in[26];
  float* out = (float*)d_out;

  const int N = in_sizes[0] / 96;
  const int E = in_sizes[6] / 2;
  const int G = out_size / 5;

  const int* e_src = edge_index;
  const int* e_dst = edge_index + E;

  // workspace layout
  char* w = (char*)d_ws;
  size_t o = 0;
  auto take = [&](size_t bytes) -> void* {
    void* p = w + o;
    o += (bytes + 255) & ~(size_t)255;
    return p;
  };
  float* feats = (float*)take((size_t)N * 256 * 4);  // reused as h2/x2 later
  float* h1 = (float*)take((size_t)N * 512 * 4);
  float* x1 = (float*)take((size_t)N * 512 * 4);
  float* a_src1 = (float*)take((size_t)N * 4 * 4);
  float* a_dst1 = (float*)take((size_t)N * 4 * 4);
  float* a_src2 = (float*)take((size_t)N * 4);
  float* a_dst2 = (float*)take((size_t)N * 4);
  int* deg = (int*)take((size_t)N * 2 * 4);  // deg + cnt contiguous
  int* cnt = deg + N;
  int* rowptr = (int*)take((size_t)(N + 1) * 4);
  int* csr_src = (int*)take((size_t)(E + N) * 4);
  float* pool = (float*)take((size_t)G * 128 * 4);
  float* h2 = feats;                      // feats dead after gemm1
  float* x2 = feats + (size_t)N * 128;

  // zero degree/fill counters
  hipMemsetAsync(deg, 0, (size_t)N * 2 * 4, stream);

  // CSR build (independent of features)
  hist_kernel<<<(E + 255) / 256, 256, 0, stream>>>(e_dst, deg, E);
  scan_kernel<<<1, 1024, 0, stream>>>(deg, rowptr, N);
  fill_kernel<<<(E + N + 255) / 256, 256, 0, stream>>>(e_src, e_dst, rowptr, cnt,
                                                       csr_src, E, N);

  // features + LN
  feats_kernel<<<N, 256, 0, stream>>>(x_scalar, x_opcode, x_source, x_sink,
                                      x_string, x_payload, emb_opcode, emb_source,
                                      emb_sink, emb_string, emb_payload, ln_g,
                                      ln_b, feats, N);

  // conv1
  gemm_kernel<<<dim3(512 / 64, (N + 63) / 64), 256, 0, stream>>>(feats, W1, h1, N,
                                                                 256, 512);
  att1_kernel<<<(N + 3) / 4, 256, 0, stream>>>(h1, att_src1, att_dst1, a_src1,
                                               a_dst1, N);
  gat1_agg<<<(N + 3) / 4, 256, 0, stream>>>(h1, a_src1, a_dst1, rowptr, csr_src,
                                            b1, x1, N);

  // conv2
  gemm_kernel<<<dim3(128 / 64, (N + 63) / 64), 256, 0, stream>>>(x1, W2, h2, N,
                                                                 512, 128);
  att2_kernel<<<(N + 3) / 4, 256, 0, stream>>>(h2, att_src2, att_dst2, a_src2,
                                               a_dst2, N);
  gat2_agg<<<(N + 3) / 4, 256, 0, stream>>>(h2, a_src2, a_dst2, rowptr, csr_src,
                                            b2, x2, N);

  // pool + classifier
  pool_kernel<<<G, 128, 0, stream>>>(x2, batch, pool, N);
  classifier_kernel<<<G, 64, 0, stream>>>(pool, Wc1, bc1, Wc2, bc2, out);
}

// Round 2
// 772.711 us; speedup vs baseline: 1.4704x; 1.4704x over previous
//
#include <hip/hip_runtime.h>
#include <hip/hip_bf16.h>
#include <float.h>

// ---------------------------------------------------------------------------
// GlobalFeatureGAT: feature-build+LN -> GAT(4 heads,128) -> ELU -> GAT(1,128)
// -> ELU -> per-graph max pool -> MLP(128->64->5).
// R2: GEMMs via fp16 MFMA (fp32 accum); h1/x1/h2 stored fp16 to halve
// gather traffic. Attention/softmax/aggregation math stays fp32.
// N=50000, E=500000 (+N self loops), G=64, IN_DIM=256, C=128, H1=4.
// ---------------------------------------------------------------------------

#define LEAKY(e) ((e) > 0.f ? (e) : 0.2f * (e))

typedef _Float16 half8 __attribute__((ext_vector_type(8)));
typedef float floatx4 __attribute__((ext_vector_type(4)));

// ---------------------- feature build + layernorm (fp16 out) ----------------
__global__ __launch_bounds__(256) void feats_kernel(
    const float* __restrict__ xs, const int* __restrict__ xo,
    const int* __restrict__ xsrc, const int* __restrict__ xsk,
    const int* __restrict__ xst, const int* __restrict__ xp,
    const float* __restrict__ eo, const float* __restrict__ es,
    const float* __restrict__ ek, const float* __restrict__ et,
    const float* __restrict__ ep, const float* __restrict__ lng,
    const float* __restrict__ lnb, _Float16* __restrict__ feats, int n) {
  int i = blockIdx.x;
  int t = threadIdx.x;
  __shared__ int sidx[48];
  __shared__ float red[4];

  if (t < 48) {
    if (t < 16)      sidx[t] = xo[i * 16 + t];
    else if (t < 24) sidx[t] = xsrc[i * 8 + (t - 16)];
    else if (t < 32) sidx[t] = xsk[i * 8 + (t - 24)];
    else if (t < 40) sidx[t] = xst[i * 8 + (t - 32)];
    else             sidx[t] = xp[i * 8 + (t - 40)];
  }
  __syncthreads();

  float v;
  if (t < 96) {
    v = xs[(size_t)i * 96 + t];
  } else {
    int j = t - 96;
    int grp = j >> 5;
    int d = j & 31;
    const float* tab;
    int L, off;
    switch (grp) {
      case 0: tab = eo; L = 16; off = 0; break;
      case 1: tab = es; L = 8;  off = 16; break;
      case 2: tab = ek; L = 8;  off = 24; break;
      case 3: tab = et; L = 8;  off = 32; break;
      default: tab = ep; L = 8; off = 40; break;
    }
    float s = 0.f, c = 0.f;
    for (int l = 0; l < L; l++) {
      int id = sidx[off + l];
      if (id != 0) { s += tab[(size_t)id * 32 + d]; c += 1.f; }
    }
    v = s / (c + 1e-9f);
  }

  float ws = v;
  for (int o = 32; o; o >>= 1) ws += __shfl_xor(ws, o);
  if ((t & 63) == 0) red[t >> 6] = ws;
  __syncthreads();
  float mu = (red[0] + red[1] + red[2] + red[3]) * (1.f / 256.f);
  __syncthreads();

  float diff = v - mu;
  float wq = diff * diff;
  for (int o = 32; o; o >>= 1) wq += __shfl_xor(wq, o);
  if ((t & 63) == 0) red[t >> 6] = wq;
  __syncthreads();
  float var = (red[0] + red[1] + red[2] + red[3]) * (1.f / 256.f);

  feats[(size_t)i * 256 + t] =
      (_Float16)(diff * rsqrtf(var + 1e-5f) * lng[t] + lnb[t]);
}

// ---------------------- weight transpose + fp16 convert ---------------------
__global__ __launch_bounds__(256) void transpose_f16(
    const float* __restrict__ W, _Float16* __restrict__ Wt, int K, int N) {
  int t = blockIdx.x * 256 + threadIdx.x;
  if (t < K * N) {
    int n = t / K, k = t - n * K;
    Wt[t] = (_Float16)W[(size_t)k * N + n];
  }
}

// ---------------------- fp16 MFMA GEMM: C = A @ Bt^T ------------------------
// A: M x K (row-major fp16), Bt: N x K (row-major fp16), C: M x N (fp16).
// 128x128 tile, 4 waves of 64x64, 16x16x32 MFMA, fp32 accum.
__global__ __launch_bounds__(256) void gemm_f16(
    const _Float16* __restrict__ A, const _Float16* __restrict__ Bt,
    _Float16* __restrict__ C, int M, int K, int N) {
  __shared__ _Float16 As[128][40];
  __shared__ _Float16 Bs[128][40];
  int m0 = blockIdx.y * 128;
  int n0 = blockIdx.x * 128;
  int tid = threadIdx.x;
  int wave = tid >> 6, lane = tid & 63;
  int wm = (wave >> 1) * 64, wn = (wave & 1) * 64;
  int lr = lane & 15, lq = lane >> 4;

  int srow = tid >> 1;
  int sseg = (tid & 1) * 16;

  floatx4 acc[4][4] = {};

  for (int k0 = 0; k0 < K; k0 += 32) {
    // stage A tile (guarded) and B tile
    {
      int gr = m0 + srow;
      float4 v0 = {0.f, 0.f, 0.f, 0.f}, v1 = {0.f, 0.f, 0.f, 0.f};
      if (gr < M) {
        const float4* ap = (const float4*)(A + (size_t)gr * K + k0 + sseg);
        v0 = ap[0];
        v1 = ap[1];
      }
      *(float4*)&As[srow][sseg] = v0;
      *(float4*)&As[srow][sseg + 8] = v1;

      const float4* bp = (const float4*)(Bt + (size_t)(n0 + srow) * K + k0 + sseg);
      *(float4*)&Bs[srow][sseg] = bp[0];
      *(float4*)&Bs[srow][sseg + 8] = bp[1];
    }
    __syncthreads();

    half8 af[4], bf[4];
#pragma unroll
    for (int i = 0; i < 4; i++)
      af[i] = *(const half8*)&As[wm + i * 16 + lr][lq * 8];
#pragma unroll
    for (int j = 0; j < 4; j++)
      bf[j] = *(const half8*)&Bs[wn + j * 16 + lr][lq * 8];
#pragma unroll
    for (int i = 0; i < 4; i++)
#pragma unroll
      for (int j = 0; j < 4; j++)
        acc[i][j] =
            __builtin_amdgcn_mfma_f32_16x16x32_f16(af[i], bf[j], acc[i][j], 0, 0, 0);
    __syncthreads();
  }

#pragma unroll
  for (int i = 0; i < 4; i++) {
    int rbase = m0 + wm + i * 16 + lq * 4;
#pragma unroll
    for (int r = 0; r < 4; r++) {
      int row = rbase + r;
      if (row < M) {
#pragma unroll
        for (int j = 0; j < 4; j++) {
          int col = n0 + wn + j * 16 + lr;
          C[(size_t)row * N + col] = (_Float16)acc[i][j][r];
        }
      }
    }
  }
}

// ---------------------- attention score dots --------------------------------
__global__ __launch_bounds__(256) void att1_kernel(
    const _Float16* __restrict__ h1, const float* __restrict__ as,
    const float* __restrict__ ad, float* __restrict__ osrc,
    float* __restrict__ odst, int n) {
  int node = blockIdx.x * 4 + (threadIdx.x >> 6);
  if (node >= n) return;
  int l = threadIdx.x & 63;
  int hh = l >> 4;
  int cb = (l & 15) * 8;
  const _Float16* hp = h1 + (size_t)node * 512 + l * 8;
  const float* ap = as + hh * 128 + cb;
  const float* dp = ad + hh * 128 + cb;
  float ssum = 0.f, dsum = 0.f;
  half8 hv = *(const half8*)hp;
#pragma unroll
  for (int j = 0; j < 8; j++) {
    float h = (float)hv[j];
    ssum += h * ap[j];
    dsum += h * dp[j];
  }
  for (int o = 1; o < 16; o <<= 1) {
    ssum += __shfl_xor(ssum, o);
    dsum += __shfl_xor(dsum, o);
  }
  if ((l & 15) == 0) {
    osrc[node * 4 + hh] = ssum;
    odst[node * 4 + hh] = dsum;
  }
}

__global__ __launch_bounds__(256) void att2_kernel(
    const _Float16* __restrict__ h2, const float* __restrict__ as,
    const float* __restrict__ ad, float* __restrict__ osrc,
    float* __restrict__ odst, int n) {
  int node = blockIdx.x * 4 + (threadIdx.x >> 6);
  if (node >= n) return;
  int l = threadIdx.x & 63;
  const _Float16* hp = h2 + (size_t)node * 128 + l * 2;
  float h0 = (float)hp[0], h1v = (float)hp[1];
  float s = h0 * as[l * 2] + h1v * as[l * 2 + 1];
  float d = h0 * ad[l * 2] + h1v * ad[l * 2 + 1];
  for (int o = 1; o < 64; o <<= 1) {
    s += __shfl_xor(s, o);
    d += __shfl_xor(d, o);
  }
  if (l == 0) { osrc[node] = s; odst[node] = d; }
}

// ---------------------- CSR build -------------------------------------------
__global__ __launch_bounds__(256) void hist_kernel(const int* __restrict__ dst,
                                                   int* __restrict__ deg, int E) {
  int t = blockIdx.x * 256 + threadIdx.x;
  if (t < E) atomicAdd(&deg[dst[t]], 1);
}

__global__ __launch_bounds__(1024) void scan_kernel(const int* __restrict__ deg,
                                                    int* __restrict__ rowptr, int n) {
  __shared__ int part[1024];
  int t = threadIdx.x;
  int chunk = (n + 1023) / 1024;
  int s = t * chunk;
  int e = min(s + chunk, n);
  int sum = 0;
  for (int i = s; i < e; i++) sum += deg[i] + 1;
  part[t] = sum;
  __syncthreads();
  for (int off = 1; off < 1024; off <<= 1) {
    int v = (t >= off) ? part[t - off] : 0;
    __syncthreads();
    part[t] += v;
    __syncthreads();
  }
  int run = part[t] - sum;  // exclusive prefix
  for (int i = s; i < e; i++) {
    rowptr[i] = run;
    run += deg[i] + 1;
  }
  if (e == n && s < n) rowptr[n] = run;
}

__global__ __launch_bounds__(256) void fill_kernel(
    const int* __restrict__ src, const int* __restrict__ dst,
    const int* __restrict__ rowptr, int* __restrict__ cnt,
    int* __restrict__ csr_src, int E, int n) {
  int t = blockIdx.x * 256 + threadIdx.x;
  if (t < E) {
    int d = dst[t];
    int pos = rowptr[d] + atomicAdd(&cnt[d], 1);
    csr_src[pos] = src[t];
  } else if (t < E + n) {
    int i = t - E;
    csr_src[rowptr[i + 1] - 1] = i;  // self loop in the last slot
  }
}

// ---------------------- GAT aggregation (conv1: 4 heads x 128) --------------
__global__ __launch_bounds__(256) void gat1_agg(
    const _Float16* __restrict__ h1, const float* __restrict__ asrc,
    const float* __restrict__ adst, const int* __restrict__ rowptr,
    const int* __restrict__ csr_src, const float* __restrict__ bias,
    _Float16* __restrict__ out, int n) {
  int node = blockIdx.x * 4 + (threadIdx.x >> 6);
  if (node >= n) return;
  int l = threadIdx.x & 63;
  int r0 = rowptr[node];
  int deg = rowptr[node + 1] - r0;
  float4 ad4 = *(const float4*)(adst + node * 4);
  float adv[4] = {ad4.x, ad4.y, ad4.z, ad4.w};

  float m[4] = {-1e30f, -1e30f, -1e30f, -1e30f};
  for (int k = l; k < deg; k += 64) {
    int s = csr_src[r0 + k];
    float4 av = *(const float4*)(asrc + (size_t)s * 4);
    float e;
    e = LEAKY(av.x + adv[0]); m[0] = fmaxf(m[0], e);
    e = LEAKY(av.y + adv[1]); m[1] = fmaxf(m[1], e);
    e = LEAKY(av.z + adv[2]); m[2] = fmaxf(m[2], e);
    e = LEAKY(av.w + adv[3]); m[3] = fmaxf(m[3], e);
  }
  for (int o = 1; o < 64; o <<= 1) {
#pragma unroll
    for (int h = 0; h < 4; h++) m[h] = fmaxf(m[h], __shfl_xor(m[h], o));
  }

  float sum[4] = {0.f, 0.f, 0.f, 0.f};
  for (int k = l; k < deg; k += 64) {
    int s = csr_src[r0 + k];
    float4 av = *(const float4*)(asrc + (size_t)s * 4);
    float e;
    e = LEAKY(av.x + adv[0]); sum[0] += __expf(e - m[0]);
    e = LEAKY(av.y + adv[1]); sum[1] += __expf(e - m[1]);
    e = LEAKY(av.z + adv[2]); sum[2] += __expf(e - m[2]);
    e = LEAKY(av.w + adv[3]); sum[3] += __expf(e - m[3]);
  }
  for (int o = 1; o < 64; o <<= 1) {
#pragma unroll
    for (int h = 0; h < 4; h++) sum[h] += __shfl_xor(sum[h], o);
  }

  int hh = l >> 4;
  int cb = l * 8;
  float mm = m[hh];
  float sinv = 1.f / (sum[hh] + 1e-16f);
  float adm = adv[hh];

  float acc[8] = {};
  for (int k = 0; k < deg; k++) {
    int s = csr_src[r0 + k];
    float a = asrc[(size_t)s * 4 + hh];
    float e = LEAKY(a + adm);
    float w = __expf(e - mm) * sinv;
    const half8 hv = *(const half8*)(h1 + (size_t)s * 512 + cb);
#pragma unroll
    for (int j = 0; j < 8; j++) acc[j] += w * (float)hv[j];
  }

  const float* bp = bias + cb;
  half8 ov;
#pragma unroll
  for (int j = 0; j < 8; j++) {
    float r = acc[j] + bp[j];
    ov[j] = (_Float16)(r > 0.f ? r : (__expf(r) - 1.f));  // ELU
  }
  *(half8*)(out + (size_t)node * 512 + cb) = ov;
}

// ---------------------- GAT aggregation (conv2: 1 head x 128) ---------------
__global__ __launch_bounds__(256) void gat2_agg(
    const _Float16* __restrict__ h2, const float* __restrict__ asrc,
    const float* __restrict__ adst, const int* __restrict__ rowptr,
    const int* __restrict__ csr_src, const float* __restrict__ bias,
    float* __restrict__ out, int n) {
  int node = blockIdx.x * 4 + (threadIdx.x >> 6);
  if (node >= n) return;
  int l = threadIdx.x & 63;
  int r0 = rowptr[node];
  int deg = rowptr[node + 1] - r0;
  float ad = adst[node];

  float m = -1e30f;
  for (int k = l; k < deg; k += 64) {
    int s = csr_src[r0 + k];
    float e = LEAKY(asrc[s] + ad);
    m = fmaxf(m, e);
  }
  for (int o = 1; o < 64; o <<= 1) m = fmaxf(m, __shfl_xor(m, o));

  float sum = 0.f;
  for (int k = l; k < deg; k += 64) {
    int s = csr_src[r0 + k];
    float e = LEAKY(asrc[s] + ad);
    sum += __expf(e - m);
  }
  for (int o = 1; o < 64; o <<= 1) sum += __shfl_xor(sum, o);
  float sinv = 1.f / (sum + 1e-16f);

  int cb = l * 2;
  float a0 = 0.f, a1 = 0.f;
  for (int k = 0; k < deg; k++) {
    int s = csr_src[r0 + k];
    float e = LEAKY(asrc[s] + ad);
    float w = __expf(e - m) * sinv;
    const _Float16* hp = h2 + (size_t)s * 128 + cb;
    a0 += w * (float)hp[0];
    a1 += w * (float)hp[1];
  }
  float ra = a0 + bias[cb];
  float rb = a1 + bias[cb + 1];
  out[(size_t)node * 128 + cb]     = ra > 0.f ? ra : (__expf(ra) - 1.f);
  out[(size_t)node * 128 + cb + 1] = rb > 0.f ? rb : (__expf(rb) - 1.f);
}

// ---------------------- per-graph max pool ----------------------------------
__device__ inline int lower_bound_i(const int* a, int n, int v) {
  int lo = 0, hi = n;
  while (lo < hi) {
    int mid = (lo + hi) >> 1;
    if (a[mid] < v) lo = mid + 1; else hi = mid;
  }
  return lo;
}

__global__ __launch_bounds__(128) void pool_kernel(
    const float* __restrict__ x2, const int* __restrict__ batch,
    float* __restrict__ pool, int n) {
  int g = blockIdx.x;
  int t = threadIdx.x;
  int start = lower_bound_i(batch, n, g);
  int end = lower_bound_i(batch, n, g + 1);
  float m = -FLT_MAX;
  for (int i = start; i < end; i++) m = fmaxf(m, x2[(size_t)i * 128 + t]);
  pool[g * 128 + t] = m;
}

// ---------------------- classifier ------------------------------------------
__global__ __launch_bounds__(64) void classifier_kernel(
    const float* __restrict__ pool, const float* __restrict__ Wc1,
    const float* __restrict__ bc1, const float* __restrict__ Wc2,
    const float* __restrict__ bc2, float* __restrict__ out) {
  int g = blockIdx.x;
  int t = threadIdx.x;
  __shared__ float xp[128];
  __shared__ float hc[64];
  xp[t] = pool[g * 128 + t];
  xp[t + 64] = pool[g * 128 + 64 + t];
  __syncthreads();
  float s = bc1[t];
  for (int k = 0; k < 128; k++) s += xp[k] * Wc1[k * 64 + t];
  hc[t] = s > 0.f ? s : 0.f;
  __syncthreads();
  if (t < 5) {
    float o = bc2[t];
    for (int j = 0; j < 64; j++) o += hc[j] * Wc2[j * 5 + t];
    out[g * 5 + t] = o;
  }
}

// ---------------------------------------------------------------------------
extern "C" void kernel_launch(void* const* d_in, const int* in_sizes, int n_in,
                              void* d_out, int out_size, void* d_ws, size_t ws_size,
                              hipStream_t stream) {
  const float* x_scalar = (const float*)d_in[0];
  const int* x_opcode = (const int*)d_in[1];
  const int* x_source = (const int*)d_in[2];
  const int* x_sink = (const int*)d_in[3];
  const int* x_string = (const int*)d_in[4];
  const int* x_payload = (const int*)d_in[5];
  const int* edge_index = (const int*)d_in[6];
  const int* batch = (const int*)d_in[7];
  const float* emb_opcode = (const float*)d_in[8];
  const float* emb_source = (const float*)d_in[9];
  const float* emb_sink = (const float*)d_in[10];
  const float* emb_string = (const float*)d_in[11];
  const float* emb_payload = (const float*)d_in[12];
  const float* ln_g = (const float*)d_in[13];
  const float* ln_b = (const float*)d_in[14];
  const float* W1 = (const float*)d_in[15];
  const float* att_src1 = (const float*)d_in[16];
  const float* att_dst1 = (const float*)d_in[17];
  const float* b1 = (const float*)d_in[18];
  const float* W2 = (const float*)d_in[19];
  const float* att_src2 = (const float*)d_in[20];
  const float* att_dst2 = (const float*)d_in[21];
  const float* b2 = (const float*)d_in[22];
  const float* Wc1 = (const float*)d_in[23];
  const float* bc1 = (const float*)d_in[24];
  const float* Wc2 = (const float*)d_in[25];
  const float* bc2 = (const float*)d_in[26];
  float* out = (float*)d_out;

  const int N = in_sizes[0] / 96;
  const int E = in_sizes[6] / 2;
  const int G = out_size / 5;

  const int* e_src = edge_index;
  const int* e_dst = edge_index + E;

  // workspace layout
  char* w = (char*)d_ws;
  size_t o = 0;
  auto take = [&](size_t bytes) -> void* {
    void* p = w + o;
    o += (bytes + 255) & ~(size_t)255;
    return p;
  };
  _Float16* feats = (_Float16*)take((size_t)N * 256 * 2);
  _Float16* h1 = (_Float16*)take((size_t)N * 512 * 2);
  _Float16* x1 = (_Float16*)take((size_t)N * 512 * 2);
  _Float16* h2 = (_Float16*)take((size_t)N * 128 * 2);
  float* x2 = (float*)take((size_t)N * 128 * 4);
  _Float16* Wt1 = (_Float16*)take((size_t)512 * 256 * 2);
  _Float16* Wt2 = (_Float16*)take((size_t)128 * 512 * 2);
  float* a_src1 = (float*)take((size_t)N * 4 * 4);
  float* a_dst1 = (float*)take((size_t)N * 4 * 4);
  float* a_src2 = (float*)take((size_t)N * 4);
  float* a_dst2 = (float*)take((size_t)N * 4);
  int* deg = (int*)take((size_t)N * 2 * 4);  // deg + cnt contiguous
  int* cnt = deg + N;
  int* rowptr = (int*)take((size_t)(N + 1) * 4);
  int* csr_src = (int*)take((size_t)(E + N) * 4);
  float* pool = (float*)take((size_t)G * 128 * 4);

  hipMemsetAsync(deg, 0, (size_t)N * 2 * 4, stream);

  // CSR build (independent of features)
  hist_kernel<<<(E + 255) / 256, 256, 0, stream>>>(e_dst, deg, E);
  scan_kernel<<<1, 1024, 0, stream>>>(deg, rowptr, N);
  fill_kernel<<<(E + N + 255) / 256, 256, 0, stream>>>(e_src, e_dst, rowptr, cnt,
                                                       csr_src, E, N);

  // weights -> transposed fp16
  transpose_f16<<<(256 * 512 + 255) / 256, 256, 0, stream>>>(W1, Wt1, 256, 512);
  transpose_f16<<<(512 * 128 + 255) / 256, 256, 0, stream>>>(W2, Wt2, 512, 128);

  // features + LN (fp16 out)
  feats_kernel<<<N, 256, 0, stream>>>(x_scalar, x_opcode, x_source, x_sink,
                                      x_string, x_payload, emb_opcode, emb_source,
                                      emb_sink, emb_string, emb_payload, ln_g,
                                      ln_b, feats, N);

  int mblocks = (N + 127) / 128;
  // conv1: h1 = feats @ W1  (M=N, K=256, N=512)
  gemm_f16<<<dim3(512 / 128, mblocks), 256, 0, stream>>>(feats, Wt1, h1, N, 256, 512);
  att1_kernel<<<(N + 3) / 4, 256, 0, stream>>>(h1, att_src1, att_dst1, a_src1,
                                               a_dst1, N);
  gat1_agg<<<(N + 3) / 4, 256, 0, stream>>>(h1, a_src1, a_dst1, rowptr, csr_src,
                                            b1, x1, N);

  // conv2: h2 = x1 @ W2  (M=N, K=512, N=128)
  gemm_f16<<<dim3(128 / 128, mblocks), 256, 0, stream>>>(x1, Wt2, h2, N, 512, 128);
  att2_kernel<<<(N + 3) / 4, 256, 0, stream>>>(h2, att_src2, att_dst2, a_src2,
                                               a_dst2, N);
  gat2_agg<<<(N + 3) / 4, 256, 0, stream>>>(h2, a_src2, a_dst2, rowptr, csr_src,
                                            b2, x2, N);

  // pool + classifier
  pool_kernel<<<G, 128, 0, stream>>>(x2, batch, pool, N);
  classifier_kernel<<<G, 64, 0, stream>>>(pool, Wc1, bc1, Wc2, bc2, out);
}

// Round 3
// 678.877 us; speedup vs baseline: 1.6736x; 1.1382x over previous
//
#include <hip/hip_runtime.h>
#include <hip/hip_bf16.h>
#include <float.h>

// ---------------------------------------------------------------------------
// GlobalFeatureGAT: feature-build+LN -> GAT(4 heads,128) -> ELU -> GAT(1,128)
// -> ELU -> per-graph max pool -> MLP(128->64->5).
// R3: feats_kernel rewritten wave-per-node, shfl-only (no LDS/syncthreads).
// GEMMs fp16 MFMA (fp32 accum); h1/x1/h2 fp16. Softmax/agg math fp32.
// N=50000, E=500000 (+N self loops), G=64, IN_DIM=256, C=128, H1=4.
// ---------------------------------------------------------------------------

#define LEAKY(e) ((e) > 0.f ? (e) : 0.2f * (e))

typedef _Float16 half8 __attribute__((ext_vector_type(8)));
typedef float floatx4 __attribute__((ext_vector_type(4)));

// ---------------------- feature build + layernorm (fp16 out) ----------------
// One wave per node. Lane l owns channels {l, 64+l, 128+l, 192+l}.
//   v0: scalar[l]            (all lanes)
//   v1: l<32 scalar[64+l], l>=32 opcode-emb dim l-32   (idx lanes 0..15)
//   v2: l<32 source dim l  (idx 16..23), l>=32 sink dim l-32 (idx 24..31)
//   v3: l<32 string dim l  (idx 32..39), l>=32 payload dim l-32 (idx 40..47)
__global__ __launch_bounds__(256) void feats_kernel(
    const float* __restrict__ xs, const int* __restrict__ xo,
    const int* __restrict__ xsrc, const int* __restrict__ xsk,
    const int* __restrict__ xst, const int* __restrict__ xp,
    const float* __restrict__ eo, const float* __restrict__ es,
    const float* __restrict__ ek, const float* __restrict__ et,
    const float* __restrict__ ep, const float* __restrict__ lng,
    const float* __restrict__ lnb, _Float16* __restrict__ feats, int n) {
  int node = blockIdx.x * 4 + (threadIdx.x >> 6);
  if (node >= n) return;
  int l = threadIdx.x & 63;

  // lanes 0..47 load the 48 embedding indices for this node
  int myidx = 0;
  if (l < 16)      myidx = xo[node * 16 + l];
  else if (l < 24) myidx = xsrc[node * 8 + (l - 16)];
  else if (l < 32) myidx = xsk[node * 8 + (l - 24)];
  else if (l < 40) myidx = xst[node * 8 + (l - 32)];
  else if (l < 48) myidx = xp[node * 8 + (l - 40)];

  const float* xrow = xs + (size_t)node * 96;
  float v0 = xrow[l];
  float v1, v2, v3;

  bool hi = (l >= 32);
  int d = l & 31;

  // v1: scalar (lanes<32) or opcode embedding (lanes>=32)
  {
    float s = 0.f, c = 0.f;
#pragma unroll
    for (int j = 0; j < 16; j++) {
      int id = __shfl(myidx, j);
      if (hi && id != 0) { s += eo[(size_t)id * 32 + d]; c += 1.f; }
    }
    float sc = hi ? 0.f : xrow[64 + l];
    v1 = hi ? (s / (c + 1e-9f)) : sc;
  }
  // v2: source (lanes<32) / sink (lanes>=32)
  {
    const float* tab = hi ? ek : es;
    int base = hi ? 24 : 16;
    float s = 0.f, c = 0.f;
#pragma unroll
    for (int j = 0; j < 8; j++) {
      int id = __shfl(myidx, base + j);
      if (id != 0) { s += tab[(size_t)id * 32 + d]; c += 1.f; }
    }
    v2 = s / (c + 1e-9f);
  }
  // v3: string (lanes<32) / payload (lanes>=32)
  {
    const float* tab = hi ? ep : et;
    int base = hi ? 40 : 32;
    float s = 0.f, c = 0.f;
#pragma unroll
    for (int j = 0; j < 8; j++) {
      int id = __shfl(myidx, base + j);
      if (id != 0) { s += tab[(size_t)id * 32 + d]; c += 1.f; }
    }
    v3 = s / (c + 1e-9f);
  }

  // layernorm over the 256 channels (wave-wide, shfl only)
  float sum = v0 + v1 + v2 + v3;
  for (int o = 32; o; o >>= 1) sum += __shfl_xor(sum, o);
  float mu = sum * (1.f / 256.f);

  float d0 = v0 - mu, d1 = v1 - mu, d2 = v2 - mu, d3 = v3 - mu;
  float q = d0 * d0 + d1 * d1 + d2 * d2 + d3 * d3;
  for (int o = 32; o; o >>= 1) q += __shfl_xor(q, o);
  float rstd = rsqrtf(q * (1.f / 256.f) + 1e-5f);

  _Float16* frow = feats + (size_t)node * 256;
  frow[l]       = (_Float16)(d0 * rstd * lng[l] + lnb[l]);
  frow[64 + l]  = (_Float16)(d1 * rstd * lng[64 + l] + lnb[64 + l]);
  frow[128 + l] = (_Float16)(d2 * rstd * lng[128 + l] + lnb[128 + l]);
  frow[192 + l] = (_Float16)(d3 * rstd * lng[192 + l] + lnb[192 + l]);
}

// ---------------------- weight transpose + fp16 convert ---------------------
__global__ __launch_bounds__(256) void transpose_f16(
    const float* __restrict__ W, _Float16* __restrict__ Wt, int K, int N) {
  int t = blockIdx.x * 256 + threadIdx.x;
  if (t < K * N) {
    int n = t / K, k = t - n * K;
    Wt[t] = (_Float16)W[(size_t)k * N + n];
  }
}

// ---------------------- fp16 MFMA GEMM: C = A @ Bt^T ------------------------
// A: M x K (row-major fp16), Bt: N x K (row-major fp16), C: M x N (fp16).
// 128x128 tile, 4 waves of 64x64, 16x16x32 MFMA, fp32 accum.
__global__ __launch_bounds__(256) void gemm_f16(
    const _Float16* __restrict__ A, const _Float16* __restrict__ Bt,
    _Float16* __restrict__ C, int M, int K, int N) {
  __shared__ _Float16 As[128][40];
  __shared__ _Float16 Bs[128][40];
  int m0 = blockIdx.y * 128;
  int n0 = blockIdx.x * 128;
  int tid = threadIdx.x;
  int wave = tid >> 6, lane = tid & 63;
  int wm = (wave >> 1) * 64, wn = (wave & 1) * 64;
  int lr = lane & 15, lq = lane >> 4;

  int srow = tid >> 1;
  int sseg = (tid & 1) * 16;

  floatx4 acc[4][4] = {};

  for (int k0 = 0; k0 < K; k0 += 32) {
    {
      int gr = m0 + srow;
      float4 v0 = {0.f, 0.f, 0.f, 0.f}, v1 = {0.f, 0.f, 0.f, 0.f};
      if (gr < M) {
        const float4* ap = (const float4*)(A + (size_t)gr * K + k0 + sseg);
        v0 = ap[0];
        v1 = ap[1];
      }
      *(float4*)&As[srow][sseg] = v0;
      *(float4*)&As[srow][sseg + 8] = v1;

      const float4* bp = (const float4*)(Bt + (size_t)(n0 + srow) * K + k0 + sseg);
      *(float4*)&Bs[srow][sseg] = bp[0];
      *(float4*)&Bs[srow][sseg + 8] = bp[1];
    }
    __syncthreads();

    half8 af[4], bf[4];
#pragma unroll
    for (int i = 0; i < 4; i++)
      af[i] = *(const half8*)&As[wm + i * 16 + lr][lq * 8];
#pragma unroll
    for (int j = 0; j < 4; j++)
      bf[j] = *(const half8*)&Bs[wn + j * 16 + lr][lq * 8];
#pragma unroll
    for (int i = 0; i < 4; i++)
#pragma unroll
      for (int j = 0; j < 4; j++)
        acc[i][j] =
            __builtin_amdgcn_mfma_f32_16x16x32_f16(af[i], bf[j], acc[i][j], 0, 0, 0);
    __syncthreads();
  }

#pragma unroll
  for (int i = 0; i < 4; i++) {
    int rbase = m0 + wm + i * 16 + lq * 4;
#pragma unroll
    for (int r = 0; r < 4; r++) {
      int row = rbase + r;
      if (row < M) {
#pragma unroll
        for (int j = 0; j < 4; j++) {
          int col = n0 + wn + j * 16 + lr;
          C[(size_t)row * N + col] = (_Float16)acc[i][j][r];
        }
      }
    }
  }
}

// ---------------------- attention score dots --------------------------------
__global__ __launch_bounds__(256) void att1_kernel(
    const _Float16* __restrict__ h1, const float* __restrict__ as,
    const float* __restrict__ ad, float* __restrict__ osrc,
    float* __restrict__ odst, int n) {
  int node = blockIdx.x * 4 + (threadIdx.x >> 6);
  if (node >= n) return;
  int l = threadIdx.x & 63;
  int hh = l >> 4;
  int cb = (l & 15) * 8;
  const _Float16* hp = h1 + (size_t)node * 512 + l * 8;
  const float* ap = as + hh * 128 + cb;
  const float* dp = ad + hh * 128 + cb;
  float ssum = 0.f, dsum = 0.f;
  half8 hv = *(const half8*)hp;
#pragma unroll
  for (int j = 0; j < 8; j++) {
    float h = (float)hv[j];
    ssum += h * ap[j];
    dsum += h * dp[j];
  }
  for (int o = 1; o < 16; o <<= 1) {
    ssum += __shfl_xor(ssum, o);
    dsum += __shfl_xor(dsum, o);
  }
  if ((l & 15) == 0) {
    osrc[node * 4 + hh] = ssum;
    odst[node * 4 + hh] = dsum;
  }
}

__global__ __launch_bounds__(256) void att2_kernel(
    const _Float16* __restrict__ h2, const float* __restrict__ as,
    const float* __restrict__ ad, float* __restrict__ osrc,
    float* __restrict__ odst, int n) {
  int node = blockIdx.x * 4 + (threadIdx.x >> 6);
  if (node >= n) return;
  int l = threadIdx.x & 63;
  const _Float16* hp = h2 + (size_t)node * 128 + l * 2;
  float h0 = (float)hp[0], h1v = (float)hp[1];
  float s = h0 * as[l * 2] + h1v * as[l * 2 + 1];
  float d = h0 * ad[l * 2] + h1v * ad[l * 2 + 1];
  for (int o = 1; o < 64; o <<= 1) {
    s += __shfl_xor(s, o);
    d += __shfl_xor(d, o);
  }
  if (l == 0) { osrc[node] = s; odst[node] = d; }
}

// ---------------------- CSR build -------------------------------------------
__global__ __launch_bounds__(256) void hist_kernel(const int* __restrict__ dst,
                                                   int* __restrict__ deg, int E) {
  int t = blockIdx.x * 256 + threadIdx.x;
  if (t < E) atomicAdd(&deg[dst[t]], 1);
}

__global__ __launch_bounds__(1024) void scan_kernel(const int* __restrict__ deg,
                                                    int* __restrict__ rowptr, int n) {
  __shared__ int part[1024];
  int t = threadIdx.x;
  int chunk = (n + 1023) / 1024;
  int s = t * chunk;
  int e = min(s + chunk, n);
  int sum = 0;
  for (int i = s; i < e; i++) sum += deg[i] + 1;
  part[t] = sum;
  __syncthreads();
  for (int off = 1; off < 1024; off <<= 1) {
    int v = (t >= off) ? part[t - off] : 0;
    __syncthreads();
    part[t] += v;
    __syncthreads();
  }
  int run = part[t] - sum;  // exclusive prefix
  for (int i = s; i < e; i++) {
    rowptr[i] = run;
    run += deg[i] + 1;
  }
  if (e == n && s < n) rowptr[n] = run;
}

__global__ __launch_bounds__(256) void fill_kernel(
    const int* __restrict__ src, const int* __restrict__ dst,
    const int* __restrict__ rowptr, int* __restrict__ cnt,
    int* __restrict__ csr_src, int E, int n) {
  int t = blockIdx.x * 256 + threadIdx.x;
  if (t < E) {
    int d = dst[t];
    int pos = rowptr[d] + atomicAdd(&cnt[d], 1);
    csr_src[pos] = src[t];
  } else if (t < E + n) {
    int i = t - E;
    csr_src[rowptr[i + 1] - 1] = i;  // self loop in the last slot
  }
}

// ---------------------- GAT aggregation (conv1: 4 heads x 128) --------------
__global__ __launch_bounds__(256) void gat1_agg(
    const _Float16* __restrict__ h1, const float* __restrict__ asrc,
    const float* __restrict__ adst, const int* __restrict__ rowptr,
    const int* __restrict__ csr_src, const float* __restrict__ bias,
    _Float16* __restrict__ out, int n) {
  int node = blockIdx.x * 4 + (threadIdx.x >> 6);
  if (node >= n) return;
  int l = threadIdx.x & 63;
  int r0 = rowptr[node];
  int deg = rowptr[node + 1] - r0;
  float4 ad4 = *(const float4*)(adst + node * 4);
  float adv[4] = {ad4.x, ad4.y, ad4.z, ad4.w};

  float m[4] = {-1e30f, -1e30f, -1e30f, -1e30f};
  for (int k = l; k < deg; k += 64) {
    int s = csr_src[r0 + k];
    float4 av = *(const float4*)(asrc + (size_t)s * 4);
    float e;
    e = LEAKY(av.x + adv[0]); m[0] = fmaxf(m[0], e);
    e = LEAKY(av.y + adv[1]); m[1] = fmaxf(m[1], e);
    e = LEAKY(av.z + adv[2]); m[2] = fmaxf(m[2], e);
    e = LEAKY(av.w + adv[3]); m[3] = fmaxf(m[3], e);
  }
  for (int o = 1; o < 64; o <<= 1) {
#pragma unroll
    for (int h = 0; h < 4; h++) m[h] = fmaxf(m[h], __shfl_xor(m[h], o));
  }

  float sum[4] = {0.f, 0.f, 0.f, 0.f};
  for (int k = l; k < deg; k += 64) {
    int s = csr_src[r0 + k];
    float4 av = *(const float4*)(asrc + (size_t)s * 4);
    float e;
    e = LEAKY(av.x + adv[0]); sum[0] += __expf(e - m[0]);
    e = LEAKY(av.y + adv[1]); sum[1] += __expf(e - m[1]);
    e = LEAKY(av.z + adv[2]); sum[2] += __expf(e - m[2]);
    e = LEAKY(av.w + adv[3]); sum[3] += __expf(e - m[3]);
  }
  for (int o = 1; o < 64; o <<= 1) {
#pragma unroll
    for (int h = 0; h < 4; h++) sum[h] += __shfl_xor(sum[h], o);
  }

  int hh = l >> 4;
  int cb = l * 8;
  float mm = m[hh];
  float sinv = 1.f / (sum[hh] + 1e-16f);
  float adm = adv[hh];

  float acc[8] = {};
  for (int k = 0; k < deg; k++) {
    int s = csr_src[r0 + k];
    float a = asrc[(size_t)s * 4 + hh];
    float e = LEAKY(a + adm);
    float w = __expf(e - mm) * sinv;
    const half8 hv = *(const half8*)(h1 + (size_t)s * 512 + cb);
#pragma unroll
    for (int j = 0; j < 8; j++) acc[j] += w * (float)hv[j];
  }

  const float* bp = bias + cb;
  half8 ov;
#pragma unroll
  for (int j = 0; j < 8; j++) {
    float r = acc[j] + bp[j];
    ov[j] = (_Float16)(r > 0.f ? r : (__expf(r) - 1.f));  // ELU
  }
  *(half8*)(out + (size_t)node * 512 + cb) = ov;
}

// ---------------------- GAT aggregation (conv2: 1 head x 128) ---------------
__global__ __launch_bounds__(256) void gat2_agg(
    const _Float16* __restrict__ h2, const float* __restrict__ asrc,
    const float* __restrict__ adst, const int* __restrict__ rowptr,
    const int* __restrict__ csr_src, const float* __restrict__ bias,
    float* __restrict__ out, int n) {
  int node = blockIdx.x * 4 + (threadIdx.x >> 6);
  if (node >= n) return;
  int l = threadIdx.x & 63;
  int r0 = rowptr[node];
  int deg = rowptr[node + 1] - r0;
  float ad = adst[node];

  float m = -1e30f;
  for (int k = l; k < deg; k += 64) {
    int s = csr_src[r0 + k];
    float e = LEAKY(asrc[s] + ad);
    m = fmaxf(m, e);
  }
  for (int o = 1; o < 64; o <<= 1) m = fmaxf(m, __shfl_xor(m, o));

  float sum = 0.f;
  for (int k = l; k < deg; k += 64) {
    int s = csr_src[r0 + k];
    float e = LEAKY(asrc[s] + ad);
    sum += __expf(e - m);
  }
  for (int o = 1; o < 64; o <<= 1) sum += __shfl_xor(sum, o);
  float sinv = 1.f / (sum + 1e-16f);

  int cb = l * 2;
  float a0 = 0.f, a1 = 0.f;
  for (int k = 0; k < deg; k++) {
    int s = csr_src[r0 + k];
    float e = LEAKY(asrc[s] + ad);
    float w = __expf(e - m) * sinv;
    const _Float16* hp = h2 + (size_t)s * 128 + cb;
    a0 += w * (float)hp[0];
    a1 += w * (float)hp[1];
  }
  float ra = a0 + bias[cb];
  float rb = a1 + bias[cb + 1];
  out[(size_t)node * 128 + cb]     = ra > 0.f ? ra : (__expf(ra) - 1.f);
  out[(size_t)node * 128 + cb + 1] = rb > 0.f ? rb : (__expf(rb) - 1.f);
}

// ---------------------- per-graph max pool ----------------------------------
__device__ inline int lower_bound_i(const int* a, int n, int v) {
  int lo = 0, hi = n;
  while (lo < hi) {
    int mid = (lo + hi) >> 1;
    if (a[mid] < v) lo = mid + 1; else hi = mid;
  }
  return lo;
}

__global__ __launch_bounds__(128) void pool_kernel(
    const float* __restrict__ x2, const int* __restrict__ batch,
    float* __restrict__ pool, int n) {
  int g = blockIdx.x;
  int t = threadIdx.x;
  int start = lower_bound_i(batch, n, g);
  int end = lower_bound_i(batch, n, g + 1);
  float m = -FLT_MAX;
  for (int i = start; i < end; i++) m = fmaxf(m, x2[(size_t)i * 128 + t]);
  pool[g * 128 + t] = m;
}

// ---------------------- classifier ------------------------------------------
__global__ __launch_bounds__(64) void classifier_kernel(
    const float* __restrict__ pool, const float* __restrict__ Wc1,
    const float* __restrict__ bc1, const float* __restrict__ Wc2,
    const float* __restrict__ bc2, float* __restrict__ out) {
  int g = blockIdx.x;
  int t = threadIdx.x;
  __shared__ float xp[128];
  __shared__ float hc[64];
  xp[t] = pool[g * 128 + t];
  xp[t + 64] = pool[g * 128 + 64 + t];
  __syncthreads();
  float s = bc1[t];
  for (int k = 0; k < 128; k++) s += xp[k] * Wc1[k * 64 + t];
  hc[t] = s > 0.f ? s : 0.f;
  __syncthreads();
  if (t < 5) {
    float o = bc2[t];
    for (int j = 0; j < 64; j++) o += hc[j] * Wc2[j * 5 + t];
    out[g * 5 + t] = o;
  }
}

// ---------------------------------------------------------------------------
extern "C" void kernel_launch(void* const* d_in, const int* in_sizes, int n_in,
                              void* d_out, int out_size, void* d_ws, size_t ws_size,
                              hipStream_t stream) {
  const float* x_scalar = (const float*)d_in[0];
  const int* x_opcode = (const int*)d_in[1];
  const int* x_source = (const int*)d_in[2];
  const int* x_sink = (const int*)d_in[3];
  const int* x_string = (const int*)d_in[4];
  const int* x_payload = (const int*)d_in[5];
  const int* edge_index = (const int*)d_in[6];
  const int* batch = (const int*)d_in[7];
  const float* emb_opcode = (const float*)d_in[8];
  const float* emb_source = (const float*)d_in[9];
  const float* emb_sink = (const float*)d_in[10];
  const float* emb_string = (const float*)d_in[11];
  const float* emb_payload = (const float*)d_in[12];
  const float* ln_g = (const float*)d_in[13];
  const float* ln_b = (const float*)d_in[14];
  const float* W1 = (const float*)d_in[15];
  const float* att_src1 = (const float*)d_in[16];
  const float* att_dst1 = (const float*)d_in[17];
  const float* b1 = (const float*)d_in[18];
  const float* W2 = (const float*)d_in[19];
  const float* att_src2 = (const float*)d_in[20];
  const float* att_dst2 = (const float*)d_in[21];
  const float* b2 = (const float*)d_in[22];
  const float* Wc1 = (const float*)d_in[23];
  const float* bc1 = (const float*)d_in[24];
  const float* Wc2 = (const float*)d_in[25];
  const float* bc2 = (const float*)d_in[26];
  float* out = (float*)d_out;

  const int N = in_sizes[0] / 96;
  const int E = in_sizes[6] / 2;
  const int G = out_size / 5;

  const int* e_src = edge_index;
  const int* e_dst = edge_index + E;

  // workspace layout
  char* w = (char*)d_ws;
  size_t o = 0;
  auto take = [&](size_t bytes) -> void* {
    void* p = w + o;
    o += (bytes + 255) & ~(size_t)255;
    return p;
  };
  _Float16* feats = (_Float16*)take((size_t)N * 256 * 2);
  _Float16* h1 = (_Float16*)take((size_t)N * 512 * 2);
  _Float16* x1 = (_Float16*)take((size_t)N * 512 * 2);
  _Float16* h2 = (_Float16*)take((size_t)N * 128 * 2);
  float* x2 = (float*)take((size_t)N * 128 * 4);
  _Float16* Wt1 = (_Float16*)take((size_t)512 * 256 * 2);
  _Float16* Wt2 = (_Float16*)take((size_t)128 * 512 * 2);
  float* a_src1 = (float*)take((size_t)N * 4 * 4);
  float* a_dst1 = (float*)take((size_t)N * 4 * 4);
  float* a_src2 = (float*)take((size_t)N * 4);
  float* a_dst2 = (float*)take((size_t)N * 4);
  int* deg = (int*)take((size_t)N * 2 * 4);  // deg + cnt contiguous
  int* cnt = deg + N;
  int* rowptr = (int*)take((size_t)(N + 1) * 4);
  int* csr_src = (int*)take((size_t)(E + N) * 4);
  float* pool = (float*)take((size_t)G * 128 * 4);

  hipMemsetAsync(deg, 0, (size_t)N * 2 * 4, stream);

  // CSR build (independent of features)
  hist_kernel<<<(E + 255) / 256, 256, 0, stream>>>(e_dst, deg, E);
  scan_kernel<<<1, 1024, 0, stream>>>(deg, rowptr, N);
  fill_kernel<<<(E + N + 255) / 256, 256, 0, stream>>>(e_src, e_dst, rowptr, cnt,
                                                       csr_src, E, N);

  // weights -> transposed fp16
  transpose_f16<<<(256 * 512 + 255) / 256, 256, 0, stream>>>(W1, Wt1, 256, 512);
  transpose_f16<<<(512 * 128 + 255) / 256, 256, 0, stream>>>(W2, Wt2, 512, 128);

  // features + LN (fp16 out), wave-per-node
  feats_kernel<<<(N + 3) / 4, 256, 0, stream>>>(
      x_scalar, x_opcode, x_source, x_sink, x_string, x_payload, emb_opcode,
      emb_source, emb_sink, emb_string, emb_payload, ln_g, ln_b, feats, N);

  int mblocks = (N + 127) / 128;
  // conv1: h1 = feats @ W1  (M=N, K=256, N=512)
  gemm_f16<<<dim3(512 / 128, mblocks), 256, 0, stream>>>(feats, Wt1, h1, N, 256, 512);
  att1_kernel<<<(N + 3) / 4, 256, 0, stream>>>(h1, att_src1, att_dst1, a_src1,
                                               a_dst1, N);
  gat1_agg<<<(N + 3) / 4, 256, 0, stream>>>(h1, a_src1, a_dst1, rowptr, csr_src,
                                            b1, x1, N);

  // conv2: h2 = x1 @ W2  (M=N, K=512, N=128)
  gemm_f16<<<dim3(128 / 128, mblocks), 256, 0, stream>>>(x1, Wt2, h2, N, 512, 128);
  att2_kernel<<<(N + 3) / 4, 256, 0, stream>>>(h2, att_src2, att_dst2, a_src2,
                                               a_dst2, N);
  gat2_agg<<<(N + 3) / 4, 256, 0, stream>>>(h2, a_src2, a_dst2, rowptr, csr_src,
                                            b2, x2, N);

  // pool + classifier
  pool_kernel<<<G, 128, 0, stream>>>(x2, batch, pool, N);
  classifier_kernel<<<G, 64, 0, stream>>>(pool, Wc1, bc1, Wc2, bc2, out);
}

// Round 5
// 568.077 us; speedup vs baseline: 2.0000x; 1.1950x over previous
//
#include <hip/hip_runtime.h>
#include <hip/hip_bf16.h>
#include <float.h>

// ---------------------------------------------------------------------------
// GlobalFeatureGAT: feature-build+LN -> GAT(4 heads,128) -> ELU -> GAT(1,128)
// -> ELU -> per-graph max pool -> MLP(128->64->5).
// R5: same as R4 but workspace aliased to fit ws_size — R4 overran d_ws
// (~172.7 MB) and corrupted adjacent device memory, failing post-timing
// validation. Now: h2/partial/pool alias feats (dead after gemm1), x2
// aliases h1 (dead after gat1_agg). Total ~133 MB.
// N=50000, E=500000 (+N self loops), G=64, IN_DIM=256, C=128, H1=4.
// ---------------------------------------------------------------------------

#define LEAKY(e) ((e) > 0.f ? (e) : 0.2f * (e))
#define POOL_CH 32  // chunks per graph in stage-1 pool

typedef _Float16 half8 __attribute__((ext_vector_type(8)));
typedef float floatx4 __attribute__((ext_vector_type(4)));

// ---------------------- feature build + layernorm (fp16 out) ----------------
// One wave per node. Lane l owns channels {l, 64+l, 128+l, 192+l}.
__global__ __launch_bounds__(256) void feats_kernel(
    const float* __restrict__ xs, const int* __restrict__ xo,
    const int* __restrict__ xsrc, const int* __restrict__ xsk,
    const int* __restrict__ xst, const int* __restrict__ xp,
    const float* __restrict__ eo, const float* __restrict__ es,
    const float* __restrict__ ek, const float* __restrict__ et,
    const float* __restrict__ ep, const float* __restrict__ lng,
    const float* __restrict__ lnb, _Float16* __restrict__ feats, int n) {
  int node = blockIdx.x * 4 + (threadIdx.x >> 6);
  if (node >= n) return;
  int l = threadIdx.x & 63;

  int myidx = 0;
  if (l < 16)      myidx = xo[node * 16 + l];
  else if (l < 24) myidx = xsrc[node * 8 + (l - 16)];
  else if (l < 32) myidx = xsk[node * 8 + (l - 24)];
  else if (l < 40) myidx = xst[node * 8 + (l - 32)];
  else if (l < 48) myidx = xp[node * 8 + (l - 40)];

  const float* xrow = xs + (size_t)node * 96;
  float v0 = xrow[l];
  float v1, v2, v3;

  bool hi = (l >= 32);
  int d = l & 31;

  {
    float s = 0.f, c = 0.f;
#pragma unroll
    for (int j = 0; j < 16; j++) {
      int id = __shfl(myidx, j);
      if (hi && id != 0) { s += eo[(size_t)id * 32 + d]; c += 1.f; }
    }
    float sc = hi ? 0.f : xrow[64 + l];
    v1 = hi ? (s / (c + 1e-9f)) : sc;
  }
  {
    const float* tab = hi ? ek : es;
    int base = hi ? 24 : 16;
    float s = 0.f, c = 0.f;
#pragma unroll
    for (int j = 0; j < 8; j++) {
      int id = __shfl(myidx, base + j);
      if (id != 0) { s += tab[(size_t)id * 32 + d]; c += 1.f; }
    }
    v2 = s / (c + 1e-9f);
  }
  {
    const float* tab = hi ? ep : et;
    int base = hi ? 40 : 32;
    float s = 0.f, c = 0.f;
#pragma unroll
    for (int j = 0; j < 8; j++) {
      int id = __shfl(myidx, base + j);
      if (id != 0) { s += tab[(size_t)id * 32 + d]; c += 1.f; }
    }
    v3 = s / (c + 1e-9f);
  }

  float sum = v0 + v1 + v2 + v3;
  for (int o = 32; o; o >>= 1) sum += __shfl_xor(sum, o);
  float mu = sum * (1.f / 256.f);

  float d0 = v0 - mu, d1 = v1 - mu, d2 = v2 - mu, d3 = v3 - mu;
  float q = d0 * d0 + d1 * d1 + d2 * d2 + d3 * d3;
  for (int o = 32; o; o >>= 1) q += __shfl_xor(q, o);
  float rstd = rsqrtf(q * (1.f / 256.f) + 1e-5f);

  _Float16* frow = feats + (size_t)node * 256;
  frow[l]       = (_Float16)(d0 * rstd * lng[l] + lnb[l]);
  frow[64 + l]  = (_Float16)(d1 * rstd * lng[64 + l] + lnb[64 + l]);
  frow[128 + l] = (_Float16)(d2 * rstd * lng[128 + l] + lnb[128 + l]);
  frow[192 + l] = (_Float16)(d3 * rstd * lng[192 + l] + lnb[192 + l]);
}

// ---------------------- weight transpose + fp16 convert ---------------------
__global__ __launch_bounds__(256) void transpose_f16(
    const float* __restrict__ W, _Float16* __restrict__ Wt, int K, int N) {
  int t = blockIdx.x * 256 + threadIdx.x;
  if (t < K * N) {
    int n = t / K, k = t - n * K;
    Wt[t] = (_Float16)W[(size_t)k * N + n];
  }
}

// ---------------------- fp16 MFMA GEMM: C = A @ Bt^T ------------------------
// A: M x K (row-major fp16), Bt: N x K (row-major fp16), C: M x N (fp16).
// 128x128 tile, 4 waves of 64x64, 16x16x32 MFMA, fp32 accum.
__global__ __launch_bounds__(256) void gemm_f16(
    const _Float16* __restrict__ A, const _Float16* __restrict__ Bt,
    _Float16* __restrict__ C, int M, int K, int N) {
  __shared__ _Float16 As[128][40];
  __shared__ _Float16 Bs[128][40];
  int m0 = blockIdx.y * 128;
  int n0 = blockIdx.x * 128;
  int tid = threadIdx.x;
  int wave = tid >> 6, lane = tid & 63;
  int wm = (wave >> 1) * 64, wn = (wave & 1) * 64;
  int lr = lane & 15, lq = lane >> 4;

  int srow = tid >> 1;
  int sseg = (tid & 1) * 16;

  floatx4 acc[4][4] = {};

  for (int k0 = 0; k0 < K; k0 += 32) {
    {
      int gr = m0 + srow;
      float4 v0 = {0.f, 0.f, 0.f, 0.f}, v1 = {0.f, 0.f, 0.f, 0.f};
      if (gr < M) {
        const float4* ap = (const float4*)(A + (size_t)gr * K + k0 + sseg);
        v0 = ap[0];
        v1 = ap[1];
      }
      *(float4*)&As[srow][sseg] = v0;
      *(float4*)&As[srow][sseg + 8] = v1;

      const float4* bp = (const float4*)(Bt + (size_t)(n0 + srow) * K + k0 + sseg);
      *(float4*)&Bs[srow][sseg] = bp[0];
      *(float4*)&Bs[srow][sseg + 8] = bp[1];
    }
    __syncthreads();

    half8 af[4], bf[4];
#pragma unroll
    for (int i = 0; i < 4; i++)
      af[i] = *(const half8*)&As[wm + i * 16 + lr][lq * 8];
#pragma unroll
    for (int j = 0; j < 4; j++)
      bf[j] = *(const half8*)&Bs[wn + j * 16 + lr][lq * 8];
#pragma unroll
    for (int i = 0; i < 4; i++)
#pragma unroll
      for (int j = 0; j < 4; j++)
        acc[i][j] =
            __builtin_amdgcn_mfma_f32_16x16x32_f16(af[i], bf[j], acc[i][j], 0, 0, 0);
    __syncthreads();
  }

#pragma unroll
  for (int i = 0; i < 4; i++) {
    int rbase = m0 + wm + i * 16 + lq * 4;
#pragma unroll
    for (int r = 0; r < 4; r++) {
      int row = rbase + r;
      if (row < M) {
#pragma unroll
        for (int j = 0; j < 4; j++) {
          int col = n0 + wn + j * 16 + lr;
          C[(size_t)row * N + col] = (_Float16)acc[i][j][r];
        }
      }
    }
  }
}

// ---------------------- attention score dots --------------------------------
__global__ __launch_bounds__(256) void att1_kernel(
    const _Float16* __restrict__ h1, const float* __restrict__ as,
    const float* __restrict__ ad, float* __restrict__ osrc,
    float* __restrict__ odst, int n) {
  int node = blockIdx.x * 4 + (threadIdx.x >> 6);
  if (node >= n) return;
  int l = threadIdx.x & 63;
  int hh = l >> 4;
  int cb = (l & 15) * 8;
  const _Float16* hp = h1 + (size_t)node * 512 + l * 8;
  const float* ap = as + hh * 128 + cb;
  const float* dp = ad + hh * 128 + cb;
  float ssum = 0.f, dsum = 0.f;
  half8 hv = *(const half8*)hp;
#pragma unroll
  for (int j = 0; j < 8; j++) {
    float h = (float)hv[j];
    ssum += h * ap[j];
    dsum += h * dp[j];
  }
  for (int o = 1; o < 16; o <<= 1) {
    ssum += __shfl_xor(ssum, o);
    dsum += __shfl_xor(dsum, o);
  }
  if ((l & 15) == 0) {
    osrc[node * 4 + hh] = ssum;
    odst[node * 4 + hh] = dsum;
  }
}

__global__ __launch_bounds__(256) void att2_kernel(
    const _Float16* __restrict__ h2, const float* __restrict__ as,
    const float* __restrict__ ad, float* __restrict__ osrc,
    float* __restrict__ odst, int n) {
  int node = blockIdx.x * 4 + (threadIdx.x >> 6);
  if (node >= n) return;
  int l = threadIdx.x & 63;
  const _Float16* hp = h2 + (size_t)node * 128 + l * 2;
  float h0 = (float)hp[0], h1v = (float)hp[1];
  float s = h0 * as[l * 2] + h1v * as[l * 2 + 1];
  float d = h0 * ad[l * 2] + h1v * ad[l * 2 + 1];
  for (int o = 1; o < 64; o <<= 1) {
    s += __shfl_xor(s, o);
    d += __shfl_xor(d, o);
  }
  if (l == 0) { osrc[node] = s; odst[node] = d; }
}

// ---------------------- CSR build -------------------------------------------
__global__ __launch_bounds__(256) void hist_kernel(const int* __restrict__ dst,
                                                   int* __restrict__ deg, int E) {
  int t = blockIdx.x * 256 + threadIdx.x;
  if (t < E) atomicAdd(&deg[dst[t]], 1);
}

__global__ __launch_bounds__(1024) void scan_kernel(const int* __restrict__ deg,
                                                    int* __restrict__ rowptr, int n) {
  __shared__ int part[1024];
  int t = threadIdx.x;
  int chunk = (n + 1023) / 1024;
  int s = t * chunk;
  int e = min(s + chunk, n);
  int sum = 0;
  for (int i = s; i < e; i++) sum += deg[i] + 1;
  part[t] = sum;
  __syncthreads();
  for (int off = 1; off < 1024; off <<= 1) {
    int v = (t >= off) ? part[t - off] : 0;
    __syncthreads();
    part[t] += v;
    __syncthreads();
  }
  int run = part[t] - sum;  // exclusive prefix
  for (int i = s; i < e; i++) {
    rowptr[i] = run;
    run += deg[i] + 1;
  }
  if (e == n && s < n) rowptr[n] = run;
}

__global__ __launch_bounds__(256) void fill_kernel(
    const int* __restrict__ src, const int* __restrict__ dst,
    const int* __restrict__ rowptr, int* __restrict__ cnt,
    int* __restrict__ csr_src, int E, int n) {
  int t = blockIdx.x * 256 + threadIdx.x;
  if (t < E) {
    int d = dst[t];
    int pos = rowptr[d] + atomicAdd(&cnt[d], 1);
    csr_src[pos] = src[t];
  } else if (t < E + n) {
    int i = t - E;
    csr_src[rowptr[i + 1] - 1] = i;  // self loop in the last slot
  }
}

// ---------------------- GAT aggregation (conv1: 4 heads x 128) --------------
__global__ __launch_bounds__(256) void gat1_agg(
    const _Float16* __restrict__ h1, const float* __restrict__ asrc,
    const float* __restrict__ adst, const int* __restrict__ rowptr,
    const int* __restrict__ csr_src, const float* __restrict__ bias,
    _Float16* __restrict__ out, int n) {
  int node = blockIdx.x * 4 + (threadIdx.x >> 6);
  if (node >= n) return;
  int l = threadIdx.x & 63;
  int r0 = rowptr[node];
  int deg = rowptr[node + 1] - r0;
  float4 ad4 = *(const float4*)(adst + node * 4);
  float adv[4] = {ad4.x, ad4.y, ad4.z, ad4.w};

  float m[4] = {-1e30f, -1e30f, -1e30f, -1e30f};
  for (int k = l; k < deg; k += 64) {
    int s = csr_src[r0 + k];
    float4 av = *(const float4*)(asrc + (size_t)s * 4);
    float e;
    e = LEAKY(av.x + adv[0]); m[0] = fmaxf(m[0], e);
    e = LEAKY(av.y + adv[1]); m[1] = fmaxf(m[1], e);
    e = LEAKY(av.z + adv[2]); m[2] = fmaxf(m[2], e);
    e = LEAKY(av.w + adv[3]); m[3] = fmaxf(m[3], e);
  }
  for (int o = 1; o < 64; o <<= 1) {
#pragma unroll
    for (int h = 0; h < 4; h++) m[h] = fmaxf(m[h], __shfl_xor(m[h], o));
  }

  float sum[4] = {0.f, 0.f, 0.f, 0.f};
  for (int k = l; k < deg; k += 64) {
    int s = csr_src[r0 + k];
    float4 av = *(const float4*)(asrc + (size_t)s * 4);
    float e;
    e = LEAKY(av.x + adv[0]); sum[0] += __expf(e - m[0]);
    e = LEAKY(av.y + adv[1]); sum[1] += __expf(e - m[1]);
    e = LEAKY(av.z + adv[2]); sum[2] += __expf(e - m[2]);
    e = LEAKY(av.w + adv[3]); sum[3] += __expf(e - m[3]);
  }
  for (int o = 1; o < 64; o <<= 1) {
#pragma unroll
    for (int h = 0; h < 4; h++) sum[h] += __shfl_xor(sum[h], o);
  }

  int hh = l >> 4;
  int cb = l * 8;
  float mm = m[hh];
  float sinv = 1.f / (sum[hh] + 1e-16f);
  float adm = adv[hh];

  float acc[8] = {};
  for (int k = 0; k < deg; k++) {
    int s = csr_src[r0 + k];
    float a = asrc[(size_t)s * 4 + hh];
    float e = LEAKY(a + adm);
    float w = __expf(e - mm) * sinv;
    const half8 hv = *(const half8*)(h1 + (size_t)s * 512 + cb);
#pragma unroll
    for (int j = 0; j < 8; j++) acc[j] += w * (float)hv[j];
  }

  const float* bp = bias + cb;
  half8 ov;
#pragma unroll
  for (int j = 0; j < 8; j++) {
    float r = acc[j] + bp[j];
    ov[j] = (_Float16)(r > 0.f ? r : (__expf(r) - 1.f));  // ELU
  }
  *(half8*)(out + (size_t)node * 512 + cb) = ov;
}

// ---------------------- GAT aggregation (conv2: 1 head x 128) ---------------
__global__ __launch_bounds__(256) void gat2_agg(
    const _Float16* __restrict__ h2, const float* __restrict__ asrc,
    const float* __restrict__ adst, const int* __restrict__ rowptr,
    const int* __restrict__ csr_src, const float* __restrict__ bias,
    float* __restrict__ out, int n) {
  int node = blockIdx.x * 4 + (threadIdx.x >> 6);
  if (node >= n) return;
  int l = threadIdx.x & 63;
  int r0 = rowptr[node];
  int deg = rowptr[node + 1] - r0;
  float ad = adst[node];

  float m = -1e30f;
  for (int k = l; k < deg; k += 64) {
    int s = csr_src[r0 + k];
    float e = LEAKY(asrc[s] + ad);
    m = fmaxf(m, e);
  }
  for (int o = 1; o < 64; o <<= 1) m = fmaxf(m, __shfl_xor(m, o));

  float sum = 0.f;
  for (int k = l; k < deg; k += 64) {
    int s = csr_src[r0 + k];
    float e = LEAKY(asrc[s] + ad);
    sum += __expf(e - m);
  }
  for (int o = 1; o < 64; o <<= 1) sum += __shfl_xor(sum, o);
  float sinv = 1.f / (sum + 1e-16f);

  int cb = l * 2;
  float a0 = 0.f, a1 = 0.f;
  for (int k = 0; k < deg; k++) {
    int s = csr_src[r0 + k];
    float e = LEAKY(asrc[s] + ad);
    float w = __expf(e - m) * sinv;
    const _Float16* hp = h2 + (size_t)s * 128 + cb;
    a0 += w * (float)hp[0];
    a1 += w * (float)hp[1];
  }
  float ra = a0 + bias[cb];
  float rb = a1 + bias[cb + 1];
  out[(size_t)node * 128 + cb]     = ra > 0.f ? ra : (__expf(ra) - 1.f);
  out[(size_t)node * 128 + cb + 1] = rb > 0.f ? rb : (__expf(rb) - 1.f);
}

// ---------------------- per-graph max pool (2-stage) ------------------------
__device__ inline int lower_bound_i(const int* a, int n, int v) {
  int lo = 0, hi = n;
  while (lo < hi) {
    int mid = (lo + hi) >> 1;
    if (a[mid] < v) lo = mid + 1; else hi = mid;
  }
  return lo;
}

// stage 1: grid (POOL_CH, G); block g,j reduces chunk j of graph g's range
__global__ __launch_bounds__(128) void pool_partial(
    const float* __restrict__ x2, const int* __restrict__ batch,
    float* __restrict__ partial, int n) {
  int g = blockIdx.y;
  int j = blockIdx.x;
  int t = threadIdx.x;
  int start = lower_bound_i(batch, n, g);
  int end = lower_bound_i(batch, n, g + 1);
  int len = end - start;
  int c0 = start + (int)((long long)len * j / POOL_CH);
  int c1 = start + (int)((long long)len * (j + 1) / POOL_CH);
  float m = -FLT_MAX;
  for (int i = c0; i < c1; i++) m = fmaxf(m, x2[(size_t)i * 128 + t]);
  partial[((size_t)g * POOL_CH + j) * 128 + t] = m;
}

// stage 2: one block per graph
__global__ __launch_bounds__(128) void pool_final(
    const float* __restrict__ partial, float* __restrict__ pool) {
  int g = blockIdx.x;
  int t = threadIdx.x;
  float m = -FLT_MAX;
#pragma unroll
  for (int j = 0; j < POOL_CH; j++)
    m = fmaxf(m, partial[((size_t)g * POOL_CH + j) * 128 + t]);
  pool[g * 128 + t] = m;
}

// ---------------------- classifier ------------------------------------------
__global__ __launch_bounds__(64) void classifier_kernel(
    const float* __restrict__ pool, const float* __restrict__ Wc1,
    const float* __restrict__ bc1, const float* __restrict__ Wc2,
    const float* __restrict__ bc2, float* __restrict__ out) {
  int g = blockIdx.x;
  int t = threadIdx.x;
  __shared__ float xp[128];
  __shared__ float hc[64];
  xp[t] = pool[g * 128 + t];
  xp[t + 64] = pool[g * 128 + 64 + t];
  __syncthreads();
  float s = bc1[t];
  for (int k = 0; k < 128; k++) s += xp[k] * Wc1[k * 64 + t];
  hc[t] = s > 0.f ? s : 0.f;
  __syncthreads();
  if (t < 5) {
    float o = bc2[t];
    for (int j = 0; j < 64; j++) o += hc[j] * Wc2[j * 5 + t];
    out[g * 5 + t] = o;
  }
}

// ---------------------------------------------------------------------------
extern "C" void kernel_launch(void* const* d_in, const int* in_sizes, int n_in,
                              void* d_out, int out_size, void* d_ws, size_t ws_size,
                              hipStream_t stream) {
  const float* x_scalar = (const float*)d_in[0];
  const int* x_opcode = (const int*)d_in[1];
  const int* x_source = (const int*)d_in[2];
  const int* x_sink = (const int*)d_in[3];
  const int* x_string = (const int*)d_in[4];
  const int* x_payload = (const int*)d_in[5];
  const int* edge_index = (const int*)d_in[6];
  const int* batch = (const int*)d_in[7];
  const float* emb_opcode = (const float*)d_in[8];
  const float* emb_source = (const float*)d_in[9];
  const float* emb_sink = (const float*)d_in[10];
  const float* emb_string = (const float*)d_in[11];
  const float* emb_payload = (const float*)d_in[12];
  const float* ln_g = (const float*)d_in[13];
  const float* ln_b = (const float*)d_in[14];
  const float* W1 = (const float*)d_in[15];
  const float* att_src1 = (const float*)d_in[16];
  const float* att_dst1 = (const float*)d_in[17];
  const float* b1 = (const float*)d_in[18];
  const float* W2 = (const float*)d_in[19];
  const float* att_src2 = (const float*)d_in[20];
  const float* att_dst2 = (const float*)d_in[21];
  const float* b2 = (const float*)d_in[22];
  const float* Wc1 = (const float*)d_in[23];
  const float* bc1 = (const float*)d_in[24];
  const float* Wc2 = (const float*)d_in[25];
  const float* bc2 = (const float*)d_in[26];
  float* out = (float*)d_out;

  const int N = in_sizes[0] / 96;
  const int E = in_sizes[6] / 2;
  const int G = out_size / 5;

  const int* e_src = edge_index;
  const int* e_dst = edge_index + E;

  // ---- workspace layout with aliasing (lifetime-checked) ----
  // Region A (N*256*2 B): feats [live: feats_kernel -> gemm1]
  //   then reused: h2 (N*128*2) at offset 0 [gemm2 -> gat2_agg],
  //                partial (G*POOL_CH*128*4) after h2,
  //                pool (G*128*4) after partial.
  // Region B (N*512*2 B): h1 [gemm1 -> gat1_agg]
  //   then reused: x2 (N*128*4) at offset 0 [gat2_agg -> pool_partial].
  char* w = (char*)d_ws;
  size_t o = 0;
  auto take = [&](size_t bytes) -> void* {
    void* p = w + o;
    o += (bytes + 255) & ~(size_t)255;
    return p;
  };
  char* regionA = (char*)take((size_t)N * 256 * 2);
  char* regionB = (char*)take((size_t)N * 512 * 2);
  _Float16* x1 = (_Float16*)take((size_t)N * 512 * 2);
  _Float16* Wt1 = (_Float16*)take((size_t)512 * 256 * 2);
  _Float16* Wt2 = (_Float16*)take((size_t)128 * 512 * 2);
  float* a_src1 = (float*)take((size_t)N * 4 * 4);
  float* a_dst1 = (float*)take((size_t)N * 4 * 4);
  float* a_src2 = (float*)take((size_t)N * 4);
  float* a_dst2 = (float*)take((size_t)N * 4);
  int* deg = (int*)take((size_t)N * 2 * 4);  // deg + cnt contiguous
  int* cnt = deg + N;
  int* rowptr = (int*)take((size_t)(N + 1) * 4);
  int* csr_src = (int*)take((size_t)(E + N) * 4);
  // total ~133 MB (R4's 172.7 MB overran ws_size)

  _Float16* feats = (_Float16*)regionA;
  _Float16* h2 = (_Float16*)regionA;  // feats dead after gemm1
  float* partial = (float*)(regionA + ((size_t)N * 128 * 2 + 255 & ~(size_t)255));
  float* pool = partial + (size_t)G * POOL_CH * 128;
  _Float16* h1 = (_Float16*)regionB;
  float* x2 = (float*)regionB;        // h1 dead after gat1_agg

  hipMemsetAsync(deg, 0, (size_t)N * 2 * 4, stream);

  // CSR build (independent of features)
  hist_kernel<<<(E + 255) / 256, 256, 0, stream>>>(e_dst, deg, E);
  scan_kernel<<<1, 1024, 0, stream>>>(deg, rowptr, N);
  fill_kernel<<<(E + N + 255) / 256, 256, 0, stream>>>(e_src, e_dst, rowptr, cnt,
                                                       csr_src, E, N);

  // weights -> transposed fp16
  transpose_f16<<<(256 * 512 + 255) / 256, 256, 0, stream>>>(W1, Wt1, 256, 512);
  transpose_f16<<<(512 * 128 + 255) / 256, 256, 0, stream>>>(W2, Wt2, 512, 128);

  // features + LN (fp16 out), wave-per-node
  feats_kernel<<<(N + 3) / 4, 256, 0, stream>>>(
      x_scalar, x_opcode, x_source, x_sink, x_string, x_payload, emb_opcode,
      emb_source, emb_sink, emb_string, emb_payload, ln_g, ln_b, feats, N);

  int mblocks = (N + 127) / 128;
  // conv1: h1 = feats @ W1  (M=N, K=256, N=512)
  gemm_f16<<<dim3(512 / 128, mblocks), 256, 0, stream>>>(feats, Wt1, h1, N, 256, 512);
  att1_kernel<<<(N + 3) / 4, 256, 0, stream>>>(h1, att_src1, att_dst1, a_src1,
                                               a_dst1, N);
  gat1_agg<<<(N + 3) / 4, 256, 0, stream>>>(h1, a_src1, a_dst1, rowptr, csr_src,
                                            b1, x1, N);

  // conv2: h2 = x1 @ W2  (M=N, K=512, N=128) — h2 overwrites feats (dead)
  gemm_f16<<<dim3(128 / 128, mblocks), 256, 0, stream>>>(x1, Wt2, h2, N, 512, 128);
  att2_kernel<<<(N + 3) / 4, 256, 0, stream>>>(h2, att_src2, att_dst2, a_src2,
                                               a_dst2, N);
  // x2 overwrites h1 (dead after gat1_agg)
  gat2_agg<<<(N + 3) / 4, 256, 0, stream>>>(h2, a_src2, a_dst2, rowptr, csr_src,
                                            b2, x2, N);

  // pool (2-stage) + classifier
  pool_partial<<<dim3(POOL_CH, G), 128, 0, stream>>>(x2, batch, partial, N);
  pool_final<<<G, 128, 0, stream>>>(partial, pool);
  classifier_kernel<<<G, 64, 0, stream>>>(pool, Wc1, bc1, Wc2, bc2, out);
}

// Round 6
// 528.114 us; speedup vs baseline: 2.1514x; 1.0757x over previous
//
#include <hip/hip_runtime.h>
#include <hip/hip_bf16.h>
#include <float.h>

// ---------------------------------------------------------------------------
// GlobalFeatureGAT: feature-build+LN -> GAT(4 heads,128) -> ELU -> GAT(1,128)
// -> ELU -> per-graph max pool -> MLP(128->64->5).
// R6: gat1_agg/gat2_agg restructured — register-cached softmax (deg<=64 fast
// path), head = 16-lane group in gat1 (8 shfls vs 96), gather uses
// shfl-broadcast precomputed weights (no exp/asrc reload per edge).
// Workspace aliasing from R5 (fits ws_size; R4 overran and corrupted inputs).
// N=50000, E=500000 (+N self loops), G=64, IN_DIM=256, C=128, H1=4.
// ---------------------------------------------------------------------------

#define LEAKY(e) ((e) > 0.f ? (e) : 0.2f * (e))
#define POOL_CH 32  // chunks per graph in stage-1 pool

typedef _Float16 half8 __attribute__((ext_vector_type(8)));
typedef float floatx4 __attribute__((ext_vector_type(4)));

// ---------------------- feature build + layernorm (fp16 out) ----------------
// One wave per node. Lane l owns channels {l, 64+l, 128+l, 192+l}.
__global__ __launch_bounds__(256) void feats_kernel(
    const float* __restrict__ xs, const int* __restrict__ xo,
    const int* __restrict__ xsrc, const int* __restrict__ xsk,
    const int* __restrict__ xst, const int* __restrict__ xp,
    const float* __restrict__ eo, const float* __restrict__ es,
    const float* __restrict__ ek, const float* __restrict__ et,
    const float* __restrict__ ep, const float* __restrict__ lng,
    const float* __restrict__ lnb, _Float16* __restrict__ feats, int n) {
  int node = blockIdx.x * 4 + (threadIdx.x >> 6);
  if (node >= n) return;
  int l = threadIdx.x & 63;

  int myidx = 0;
  if (l < 16)      myidx = xo[node * 16 + l];
  else if (l < 24) myidx = xsrc[node * 8 + (l - 16)];
  else if (l < 32) myidx = xsk[node * 8 + (l - 24)];
  else if (l < 40) myidx = xst[node * 8 + (l - 32)];
  else if (l < 48) myidx = xp[node * 8 + (l - 40)];

  const float* xrow = xs + (size_t)node * 96;
  float v0 = xrow[l];
  float v1, v2, v3;

  bool hi = (l >= 32);
  int d = l & 31;

  {
    float s = 0.f, c = 0.f;
#pragma unroll
    for (int j = 0; j < 16; j++) {
      int id = __shfl(myidx, j);
      if (hi && id != 0) { s += eo[(size_t)id * 32 + d]; c += 1.f; }
    }
    float sc = hi ? 0.f : xrow[64 + l];
    v1 = hi ? (s / (c + 1e-9f)) : sc;
  }
  {
    const float* tab = hi ? ek : es;
    int base = hi ? 24 : 16;
    float s = 0.f, c = 0.f;
#pragma unroll
    for (int j = 0; j < 8; j++) {
      int id = __shfl(myidx, base + j);
      if (id != 0) { s += tab[(size_t)id * 32 + d]; c += 1.f; }
    }
    v2 = s / (c + 1e-9f);
  }
  {
    const float* tab = hi ? ep : et;
    int base = hi ? 40 : 32;
    float s = 0.f, c = 0.f;
#pragma unroll
    for (int j = 0; j < 8; j++) {
      int id = __shfl(myidx, base + j);
      if (id != 0) { s += tab[(size_t)id * 32 + d]; c += 1.f; }
    }
    v3 = s / (c + 1e-9f);
  }

  float sum = v0 + v1 + v2 + v3;
  for (int o = 32; o; o >>= 1) sum += __shfl_xor(sum, o);
  float mu = sum * (1.f / 256.f);

  float d0 = v0 - mu, d1 = v1 - mu, d2 = v2 - mu, d3 = v3 - mu;
  float q = d0 * d0 + d1 * d1 + d2 * d2 + d3 * d3;
  for (int o = 32; o; o >>= 1) q += __shfl_xor(q, o);
  float rstd = rsqrtf(q * (1.f / 256.f) + 1e-5f);

  _Float16* frow = feats + (size_t)node * 256;
  frow[l]       = (_Float16)(d0 * rstd * lng[l] + lnb[l]);
  frow[64 + l]  = (_Float16)(d1 * rstd * lng[64 + l] + lnb[64 + l]);
  frow[128 + l] = (_Float16)(d2 * rstd * lng[128 + l] + lnb[128 + l]);
  frow[192 + l] = (_Float16)(d3 * rstd * lng[192 + l] + lnb[192 + l]);
}

// ---------------------- weight transpose + fp16 convert ---------------------
__global__ __launch_bounds__(256) void transpose_f16(
    const float* __restrict__ W, _Float16* __restrict__ Wt, int K, int N) {
  int t = blockIdx.x * 256 + threadIdx.x;
  if (t < K * N) {
    int n = t / K, k = t - n * K;
    Wt[t] = (_Float16)W[(size_t)k * N + n];
  }
}

// ---------------------- fp16 MFMA GEMM: C = A @ Bt^T ------------------------
// A: M x K (row-major fp16), Bt: N x K (row-major fp16), C: M x N (fp16).
// 128x128 tile, 4 waves of 64x64, 16x16x32 MFMA, fp32 accum.
__global__ __launch_bounds__(256) void gemm_f16(
    const _Float16* __restrict__ A, const _Float16* __restrict__ Bt,
    _Float16* __restrict__ C, int M, int K, int N) {
  __shared__ _Float16 As[128][40];
  __shared__ _Float16 Bs[128][40];
  int m0 = blockIdx.y * 128;
  int n0 = blockIdx.x * 128;
  int tid = threadIdx.x;
  int wave = tid >> 6, lane = tid & 63;
  int wm = (wave >> 1) * 64, wn = (wave & 1) * 64;
  int lr = lane & 15, lq = lane >> 4;

  int srow = tid >> 1;
  int sseg = (tid & 1) * 16;

  floatx4 acc[4][4] = {};

  for (int k0 = 0; k0 < K; k0 += 32) {
    {
      int gr = m0 + srow;
      float4 v0 = {0.f, 0.f, 0.f, 0.f}, v1 = {0.f, 0.f, 0.f, 0.f};
      if (gr < M) {
        const float4* ap = (const float4*)(A + (size_t)gr * K + k0 + sseg);
        v0 = ap[0];
        v1 = ap[1];
      }
      *(float4*)&As[srow][sseg] = v0;
      *(float4*)&As[srow][sseg + 8] = v1;

      const float4* bp = (const float4*)(Bt + (size_t)(n0 + srow) * K + k0 + sseg);
      *(float4*)&Bs[srow][sseg] = bp[0];
      *(float4*)&Bs[srow][sseg + 8] = bp[1];
    }
    __syncthreads();

    half8 af[4], bf[4];
#pragma unroll
    for (int i = 0; i < 4; i++)
      af[i] = *(const half8*)&As[wm + i * 16 + lr][lq * 8];
#pragma unroll
    for (int j = 0; j < 4; j++)
      bf[j] = *(const half8*)&Bs[wn + j * 16 + lr][lq * 8];
#pragma unroll
    for (int i = 0; i < 4; i++)
#pragma unroll
      for (int j = 0; j < 4; j++)
        acc[i][j] =
            __builtin_amdgcn_mfma_f32_16x16x32_f16(af[i], bf[j], acc[i][j], 0, 0, 0);
    __syncthreads();
  }

#pragma unroll
  for (int i = 0; i < 4; i++) {
    int rbase = m0 + wm + i * 16 + lq * 4;
#pragma unroll
    for (int r = 0; r < 4; r++) {
      int row = rbase + r;
      if (row < M) {
#pragma unroll
        for (int j = 0; j < 4; j++) {
          int col = n0 + wn + j * 16 + lr;
          C[(size_t)row * N + col] = (_Float16)acc[i][j][r];
        }
      }
    }
  }
}

// ---------------------- attention score dots --------------------------------
__global__ __launch_bounds__(256) void att1_kernel(
    const _Float16* __restrict__ h1, const float* __restrict__ as,
    const float* __restrict__ ad, float* __restrict__ osrc,
    float* __restrict__ odst, int n) {
  int node = blockIdx.x * 4 + (threadIdx.x >> 6);
  if (node >= n) return;
  int l = threadIdx.x & 63;
  int hh = l >> 4;
  int cb = (l & 15) * 8;
  const _Float16* hp = h1 + (size_t)node * 512 + l * 8;
  const float* ap = as + hh * 128 + cb;
  const float* dp = ad + hh * 128 + cb;
  float ssum = 0.f, dsum = 0.f;
  half8 hv = *(const half8*)hp;
#pragma unroll
  for (int j = 0; j < 8; j++) {
    float h = (float)hv[j];
    ssum += h * ap[j];
    dsum += h * dp[j];
  }
  for (int o = 1; o < 16; o <<= 1) {
    ssum += __shfl_xor(ssum, o);
    dsum += __shfl_xor(dsum, o);
  }
  if ((l & 15) == 0) {
    osrc[node * 4 + hh] = ssum;
    odst[node * 4 + hh] = dsum;
  }
}

__global__ __launch_bounds__(256) void att2_kernel(
    const _Float16* __restrict__ h2, const float* __restrict__ as,
    const float* __restrict__ ad, float* __restrict__ osrc,
    float* __restrict__ odst, int n) {
  int node = blockIdx.x * 4 + (threadIdx.x >> 6);
  if (node >= n) return;
  int l = threadIdx.x & 63;
  const _Float16* hp = h2 + (size_t)node * 128 + l * 2;
  float h0 = (float)hp[0], h1v = (float)hp[1];
  float s = h0 * as[l * 2] + h1v * as[l * 2 + 1];
  float d = h0 * ad[l * 2] + h1v * ad[l * 2 + 1];
  for (int o = 1; o < 64; o <<= 1) {
    s += __shfl_xor(s, o);
    d += __shfl_xor(d, o);
  }
  if (l == 0) { osrc[node] = s; odst[node] = d; }
}

// ---------------------- CSR build -------------------------------------------
__global__ __launch_bounds__(256) void hist_kernel(const int* __restrict__ dst,
                                                   int* __restrict__ deg, int E) {
  int t = blockIdx.x * 256 + threadIdx.x;
  if (t < E) atomicAdd(&deg[dst[t]], 1);
}

__global__ __launch_bounds__(1024) void scan_kernel(const int* __restrict__ deg,
                                                    int* __restrict__ rowptr, int n) {
  __shared__ int part[1024];
  int t = threadIdx.x;
  int chunk = (n + 1023) / 1024;
  int s = t * chunk;
  int e = min(s + chunk, n);
  int sum = 0;
  for (int i = s; i < e; i++) sum += deg[i] + 1;
  part[t] = sum;
  __syncthreads();
  for (int off = 1; off < 1024; off <<= 1) {
    int v = (t >= off) ? part[t - off] : 0;
    __syncthreads();
    part[t] += v;
    __syncthreads();
  }
  int run = part[t] - sum;  // exclusive prefix
  for (int i = s; i < e; i++) {
    rowptr[i] = run;
    run += deg[i] + 1;
  }
  if (e == n && s < n) rowptr[n] = run;
}

__global__ __launch_bounds__(256) void fill_kernel(
    const int* __restrict__ src, const int* __restrict__ dst,
    const int* __restrict__ rowptr, int* __restrict__ cnt,
    int* __restrict__ csr_src, int E, int n) {
  int t = blockIdx.x * 256 + threadIdx.x;
  if (t < E) {
    int d = dst[t];
    int pos = rowptr[d] + atomicAdd(&cnt[d], 1);
    csr_src[pos] = src[t];
  } else if (t < E + n) {
    int i = t - E;
    csr_src[rowptr[i + 1] - 1] = i;  // self loop in the last slot
  }
}

// ---------------------- GAT aggregation (conv1: 4 heads x 128) --------------
// Wave per node. head = 16-lane group (hh=l>>4, li=l&15).
// Fast path deg<=64: edges cached in 4 reg chunks; softmax reduced over 16
// lanes; gather broadcasts (s,w) via shfl — no exp/asrc reload per edge.
__global__ __launch_bounds__(256) void gat1_agg(
    const _Float16* __restrict__ h1, const float* __restrict__ asrc,
    const float* __restrict__ adst, const int* __restrict__ rowptr,
    const int* __restrict__ csr_src, const float* __restrict__ bias,
    _Float16* __restrict__ out, int n) {
  int node = blockIdx.x * 4 + (threadIdx.x >> 6);
  if (node >= n) return;
  int l = threadIdx.x & 63;
  int hh = l >> 4;
  int li = l & 15;
  int r0 = rowptr[node];
  int deg = rowptr[node + 1] - r0;
  int cb = l * 8;

  float acc[8] = {};

  if (deg <= 64) {
    float adm = adst[node * 4 + hh];
    int s_reg[4];
    float ww[4];
    float m = -1e30f;
#pragma unroll
    for (int c = 0; c < 4; c++) {
      int k = c * 16 + li;
      int s = (k < deg) ? csr_src[r0 + k] : -1;
      s_reg[c] = s;
      float e = -1e30f;
      if (s >= 0) {
        float t = asrc[(size_t)s * 4 + hh] + adm;
        e = LEAKY(t);
      }
      ww[c] = e;
      m = fmaxf(m, e);
    }
#pragma unroll
    for (int o = 1; o < 16; o <<= 1) m = fmaxf(m, __shfl_xor(m, o));
    float sum = 0.f;
#pragma unroll
    for (int c = 0; c < 4; c++) {
      float w = (s_reg[c] >= 0) ? __expf(ww[c] - m) : 0.f;
      ww[c] = w;
      sum += w;
    }
#pragma unroll
    for (int o = 1; o < 16; o <<= 1) sum += __shfl_xor(sum, o);
    float sinv = 1.f / (sum + 1e-16f);
#pragma unroll
    for (int c = 0; c < 4; c++) ww[c] *= sinv;

#pragma unroll
    for (int c = 0; c < 4; c++) {
      int base = c * 16;
      if (base >= deg) break;
      int lim = min(16, deg - base);
      for (int jl = 0; jl < lim; jl++) {
        int s = __shfl(s_reg[c], jl);
        float w = __shfl(ww[c], hh * 16 + jl);
        const half8 hv = *(const half8*)(h1 + (size_t)s * 512 + cb);
#pragma unroll
        for (int q = 0; q < 8; q++) acc[q] += w * (float)hv[q];
      }
    }
  } else {
    // fallback (deg>64, rare): original 3-pass
    float4 ad4 = *(const float4*)(adst + node * 4);
    float adv[4] = {ad4.x, ad4.y, ad4.z, ad4.w};
    float m[4] = {-1e30f, -1e30f, -1e30f, -1e30f};
    for (int k = l; k < deg; k += 64) {
      int s = csr_src[r0 + k];
      float4 av = *(const float4*)(asrc + (size_t)s * 4);
      float e;
      e = LEAKY(av.x + adv[0]); m[0] = fmaxf(m[0], e);
      e = LEAKY(av.y + adv[1]); m[1] = fmaxf(m[1], e);
      e = LEAKY(av.z + adv[2]); m[2] = fmaxf(m[2], e);
      e = LEAKY(av.w + adv[3]); m[3] = fmaxf(m[3], e);
    }
    for (int o = 1; o < 64; o <<= 1) {
#pragma unroll
      for (int h = 0; h < 4; h++) m[h] = fmaxf(m[h], __shfl_xor(m[h], o));
    }
    float sum[4] = {0.f, 0.f, 0.f, 0.f};
    for (int k = l; k < deg; k += 64) {
      int s = csr_src[r0 + k];
      float4 av = *(const float4*)(asrc + (size_t)s * 4);
      float e;
      e = LEAKY(av.x + adv[0]); sum[0] += __expf(e - m[0]);
      e = LEAKY(av.y + adv[1]); sum[1] += __expf(e - m[1]);
      e = LEAKY(av.z + adv[2]); sum[2] += __expf(e - m[2]);
      e = LEAKY(av.w + adv[3]); sum[3] += __expf(e - m[3]);
    }
    for (int o = 1; o < 64; o <<= 1) {
#pragma unroll
      for (int h = 0; h < 4; h++) sum[h] += __shfl_xor(sum[h], o);
    }
    float mm = m[hh];
    float sinv = 1.f / (sum[hh] + 1e-16f);
    float adm = adv[hh];
    for (int k = 0; k < deg; k++) {
      int s = csr_src[r0 + k];
      float a = asrc[(size_t)s * 4 + hh];
      float e = LEAKY(a + adm);
      float w = __expf(e - mm) * sinv;
      const half8 hv = *(const half8*)(h1 + (size_t)s * 512 + cb);
#pragma unroll
      for (int q = 0; q < 8; q++) acc[q] += w * (float)hv[q];
    }
  }

  const float* bp = bias + cb;
  half8 ov;
#pragma unroll
  for (int j = 0; j < 8; j++) {
    float r = acc[j] + bp[j];
    ov[j] = (_Float16)(r > 0.f ? r : (__expf(r) - 1.f));  // ELU
  }
  *(half8*)(out + (size_t)node * 512 + cb) = ov;
}

// ---------------------- GAT aggregation (conv2: 1 head x 128) ---------------
__global__ __launch_bounds__(256) void gat2_agg(
    const _Float16* __restrict__ h2, const float* __restrict__ asrc,
    const float* __restrict__ adst, const int* __restrict__ rowptr,
    const int* __restrict__ csr_src, const float* __restrict__ bias,
    float* __restrict__ out, int n) {
  int node = blockIdx.x * 4 + (threadIdx.x >> 6);
  if (node >= n) return;
  int l = threadIdx.x & 63;
  int r0 = rowptr[node];
  int deg = rowptr[node + 1] - r0;
  int cb = l * 2;
  float a0 = 0.f, a1 = 0.f;

  if (deg <= 64) {
    float ad = adst[node];
    int s = (l < deg) ? csr_src[r0 + l] : -1;
    float e = -1e30f;
    if (s >= 0) {
      float t = asrc[s] + ad;
      e = LEAKY(t);
    }
    float m = e;
    for (int o = 1; o < 64; o <<= 1) m = fmaxf(m, __shfl_xor(m, o));
    float w = (s >= 0) ? __expf(e - m) : 0.f;
    float sum = w;
    for (int o = 1; o < 64; o <<= 1) sum += __shfl_xor(sum, o);
    w *= 1.f / (sum + 1e-16f);
    for (int j = 0; j < deg; j++) {
      int sj = __shfl(s, j);
      float wj = __shfl(w, j);
      const _Float16* hp = h2 + (size_t)sj * 128 + cb;
      a0 += wj * (float)hp[0];
      a1 += wj * (float)hp[1];
    }
  } else {
    float ad = adst[node];
    float m = -1e30f;
    for (int k = l; k < deg; k += 64) {
      int s = csr_src[r0 + k];
      float e = LEAKY(asrc[s] + ad);
      m = fmaxf(m, e);
    }
    for (int o = 1; o < 64; o <<= 1) m = fmaxf(m, __shfl_xor(m, o));
    float sum = 0.f;
    for (int k = l; k < deg; k += 64) {
      int s = csr_src[r0 + k];
      float e = LEAKY(asrc[s] + ad);
      sum += __expf(e - m);
    }
    for (int o = 1; o < 64; o <<= 1) sum += __shfl_xor(sum, o);
    float sinv = 1.f / (sum + 1e-16f);
    for (int k = 0; k < deg; k++) {
      int s = csr_src[r0 + k];
      float e = LEAKY(asrc[s] + ad);
      float w = __expf(e - m) * sinv;
      const _Float16* hp = h2 + (size_t)s * 128 + cb;
      a0 += w * (float)hp[0];
      a1 += w * (float)hp[1];
    }
  }

  float ra = a0 + bias[cb];
  float rb = a1 + bias[cb + 1];
  out[(size_t)node * 128 + cb]     = ra > 0.f ? ra : (__expf(ra) - 1.f);
  out[(size_t)node * 128 + cb + 1] = rb > 0.f ? rb : (__expf(rb) - 1.f);
}

// ---------------------- per-graph max pool (2-stage) ------------------------
__device__ inline int lower_bound_i(const int* a, int n, int v) {
  int lo = 0, hi = n;
  while (lo < hi) {
    int mid = (lo + hi) >> 1;
    if (a[mid] < v) lo = mid + 1; else hi = mid;
  }
  return lo;
}

// stage 1: grid (POOL_CH, G); block g,j reduces chunk j of graph g's range
__global__ __launch_bounds__(128) void pool_partial(
    const float* __restrict__ x2, const int* __restrict__ batch,
    float* __restrict__ partial, int n) {
  int g = blockIdx.y;
  int j = blockIdx.x;
  int t = threadIdx.x;
  int start = lower_bound_i(batch, n, g);
  int end = lower_bound_i(batch, n, g + 1);
  int len = end - start;
  int c0 = start + (int)((long long)len * j / POOL_CH);
  int c1 = start + (int)((long long)len * (j + 1) / POOL_CH);
  float m = -FLT_MAX;
  for (int i = c0; i < c1; i++) m = fmaxf(m, x2[(size_t)i * 128 + t]);
  partial[((size_t)g * POOL_CH + j) * 128 + t] = m;
}

// stage 2: one block per graph
__global__ __launch_bounds__(128) void pool_final(
    const float* __restrict__ partial, float* __restrict__ pool) {
  int g = blockIdx.x;
  int t = threadIdx.x;
  float m = -FLT_MAX;
#pragma unroll
  for (int j = 0; j < POOL_CH; j++)
    m = fmaxf(m, partial[((size_t)g * POOL_CH + j) * 128 + t]);
  pool[g * 128 + t] = m;
}

// ---------------------- classifier ------------------------------------------
__global__ __launch_bounds__(64) void classifier_kernel(
    const float* __restrict__ pool, const float* __restrict__ Wc1,
    const float* __restrict__ bc1, const float* __restrict__ Wc2,
    const float* __restrict__ bc2, float* __restrict__ out) {
  int g = blockIdx.x;
  int t = threadIdx.x;
  __shared__ float xp[128];
  __shared__ float hc[64];
  xp[t] = pool[g * 128 + t];
  xp[t + 64] = pool[g * 128 + 64 + t];
  __syncthreads();
  float s = bc1[t];
  for (int k = 0; k < 128; k++) s += xp[k] * Wc1[k * 64 + t];
  hc[t] = s > 0.f ? s : 0.f;
  __syncthreads();
  if (t < 5) {
    float o = bc2[t];
    for (int j = 0; j < 64; j++) o += hc[j] * Wc2[j * 5 + t];
    out[g * 5 + t] = o;
  }
}

// ---------------------------------------------------------------------------
extern "C" void kernel_launch(void* const* d_in, const int* in_sizes, int n_in,
                              void* d_out, int out_size, void* d_ws, size_t ws_size,
                              hipStream_t stream) {
  const float* x_scalar = (const float*)d_in[0];
  const int* x_opcode = (const int*)d_in[1];
  const int* x_source = (const int*)d_in[2];
  const int* x_sink = (const int*)d_in[3];
  const int* x_string = (const int*)d_in[4];
  const int* x_payload = (const int*)d_in[5];
  const int* edge_index = (const int*)d_in[6];
  const int* batch = (const int*)d_in[7];
  const float* emb_opcode = (const float*)d_in[8];
  const float* emb_source = (const float*)d_in[9];
  const float* emb_sink = (const float*)d_in[10];
  const float* emb_string = (const float*)d_in[11];
  const float* emb_payload = (const float*)d_in[12];
  const float* ln_g = (const float*)d_in[13];
  const float* ln_b = (const float*)d_in[14];
  const float* W1 = (const float*)d_in[15];
  const float* att_src1 = (const float*)d_in[16];
  const float* att_dst1 = (const float*)d_in[17];
  const float* b1 = (const float*)d_in[18];
  const float* W2 = (const float*)d_in[19];
  const float* att_src2 = (const float*)d_in[20];
  const float* att_dst2 = (const float*)d_in[21];
  const float* b2 = (const float*)d_in[22];
  const float* Wc1 = (const float*)d_in[23];
  const float* bc1 = (const float*)d_in[24];
  const float* Wc2 = (const float*)d_in[25];
  const float* bc2 = (const float*)d_in[26];
  float* out = (float*)d_out;

  const int N = in_sizes[0] / 96;
  const int E = in_sizes[6] / 2;
  const int G = out_size / 5;

  const int* e_src = edge_index;
  const int* e_dst = edge_index + E;

  // ---- workspace layout with aliasing (lifetime-checked) ----
  // Region A (N*256*2 B): feats [feats_kernel -> gemm1], then h2/partial/pool.
  // Region B (N*512*2 B): h1 [gemm1 -> gat1_agg], then x2.
  char* w = (char*)d_ws;
  size_t o = 0;
  auto take = [&](size_t bytes) -> void* {
    void* p = w + o;
    o += (bytes + 255) & ~(size_t)255;
    return p;
  };
  char* regionA = (char*)take((size_t)N * 256 * 2);
  char* regionB = (char*)take((size_t)N * 512 * 2);
  _Float16* x1 = (_Float16*)take((size_t)N * 512 * 2);
  _Float16* Wt1 = (_Float16*)take((size_t)512 * 256 * 2);
  _Float16* Wt2 = (_Float16*)take((size_t)128 * 512 * 2);
  float* a_src1 = (float*)take((size_t)N * 4 * 4);
  float* a_dst1 = (float*)take((size_t)N * 4 * 4);
  float* a_src2 = (float*)take((size_t)N * 4);
  float* a_dst2 = (float*)take((size_t)N * 4);
  int* deg = (int*)take((size_t)N * 2 * 4);  // deg + cnt contiguous
  int* cnt = deg + N;
  int* rowptr = (int*)take((size_t)(N + 1) * 4);
  int* csr_src = (int*)take((size_t)(E + N) * 4);
  // total ~133 MB

  _Float16* feats = (_Float16*)regionA;
  _Float16* h2 = (_Float16*)regionA;  // feats dead after gemm1
  float* partial = (float*)(regionA + ((size_t)N * 128 * 2 + 255 & ~(size_t)255));
  float* pool = partial + (size_t)G * POOL_CH * 128;
  _Float16* h1 = (_Float16*)regionB;
  float* x2 = (float*)regionB;        // h1 dead after gat1_agg

  hipMemsetAsync(deg, 0, (size_t)N * 2 * 4, stream);

  // CSR build (independent of features)
  hist_kernel<<<(E + 255) / 256, 256, 0, stream>>>(e_dst, deg, E);
  scan_kernel<<<1, 1024, 0, stream>>>(deg, rowptr, N);
  fill_kernel<<<(E + N + 255) / 256, 256, 0, stream>>>(e_src, e_dst, rowptr, cnt,
                                                       csr_src, E, N);

  // weights -> transposed fp16
  transpose_f16<<<(256 * 512 + 255) / 256, 256, 0, stream>>>(W1, Wt1, 256, 512);
  transpose_f16<<<(512 * 128 + 255) / 256, 256, 0, stream>>>(W2, Wt2, 512, 128);

  // features + LN (fp16 out), wave-per-node
  feats_kernel<<<(N + 3) / 4, 256, 0, stream>>>(
      x_scalar, x_opcode, x_source, x_sink, x_string, x_payload, emb_opcode,
      emb_source, emb_sink, emb_string, emb_payload, ln_g, ln_b, feats, N);

  int mblocks = (N + 127) / 128;
  // conv1: h1 = feats @ W1  (M=N, K=256, N=512)
  gemm_f16<<<dim3(512 / 128, mblocks), 256, 0, stream>>>(feats, Wt1, h1, N, 256, 512);
  att1_kernel<<<(N + 3) / 4, 256, 0, stream>>>(h1, att_src1, att_dst1, a_src1,
                                               a_dst1, N);
  gat1_agg<<<(N + 3) / 4, 256, 0, stream>>>(h1, a_src1, a_dst1, rowptr, csr_src,
                                            b1, x1, N);

  // conv2: h2 = x1 @ W2  (M=N, K=512, N=128) — h2 overwrites feats (dead)
  gemm_f16<<<dim3(128 / 128, mblocks), 256, 0, stream>>>(x1, Wt2, h2, N, 512, 128);
  att2_kernel<<<(N + 3) / 4, 256, 0, stream>>>(h2, att_src2, att_dst2, a_src2,
                                               a_dst2, N);
  // x2 overwrites h1 (dead after gat1_agg)
  gat2_agg<<<(N + 3) / 4, 256, 0, stream>>>(h2, a_src2, a_dst2, rowptr, csr_src,
                                            b2, x2, N);

  // pool (2-stage) + classifier
  pool_partial<<<dim3(POOL_CH, G), 128, 0, stream>>>(x2, batch, partial, N);
  pool_final<<<G, 128, 0, stream>>>(partial, pool);
  classifier_kernel<<<G, 64, 0, stream>>>(pool, Wc1, bc1, Wc2, bc2, out);
}

// Round 7
// 450.460 us; speedup vs baseline: 2.5223x; 1.1724x over previous
//
#include <hip/hip_runtime.h>
#include <hip/hip_bf16.h>
#include <float.h>

// ---------------------------------------------------------------------------
// GlobalFeatureGAT: feature-build+LN -> GAT(4 heads,128) -> ELU -> GAT(1,128)
// -> ELU -> per-graph max pool -> MLP(128->64->5).
// R7: (1) GEMM rewritten with global_load_lds(16B) staging into XOR-swizzled
// unpadded LDS + attention dots fused into the GEMM epilogue (att1/att2
// kernels deleted; each 128-col block = exactly one head). GEMM operands
// padded to Npad rows (ws_size ~171.6 MB, we use ~133 MB — R3/R4 bracketed it).
// (2) single-block scan replaced by 3-phase parallel scan. (3) gather loops
// 2-way unrolled in gat1/gat2 for more outstanding loads.
// N=50000, E=500000 (+N self loops), G=64, IN_DIM=256, C=128, H1=4.
// ---------------------------------------------------------------------------

#define LEAKY(e) ((e) > 0.f ? (e) : 0.2f * (e))
#define POOL_CH 32  // chunks per graph in stage-1 pool

typedef _Float16 half8 __attribute__((ext_vector_type(8)));
typedef float floatx4 __attribute__((ext_vector_type(4)));

__device__ __forceinline__ void async_copy16(const _Float16* gsrc,
                                             const _Float16* ldst) {
  __builtin_amdgcn_global_load_lds(
      (const __attribute__((address_space(1))) unsigned int*)gsrc,
      (__attribute__((address_space(3))) unsigned int*)ldst, 16, 0, 0);
}

// ---------------------- feature build + layernorm (fp16 out) ----------------
// One wave per node. Lane l owns channels {l, 64+l, 128+l, 192+l}.
__global__ __launch_bounds__(256) void feats_kernel(
    const float* __restrict__ xs, const int* __restrict__ xo,
    const int* __restrict__ xsrc, const int* __restrict__ xsk,
    const int* __restrict__ xst, const int* __restrict__ xp,
    const float* __restrict__ eo, const float* __restrict__ es,
    const float* __restrict__ ek, const float* __restrict__ et,
    const float* __restrict__ ep, const float* __restrict__ lng,
    const float* __restrict__ lnb, _Float16* __restrict__ feats, int n) {
  int node = blockIdx.x * 4 + (threadIdx.x >> 6);
  if (node >= n) return;
  int l = threadIdx.x & 63;

  int myidx = 0;
  if (l < 16)      myidx = xo[node * 16 + l];
  else if (l < 24) myidx = xsrc[node * 8 + (l - 16)];
  else if (l < 32) myidx = xsk[node * 8 + (l - 24)];
  else if (l < 40) myidx = xst[node * 8 + (l - 32)];
  else if (l < 48) myidx = xp[node * 8 + (l - 40)];

  const float* xrow = xs + (size_t)node * 96;
  float v0 = xrow[l];
  float v1, v2, v3;

  bool hi = (l >= 32);
  int d = l & 31;

  {
    float s = 0.f, c = 0.f;
#pragma unroll
    for (int j = 0; j < 16; j++) {
      int id = __shfl(myidx, j);
      if (hi && id != 0) { s += eo[(size_t)id * 32 + d]; c += 1.f; }
    }
    float sc = hi ? 0.f : xrow[64 + l];
    v1 = hi ? (s / (c + 1e-9f)) : sc;
  }
  {
    const float* tab = hi ? ek : es;
    int base = hi ? 24 : 16;
    float s = 0.f, c = 0.f;
#pragma unroll
    for (int j = 0; j < 8; j++) {
      int id = __shfl(myidx, base + j);
      if (id != 0) { s += tab[(size_t)id * 32 + d]; c += 1.f; }
    }
    v2 = s / (c + 1e-9f);
  }
  {
    const float* tab = hi ? ep : et;
    int base = hi ? 40 : 32;
    float s = 0.f, c = 0.f;
#pragma unroll
    for (int j = 0; j < 8; j++) {
      int id = __shfl(myidx, base + j);
      if (id != 0) { s += tab[(size_t)id * 32 + d]; c += 1.f; }
    }
    v3 = s / (c + 1e-9f);
  }

  float sum = v0 + v1 + v2 + v3;
  for (int o = 32; o; o >>= 1) sum += __shfl_xor(sum, o);
  float mu = sum * (1.f / 256.f);

  float d0 = v0 - mu, d1 = v1 - mu, d2 = v2 - mu, d3 = v3 - mu;
  float q = d0 * d0 + d1 * d1 + d2 * d2 + d3 * d3;
  for (int o = 32; o; o >>= 1) q += __shfl_xor(q, o);
  float rstd = rsqrtf(q * (1.f / 256.f) + 1e-5f);

  _Float16* frow = feats + (size_t)node * 256;
  frow[l]       = (_Float16)(d0 * rstd * lng[l] + lnb[l]);
  frow[64 + l]  = (_Float16)(d1 * rstd * lng[64 + l] + lnb[64 + l]);
  frow[128 + l] = (_Float16)(d2 * rstd * lng[128 + l] + lnb[128 + l]);
  frow[192 + l] = (_Float16)(d3 * rstd * lng[192 + l] + lnb[192 + l]);
}

// ---------------------- weight transpose + fp16 convert ---------------------
__global__ __launch_bounds__(256) void transpose_f16(
    const float* __restrict__ W, _Float16* __restrict__ Wt, int K, int N) {
  int t = blockIdx.x * 256 + threadIdx.x;
  if (t < K * N) {
    int n = t / K, k = t - n * K;
    Wt[t] = (_Float16)W[(size_t)k * N + n];
  }
}

// ------------- fp16 MFMA GEMM + fused attention dots ------------------------
// A: Mpad x K (row-major fp16, padded rows garbage), Bt: N x K, C: Mpad x N.
// 128x128 tile, 4 waves of 64x64, 16x16x32 MFMA, fp32 accum.
// LDS tiles 128x32 halves, stored as 16B chunks with XOR swizzle
// (chunk pos p = cs ^ (row&3)) so global_load_lds (wave-uniform base +
// lane*16) works unpadded while ds_read_b128 stays <=2-way conflicted.
// Epilogue: a_src_out[row*astride + n0/128] = sum_col C[row,col]*att_src[col]
// (one head per 128-col block), same for a_dst. fp32, from the accumulators.
__global__ __launch_bounds__(256) void gemm_f16_att(
    const _Float16* __restrict__ A, const _Float16* __restrict__ Bt,
    _Float16* __restrict__ C, const float* __restrict__ att_src,
    const float* __restrict__ att_dst, float* __restrict__ a_src_out,
    float* __restrict__ a_dst_out, int astride, int K, int N) {
  __shared__ __attribute__((aligned(16))) _Float16 As[128 * 32];
  __shared__ __attribute__((aligned(16))) _Float16 Bs[128 * 32];
  int m0 = blockIdx.y * 128;
  int n0 = blockIdx.x * 128;
  int tid = threadIdx.x;
  int wave = tid >> 6, lane = tid & 63;
  int wm = (wave >> 1) * 64, wn = (wave & 1) * 64;
  int lr = lane & 15, lq = lane >> 4;
  int wbase = tid & ~63;  // wave*64

  floatx4 acc[4][4] = {};

  for (int k0 = 0; k0 < K; k0 += 32) {
#pragma unroll
    for (int c = 0; c < 2; c++) {
      int sid = c * 256 + tid;
      int row = sid >> 2;
      int cs = (sid & 3) ^ (row & 3);
      const _Float16* ga = A + (size_t)(m0 + row) * K + k0 + cs * 8;
      const _Float16* gb = Bt + (size_t)(n0 + row) * K + k0 + cs * 8;
      async_copy16(ga, As + (size_t)(c * 256 + wbase) * 8);
      async_copy16(gb, Bs + (size_t)(c * 256 + wbase) * 8);
    }
    __syncthreads();

    half8 af[4], bf[4];
#pragma unroll
    for (int i = 0; i < 4; i++) {
      int row = wm + i * 16 + lr;
      af[i] = *(const half8*)(As + ((row << 2) + (lq ^ (row & 3))) * 8);
    }
#pragma unroll
    for (int j = 0; j < 4; j++) {
      int row = wn + j * 16 + lr;
      bf[j] = *(const half8*)(Bs + ((row << 2) + (lq ^ (row & 3))) * 8);
    }
#pragma unroll
    for (int i = 0; i < 4; i++)
#pragma unroll
      for (int j = 0; j < 4; j++)
        acc[i][j] =
            __builtin_amdgcn_mfma_f32_16x16x32_f16(af[i], bf[j], acc[i][j], 0, 0, 0);
    __syncthreads();
  }

  // C store (padded rows exist in C, no guard needed)
#pragma unroll
  for (int i = 0; i < 4; i++) {
    int rbase = m0 + wm + i * 16 + lq * 4;
#pragma unroll
    for (int r = 0; r < 4; r++) {
      int row = rbase + r;
#pragma unroll
      for (int j = 0; j < 4; j++) {
        int col = n0 + wn + j * 16 + lr;
        C[(size_t)row * N + col] = (_Float16)acc[i][j][r];
      }
    }
  }

  // fused attention dots epilogue
  float asv[4], adv[4];
#pragma unroll
  for (int j = 0; j < 4; j++) {
    int col = n0 + wn + j * 16 + lr;
    asv[j] = att_src[col];
    adv[j] = att_dst[col];
  }
  float ps[4][4], pd[4][4];
#pragma unroll
  for (int i = 0; i < 4; i++)
#pragma unroll
    for (int r = 0; r < 4; r++) {
      float s = 0.f, d = 0.f;
#pragma unroll
      for (int j = 0; j < 4; j++) {
        s += acc[i][j][r] * asv[j];
        d += acc[i][j][r] * adv[j];
      }
#pragma unroll
      for (int o = 1; o < 16; o <<= 1) {
        s += __shfl_xor(s, o);
        d += __shfl_xor(d, o);
      }
      ps[i][r] = s;
      pd[i][r] = d;
    }
  float* sred = (float*)&As[0];  // reuse LDS (post-loop barrier already done)
  if (wn == 64 && lr == 0) {
#pragma unroll
    for (int i = 0; i < 4; i++)
#pragma unroll
      for (int r = 0; r < 4; r++) {
        int rl = wm + i * 16 + lq * 4 + r;
        sred[rl * 2] = ps[i][r];
        sred[rl * 2 + 1] = pd[i][r];
      }
  }
  __syncthreads();
  if (wn == 0 && lr == 0) {
    int hsel = n0 >> 7;
#pragma unroll
    for (int i = 0; i < 4; i++)
#pragma unroll
      for (int r = 0; r < 4; r++) {
        int rl = wm + i * 16 + lq * 4 + r;
        int row = m0 + rl;
        a_src_out[(size_t)row * astride + hsel] = ps[i][r] + sred[rl * 2];
        a_dst_out[(size_t)row * astride + hsel] = pd[i][r] + sred[rl * 2 + 1];
      }
  }
}

// ---------------------- CSR build -------------------------------------------
__global__ __launch_bounds__(256) void hist_kernel(const int* __restrict__ dst,
                                                   int* __restrict__ deg, int E) {
  int t = blockIdx.x * 256 + threadIdx.x;
  if (t < E) atomicAdd(&deg[dst[t]], 1);
}

// 3-phase parallel exclusive scan of (deg[i]+1)
__global__ __launch_bounds__(256) void scan_a(const int* __restrict__ deg,
                                              int* __restrict__ rowptr,
                                              int* __restrict__ bsum, int n) {
  __shared__ int sh[256];
  int b = blockIdx.x, t = threadIdx.x;
  int i = b * 256 + t;
  int v = (i < n) ? deg[i] + 1 : 0;
  sh[t] = v;
  __syncthreads();
  int x = v;
  for (int o = 1; o < 256; o <<= 1) {
    int y = (t >= o) ? sh[t - o] : 0;
    __syncthreads();
    x += y;
    sh[t] = x;
    __syncthreads();
  }
  if (i < n) rowptr[i] = x - v;  // exclusive within block
  if (t == 255) bsum[b] = x;     // block total
}

__global__ __launch_bounds__(256) void scan_b(int* __restrict__ bsum, int nb) {
  __shared__ int sh[256];
  int t = threadIdx.x;
  int v = (t < nb) ? bsum[t] : 0;
  sh[t] = v;
  __syncthreads();
  int x = v;
  for (int o = 1; o < 256; o <<= 1) {
    int y = (t >= o) ? sh[t - o] : 0;
    __syncthreads();
    x += y;
    sh[t] = x;
    __syncthreads();
  }
  if (t < nb) bsum[t] = x - v;  // exclusive block offsets
}

__global__ __launch_bounds__(256) void scan_c(int* __restrict__ rowptr,
                                              const int* __restrict__ bsum,
                                              int n, int total) {
  int i = blockIdx.x * 256 + threadIdx.x;
  if (i < n) rowptr[i] += bsum[blockIdx.x];
  else if (i == n) rowptr[n] = total;
}

__global__ __launch_bounds__(256) void fill_kernel(
    const int* __restrict__ src, const int* __restrict__ dst,
    const int* __restrict__ rowptr, int* __restrict__ cnt,
    int* __restrict__ csr_src, int E, int n) {
  int t = blockIdx.x * 256 + threadIdx.x;
  if (t < E) {
    int d = dst[t];
    int pos = rowptr[d] + atomicAdd(&cnt[d], 1);
    csr_src[pos] = src[t];
  } else if (t < E + n) {
    int i = t - E;
    csr_src[rowptr[i + 1] - 1] = i;  // self loop in the last slot
  }
}

// ---------------------- GAT aggregation (conv1: 4 heads x 128) --------------
__global__ __launch_bounds__(256) void gat1_agg(
    const _Float16* __restrict__ h1, const float* __restrict__ asrc,
    const float* __restrict__ adst, const int* __restrict__ rowptr,
    const int* __restrict__ csr_src, const float* __restrict__ bias,
    _Float16* __restrict__ out, int n) {
  int node = blockIdx.x * 4 + (threadIdx.x >> 6);
  if (node >= n) return;
  int l = threadIdx.x & 63;
  int hh = l >> 4;
  int li = l & 15;
  int r0 = rowptr[node];
  int deg = rowptr[node + 1] - r0;
  int cb = l * 8;

  float acc[8] = {};

  if (deg <= 64) {
    float adm = adst[node * 4 + hh];
    int s_reg[4];
    float ww[4];
    float m = -1e30f;
#pragma unroll
    for (int c = 0; c < 4; c++) {
      int k = c * 16 + li;
      int s = (k < deg) ? csr_src[r0 + k] : -1;
      s_reg[c] = s;
      float e = -1e30f;
      if (s >= 0) {
        float t = asrc[(size_t)s * 4 + hh] + adm;
        e = LEAKY(t);
      }
      ww[c] = e;
      m = fmaxf(m, e);
    }
#pragma unroll
    for (int o = 1; o < 16; o <<= 1) m = fmaxf(m, __shfl_xor(m, o));
    float sum = 0.f;
#pragma unroll
    for (int c = 0; c < 4; c++) {
      float w = (s_reg[c] >= 0) ? __expf(ww[c] - m) : 0.f;
      ww[c] = w;
      sum += w;
    }
#pragma unroll
    for (int o = 1; o < 16; o <<= 1) sum += __shfl_xor(sum, o);
    float sinv = 1.f / (sum + 1e-16f);
#pragma unroll
    for (int c = 0; c < 4; c++) ww[c] *= sinv;

#pragma unroll
    for (int c = 0; c < 4; c++) {
      int base = c * 16;
      if (base >= deg) break;
      int lim = min(16, deg - base);
      int jl = 0;
      for (; jl + 2 <= lim; jl += 2) {  // 2-way unroll: 2 loads in flight
        int s0 = __shfl(s_reg[c], jl);
        int s1 = __shfl(s_reg[c], jl + 1);
        float w0 = __shfl(ww[c], hh * 16 + jl);
        float w1 = __shfl(ww[c], hh * 16 + jl + 1);
        const half8 hv0 = *(const half8*)(h1 + (size_t)s0 * 512 + cb);
        const half8 hv1 = *(const half8*)(h1 + (size_t)s1 * 512 + cb);
#pragma unroll
        for (int q = 0; q < 8; q++) acc[q] += w0 * (float)hv0[q];
#pragma unroll
        for (int q = 0; q < 8; q++) acc[q] += w1 * (float)hv1[q];
      }
      if (jl < lim) {
        int s0 = __shfl(s_reg[c], jl);
        float w0 = __shfl(ww[c], hh * 16 + jl);
        const half8 hv0 = *(const half8*)(h1 + (size_t)s0 * 512 + cb);
#pragma unroll
        for (int q = 0; q < 8; q++) acc[q] += w0 * (float)hv0[q];
      }
    }
  } else {
    // fallback (deg>64, rare): 3-pass
    float4 ad4 = *(const float4*)(adst + node * 4);
    float adv[4] = {ad4.x, ad4.y, ad4.z, ad4.w};
    float m[4] = {-1e30f, -1e30f, -1e30f, -1e30f};
    for (int k = l; k < deg; k += 64) {
      int s = csr_src[r0 + k];
      float4 av = *(const float4*)(asrc + (size_t)s * 4);
      float e;
      e = LEAKY(av.x + adv[0]); m[0] = fmaxf(m[0], e);
      e = LEAKY(av.y + adv[1]); m[1] = fmaxf(m[1], e);
      e = LEAKY(av.z + adv[2]); m[2] = fmaxf(m[2], e);
      e = LEAKY(av.w + adv[3]); m[3] = fmaxf(m[3], e);
    }
    for (int o = 1; o < 64; o <<= 1) {
#pragma unroll
      for (int h = 0; h < 4; h++) m[h] = fmaxf(m[h], __shfl_xor(m[h], o));
    }
    float sum[4] = {0.f, 0.f, 0.f, 0.f};
    for (int k = l; k < deg; k += 64) {
      int s = csr_src[r0 + k];
      float4 av = *(const float4*)(asrc + (size_t)s * 4);
      float e;
      e = LEAKY(av.x + adv[0]); sum[0] += __expf(e - m[0]);
      e = LEAKY(av.y + adv[1]); sum[1] += __expf(e - m[1]);
      e = LEAKY(av.z + adv[2]); sum[2] += __expf(e - m[2]);
      e = LEAKY(av.w + adv[3]); sum[3] += __expf(e - m[3]);
    }
    for (int o = 1; o < 64; o <<= 1) {
#pragma unroll
      for (int h = 0; h < 4; h++) sum[h] += __shfl_xor(sum[h], o);
    }
    float mm = m[hh];
    float sinv = 1.f / (sum[hh] + 1e-16f);
    float adm = adv[hh];
    for (int k = 0; k < deg; k++) {
      int s = csr_src[r0 + k];
      float a = asrc[(size_t)s * 4 + hh];
      float e = LEAKY(a + adm);
      float w = __expf(e - mm) * sinv;
      const half8 hv = *(const half8*)(h1 + (size_t)s * 512 + cb);
#pragma unroll
      for (int q = 0; q < 8; q++) acc[q] += w * (float)hv[q];
    }
  }

  const float* bp = bias + cb;
  half8 ov;
#pragma unroll
  for (int j = 0; j < 8; j++) {
    float r = acc[j] + bp[j];
    ov[j] = (_Float16)(r > 0.f ? r : (__expf(r) - 1.f));  // ELU
  }
  *(half8*)(out + (size_t)node * 512 + cb) = ov;
}

// ---------------------- GAT aggregation (conv2: 1 head x 128) ---------------
__global__ __launch_bounds__(256) void gat2_agg(
    const _Float16* __restrict__ h2, const float* __restrict__ asrc,
    const float* __restrict__ adst, const int* __restrict__ rowptr,
    const int* __restrict__ csr_src, const float* __restrict__ bias,
    float* __restrict__ out, int n) {
  int node = blockIdx.x * 4 + (threadIdx.x >> 6);
  if (node >= n) return;
  int l = threadIdx.x & 63;
  int r0 = rowptr[node];
  int deg = rowptr[node + 1] - r0;
  int cb = l * 2;
  float a0 = 0.f, a1 = 0.f;

  if (deg <= 64) {
    float ad = adst[node];
    int s = (l < deg) ? csr_src[r0 + l] : -1;
    float e = -1e30f;
    if (s >= 0) {
      float t = asrc[s] + ad;
      e = LEAKY(t);
    }
    float m = e;
    for (int o = 1; o < 64; o <<= 1) m = fmaxf(m, __shfl_xor(m, o));
    float w = (s >= 0) ? __expf(e - m) : 0.f;
    float sum = w;
    for (int o = 1; o < 64; o <<= 1) sum += __shfl_xor(sum, o);
    w *= 1.f / (sum + 1e-16f);
    int j = 0;
    for (; j + 2 <= deg; j += 2) {
      int s0 = __shfl(s, j);
      int s1 = __shfl(s, j + 1);
      float w0 = __shfl(w, j);
      float w1 = __shfl(w, j + 1);
      const _Float16* hp0 = h2 + (size_t)s0 * 128 + cb;
      const _Float16* hp1 = h2 + (size_t)s1 * 128 + cb;
      float p00 = (float)hp0[0], p01 = (float)hp0[1];
      float p10 = (float)hp1[0], p11 = (float)hp1[1];
      a0 += w0 * p00 + w1 * p10;
      a1 += w0 * p01 + w1 * p11;
    }
    if (j < deg) {
      int sj = __shfl(s, j);
      float wj = __shfl(w, j);
      const _Float16* hp = h2 + (size_t)sj * 128 + cb;
      a0 += wj * (float)hp[0];
      a1 += wj * (float)hp[1];
    }
  } else {
    float ad = adst[node];
    float m = -1e30f;
    for (int k = l; k < deg; k += 64) {
      int s = csr_src[r0 + k];
      float e = LEAKY(asrc[s] + ad);
      m = fmaxf(m, e);
    }
    for (int o = 1; o < 64; o <<= 1) m = fmaxf(m, __shfl_xor(m, o));
    float sum = 0.f;
    for (int k = l; k < deg; k += 64) {
      int s = csr_src[r0 + k];
      float e = LEAKY(asrc[s] + ad);
      sum += __expf(e - m);
    }
    for (int o = 1; o < 64; o <<= 1) sum += __shfl_xor(sum, o);
    float sinv = 1.f / (sum + 1e-16f);
    for (int k = 0; k < deg; k++) {
      int s = csr_src[r0 + k];
      float e = LEAKY(asrc[s] + ad);
      float w = __expf(e - m) * sinv;
      const _Float16* hp = h2 + (size_t)s * 128 + cb;
      a0 += w * (float)hp[0];
      a1 += w * (float)hp[1];
    }
  }

  float ra = a0 + bias[cb];
  float rb = a1 + bias[cb + 1];
  out[(size_t)node * 128 + cb]     = ra > 0.f ? ra : (__expf(ra) - 1.f);
  out[(size_t)node * 128 + cb + 1] = rb > 0.f ? rb : (__expf(rb) - 1.f);
}

// ---------------------- per-graph max pool (2-stage) ------------------------
__device__ inline int lower_bound_i(const int* a, int n, int v) {
  int lo = 0, hi = n;
  while (lo < hi) {
    int mid = (lo + hi) >> 1;
    if (a[mid] < v) lo = mid + 1; else hi = mid;
  }
  return lo;
}

__global__ __launch_bounds__(128) void pool_partial(
    const float* __restrict__ x2, const int* __restrict__ batch,
    float* __restrict__ partial, int n) {
  int g = blockIdx.y;
  int j = blockIdx.x;
  int t = threadIdx.x;
  int start = lower_bound_i(batch, n, g);
  int end = lower_bound_i(batch, n, g + 1);
  int len = end - start;
  int c0 = start + (int)((long long)len * j / POOL_CH);
  int c1 = start + (int)((long long)len * (j + 1) / POOL_CH);
  float m = -FLT_MAX;
  for (int i = c0; i < c1; i++) m = fmaxf(m, x2[(size_t)i * 128 + t]);
  partial[((size_t)g * POOL_CH + j) * 128 + t] = m;
}

__global__ __launch_bounds__(128) void pool_final(
    const float* __restrict__ partial, float* __restrict__ pool) {
  int g = blockIdx.x;
  int t = threadIdx.x;
  float m = -FLT_MAX;
#pragma unroll
  for (int j = 0; j < POOL_CH; j++)
    m = fmaxf(m, partial[((size_t)g * POOL_CH + j) * 128 + t]);
  pool[g * 128 + t] = m;
}

// ---------------------- classifier ------------------------------------------
__global__ __launch_bounds__(64) void classifier_kernel(
    const float* __restrict__ pool, const float* __restrict__ Wc1,
    const float* __restrict__ bc1, const float* __restrict__ Wc2,
    const float* __restrict__ bc2, float* __restrict__ out) {
  int g = blockIdx.x;
  int t = threadIdx.x;
  __shared__ float xp[128];
  __shared__ float hc[64];
  xp[t] = pool[g * 128 + t];
  xp[t + 64] = pool[g * 128 + 64 + t];
  __syncthreads();
  float s = bc1[t];
  for (int k = 0; k < 128; k++) s += xp[k] * Wc1[k * 64 + t];
  hc[t] = s > 0.f ? s : 0.f;
  __syncthreads();
  if (t < 5) {
    float o = bc2[t];
    for (int j = 0; j < 64; j++) o += hc[j] * Wc2[j * 5 + t];
    out[g * 5 + t] = o;
  }
}

// ---------------------------------------------------------------------------
extern "C" void kernel_launch(void* const* d_in, const int* in_sizes, int n_in,
                              void* d_out, int out_size, void* d_ws, size_t ws_size,
                              hipStream_t stream) {
  const float* x_scalar = (const float*)d_in[0];
  const int* x_opcode = (const int*)d_in[1];
  const int* x_source = (const int*)d_in[2];
  const int* x_sink = (const int*)d_in[3];
  const int* x_string = (const int*)d_in[4];
  const int* x_payload = (const int*)d_in[5];
  const int* edge_index = (const int*)d_in[6];
  const int* batch = (const int*)d_in[7];
  const float* emb_opcode = (const float*)d_in[8];
  const float* emb_source = (const float*)d_in[9];
  const float* emb_sink = (const float*)d_in[10];
  const float* emb_string = (const float*)d_in[11];
  const float* emb_payload = (const float*)d_in[12];
  const float* ln_g = (const float*)d_in[13];
  const float* ln_b = (const float*)d_in[14];
  const float* W1 = (const float*)d_in[15];
  const float* att_src1 = (const float*)d_in[16];
  const float* att_dst1 = (const float*)d_in[17];
  const float* b1 = (const float*)d_in[18];
  const float* W2 = (const float*)d_in[19];
  const float* att_src2 = (const float*)d_in[20];
  const float* att_dst2 = (const float*)d_in[21];
  const float* b2 = (const float*)d_in[22];
  const float* Wc1 = (const float*)d_in[23];
  const float* bc1 = (const float*)d_in[24];
  const float* Wc2 = (const float*)d_in[25];
  const float* bc2 = (const float*)d_in[26];
  float* out = (float*)d_out;

  const int N = in_sizes[0] / 96;
  const int E = in_sizes[6] / 2;
  const int G = out_size / 5;
  const int Npad = (N + 127) / 128 * 128;  // GEMM row padding

  const int* e_src = edge_index;
  const int* e_dst = edge_index + E;

  // ---- workspace layout with aliasing (lifetime-checked; ws ~171.6 MB) ----
  // Region A (Npad*256*2): feats [feats_kernel -> gemm1], then h2/partial/pool.
  // Region B (Npad*512*2): h1 [gemm1 -> gat1_agg], then x2.
  char* w = (char*)d_ws;
  size_t o = 0;
  auto take = [&](size_t bytes) -> void* {
    void* p = w + o;
    o += (bytes + 255) & ~(size_t)255;
    return p;
  };
  char* regionA = (char*)take((size_t)Npad * 256 * 2);
  char* regionB = (char*)take((size_t)Npad * 512 * 2);
  _Float16* x1 = (_Float16*)take((size_t)Npad * 512 * 2);
  _Float16* Wt1 = (_Float16*)take((size_t)512 * 256 * 2);
  _Float16* Wt2 = (_Float16*)take((size_t)128 * 512 * 2);
  float* a_src1 = (float*)take((size_t)Npad * 4 * 4);
  float* a_dst1 = (float*)take((size_t)Npad * 4 * 4);
  float* a_src2 = (float*)take((size_t)Npad * 4);
  float* a_dst2 = (float*)take((size_t)Npad * 4);
  int* deg = (int*)take((size_t)N * 2 * 4);  // deg + cnt contiguous
  int* cnt = deg + N;
  int* rowptr = (int*)take((size_t)(N + 1) * 4);
  int* csr_src = (int*)take((size_t)(E + N) * 4);
  int* bsum = (int*)take(256 * 4);
  // total ~133.3 MB < ws_size (~171.6 MB, bracketed by R3 pass / R4 fail)

  _Float16* feats = (_Float16*)regionA;
  _Float16* h2 = (_Float16*)regionA;  // feats dead after gemm1
  float* partial = (float*)(regionA + (((size_t)Npad * 128 * 2 + 255) & ~(size_t)255));
  float* pool = partial + (size_t)G * POOL_CH * 128;
  _Float16* h1 = (_Float16*)regionB;
  float* x2 = (float*)regionB;        // h1 dead after gat1_agg

  hipMemsetAsync(deg, 0, (size_t)N * 2 * 4, stream);

  // CSR build (independent of features)
  hist_kernel<<<(E + 255) / 256, 256, 0, stream>>>(e_dst, deg, E);
  int nb = (N + 255) / 256;
  scan_a<<<nb, 256, 0, stream>>>(deg, rowptr, bsum, N);
  scan_b<<<1, 256, 0, stream>>>(bsum, nb);
  scan_c<<<(N + 256) / 256, 256, 0, stream>>>(rowptr, bsum, N, E + N);
  fill_kernel<<<(E + N + 255) / 256, 256, 0, stream>>>(e_src, e_dst, rowptr, cnt,
                                                       csr_src, E, N);

  // weights -> transposed fp16
  transpose_f16<<<(256 * 512 + 255) / 256, 256, 0, stream>>>(W1, Wt1, 256, 512);
  transpose_f16<<<(512 * 128 + 255) / 256, 256, 0, stream>>>(W2, Wt2, 512, 128);

  // features + LN (fp16 out), wave-per-node
  feats_kernel<<<(N + 3) / 4, 256, 0, stream>>>(
      x_scalar, x_opcode, x_source, x_sink, x_string, x_payload, emb_opcode,
      emb_source, emb_sink, emb_string, emb_payload, ln_g, ln_b, feats, N);

  int mblocks = Npad / 128;
  // conv1: h1 = feats @ W1 (K=256, N=512) + fused a_src1/a_dst1 (4 heads)
  gemm_f16_att<<<dim3(512 / 128, mblocks), 256, 0, stream>>>(
      feats, Wt1, h1, att_src1, att_dst1, a_src1, a_dst1, 4, 256, 512);
  gat1_agg<<<(N + 3) / 4, 256, 0, stream>>>(h1, a_src1, a_dst1, rowptr, csr_src,
                                            b1, x1, N);

  // conv2: h2 = x1 @ W2 (K=512, N=128) + fused a_src2/a_dst2 (1 head)
  gemm_f16_att<<<dim3(128 / 128, mblocks), 256, 0, stream>>>(
      x1, Wt2, h2, att_src2, att_dst2, a_src2, a_dst2, 1, 512, 128);
  gat2_agg<<<(N + 3) / 4, 256, 0, stream>>>(h2, a_src2, a_dst2, rowptr, csr_src,
                                            b2, x2, N);

  // pool (2-stage) + classifier
  pool_partial<<<dim3(POOL_CH, G), 128, 0, stream>>>(x2, batch, partial, N);
  pool_final<<<G, 128, 0, stream>>>(partial, pool);
  classifier_kernel<<<G, 64, 0, stream>>>(pool, Wc1, bc1, Wc2, bc2, out);
}

// Round 8
// 441.816 us; speedup vs baseline: 2.5716x; 1.0196x over previous
//
#include <hip/hip_runtime.h>
#include <hip/hip_bf16.h>
#include <float.h>

// ---------------------------------------------------------------------------
// GlobalFeatureGAT: feature-build+LN -> GAT(4 heads,128) -> ELU -> GAT(1,128)
// -> ELU -> per-graph max pool -> MLP(128->64->5).
// R8: gat1/gat2 gather 4-wide unrolled (latency-vs-bandwidth discriminator:
// R7's 563MB/89.5us = 6.29 TB/s delivered == measured streaming ceiling).
// Both transposes merged into one launch. Rest frozen from R7.
// N=50000, E=500000 (+N self loops), G=64, IN_DIM=256, C=128, H1=4.
// ---------------------------------------------------------------------------

#define LEAKY(e) ((e) > 0.f ? (e) : 0.2f * (e))
#define POOL_CH 32  // chunks per graph in stage-1 pool

typedef _Float16 half8 __attribute__((ext_vector_type(8)));
typedef float floatx4 __attribute__((ext_vector_type(4)));

__device__ __forceinline__ void async_copy16(const _Float16* gsrc,
                                             const _Float16* ldst) {
  __builtin_amdgcn_global_load_lds(
      (const __attribute__((address_space(1))) unsigned int*)gsrc,
      (__attribute__((address_space(3))) unsigned int*)ldst, 16, 0, 0);
}

// ---------------------- feature build + layernorm (fp16 out) ----------------
// One wave per node. Lane l owns channels {l, 64+l, 128+l, 192+l}.
__global__ __launch_bounds__(256) void feats_kernel(
    const float* __restrict__ xs, const int* __restrict__ xo,
    const int* __restrict__ xsrc, const int* __restrict__ xsk,
    const int* __restrict__ xst, const int* __restrict__ xp,
    const float* __restrict__ eo, const float* __restrict__ es,
    const float* __restrict__ ek, const float* __restrict__ et,
    const float* __restrict__ ep, const float* __restrict__ lng,
    const float* __restrict__ lnb, _Float16* __restrict__ feats, int n) {
  int node = blockIdx.x * 4 + (threadIdx.x >> 6);
  if (node >= n) return;
  int l = threadIdx.x & 63;

  int myidx = 0;
  if (l < 16)      myidx = xo[node * 16 + l];
  else if (l < 24) myidx = xsrc[node * 8 + (l - 16)];
  else if (l < 32) myidx = xsk[node * 8 + (l - 24)];
  else if (l < 40) myidx = xst[node * 8 + (l - 32)];
  else if (l < 48) myidx = xp[node * 8 + (l - 40)];

  const float* xrow = xs + (size_t)node * 96;
  float v0 = xrow[l];
  float v1, v2, v3;

  bool hi = (l >= 32);
  int d = l & 31;

  {
    float s = 0.f, c = 0.f;
#pragma unroll
    for (int j = 0; j < 16; j++) {
      int id = __shfl(myidx, j);
      if (hi && id != 0) { s += eo[(size_t)id * 32 + d]; c += 1.f; }
    }
    float sc = hi ? 0.f : xrow[64 + l];
    v1 = hi ? (s / (c + 1e-9f)) : sc;
  }
  {
    const float* tab = hi ? ek : es;
    int base = hi ? 24 : 16;
    float s = 0.f, c = 0.f;
#pragma unroll
    for (int j = 0; j < 8; j++) {
      int id = __shfl(myidx, base + j);
      if (id != 0) { s += tab[(size_t)id * 32 + d]; c += 1.f; }
    }
    v2 = s / (c + 1e-9f);
  }
  {
    const float* tab = hi ? ep : et;
    int base = hi ? 40 : 32;
    float s = 0.f, c = 0.f;
#pragma unroll
    for (int j = 0; j < 8; j++) {
      int id = __shfl(myidx, base + j);
      if (id != 0) { s += tab[(size_t)id * 32 + d]; c += 1.f; }
    }
    v3 = s / (c + 1e-9f);
  }

  float sum = v0 + v1 + v2 + v3;
  for (int o = 32; o; o >>= 1) sum += __shfl_xor(sum, o);
  float mu = sum * (1.f / 256.f);

  float d0 = v0 - mu, d1 = v1 - mu, d2 = v2 - mu, d3 = v3 - mu;
  float q = d0 * d0 + d1 * d1 + d2 * d2 + d3 * d3;
  for (int o = 32; o; o >>= 1) q += __shfl_xor(q, o);
  float rstd = rsqrtf(q * (1.f / 256.f) + 1e-5f);

  _Float16* frow = feats + (size_t)node * 256;
  frow[l]       = (_Float16)(d0 * rstd * lng[l] + lnb[l]);
  frow[64 + l]  = (_Float16)(d1 * rstd * lng[64 + l] + lnb[64 + l]);
  frow[128 + l] = (_Float16)(d2 * rstd * lng[128 + l] + lnb[128 + l]);
  frow[192 + l] = (_Float16)(d3 * rstd * lng[192 + l] + lnb[192 + l]);
}

// ------------- weight transpose + fp16 convert (both weights, one launch) ---
__global__ __launch_bounds__(256) void transpose_both_f16(
    const float* __restrict__ W1, _Float16* __restrict__ Wt1,
    const float* __restrict__ W2, _Float16* __restrict__ Wt2) {
  int t = blockIdx.x * 256 + threadIdx.x;
  if (t < 256 * 512) {
    int n = t / 256, k = t - n * 256;      // Wt1[n*256+k] = W1[k*512+n]
    Wt1[t] = (_Float16)W1[(size_t)k * 512 + n];
  } else {
    int u = t - 256 * 512;                 // Wt2[n*512+k] = W2[k*128+n]
    int n = u / 512, k = u - n * 512;
    Wt2[u] = (_Float16)W2[(size_t)k * 128 + n];
  }
}

// ------------- fp16 MFMA GEMM + fused attention dots ------------------------
// A: Mpad x K (row-major fp16, padded rows garbage), Bt: N x K, C: Mpad x N.
// 128x128 tile, 4 waves of 64x64, 16x16x32 MFMA, fp32 accum.
// LDS tiles via global_load_lds(16B) with XOR swizzle (unpadded).
// Epilogue: per-head attention dots from the accumulators (fp32).
__global__ __launch_bounds__(256) void gemm_f16_att(
    const _Float16* __restrict__ A, const _Float16* __restrict__ Bt,
    _Float16* __restrict__ C, const float* __restrict__ att_src,
    const float* __restrict__ att_dst, float* __restrict__ a_src_out,
    float* __restrict__ a_dst_out, int astride, int K, int N) {
  __shared__ __attribute__((aligned(16))) _Float16 As[128 * 32];
  __shared__ __attribute__((aligned(16))) _Float16 Bs[128 * 32];
  int m0 = blockIdx.y * 128;
  int n0 = blockIdx.x * 128;
  int tid = threadIdx.x;
  int wave = tid >> 6, lane = tid & 63;
  int wm = (wave >> 1) * 64, wn = (wave & 1) * 64;
  int lr = lane & 15, lq = lane >> 4;
  int wbase = tid & ~63;  // wave*64

  floatx4 acc[4][4] = {};

  for (int k0 = 0; k0 < K; k0 += 32) {
#pragma unroll
    for (int c = 0; c < 2; c++) {
      int sid = c * 256 + tid;
      int row = sid >> 2;
      int cs = (sid & 3) ^ (row & 3);
      const _Float16* ga = A + (size_t)(m0 + row) * K + k0 + cs * 8;
      const _Float16* gb = Bt + (size_t)(n0 + row) * K + k0 + cs * 8;
      async_copy16(ga, As + (size_t)(c * 256 + wbase) * 8);
      async_copy16(gb, Bs + (size_t)(c * 256 + wbase) * 8);
    }
    __syncthreads();

    half8 af[4], bf[4];
#pragma unroll
    for (int i = 0; i < 4; i++) {
      int row = wm + i * 16 + lr;
      af[i] = *(const half8*)(As + ((row << 2) + (lq ^ (row & 3))) * 8);
    }
#pragma unroll
    for (int j = 0; j < 4; j++) {
      int row = wn + j * 16 + lr;
      bf[j] = *(const half8*)(Bs + ((row << 2) + (lq ^ (row & 3))) * 8);
    }
#pragma unroll
    for (int i = 0; i < 4; i++)
#pragma unroll
      for (int j = 0; j < 4; j++)
        acc[i][j] =
            __builtin_amdgcn_mfma_f32_16x16x32_f16(af[i], bf[j], acc[i][j], 0, 0, 0);
    __syncthreads();
  }

  // C store (padded rows exist in C, no guard needed)
#pragma unroll
  for (int i = 0; i < 4; i++) {
    int rbase = m0 + wm + i * 16 + lq * 4;
#pragma unroll
    for (int r = 0; r < 4; r++) {
      int row = rbase + r;
#pragma unroll
      for (int j = 0; j < 4; j++) {
        int col = n0 + wn + j * 16 + lr;
        C[(size_t)row * N + col] = (_Float16)acc[i][j][r];
      }
    }
  }

  // fused attention dots epilogue
  float asv[4], adv[4];
#pragma unroll
  for (int j = 0; j < 4; j++) {
    int col = n0 + wn + j * 16 + lr;
    asv[j] = att_src[col];
    adv[j] = att_dst[col];
  }
  float ps[4][4], pd[4][4];
#pragma unroll
  for (int i = 0; i < 4; i++)
#pragma unroll
    for (int r = 0; r < 4; r++) {
      float s = 0.f, d = 0.f;
#pragma unroll
      for (int j = 0; j < 4; j++) {
        s += acc[i][j][r] * asv[j];
        d += acc[i][j][r] * adv[j];
      }
#pragma unroll
      for (int o = 1; o < 16; o <<= 1) {
        s += __shfl_xor(s, o);
        d += __shfl_xor(d, o);
      }
      ps[i][r] = s;
      pd[i][r] = d;
    }
  float* sred = (float*)&As[0];  // reuse LDS (post-loop barrier already done)
  if (wn == 64 && lr == 0) {
#pragma unroll
    for (int i = 0; i < 4; i++)
#pragma unroll
      for (int r = 0; r < 4; r++) {
        int rl = wm + i * 16 + lq * 4 + r;
        sred[rl * 2] = ps[i][r];
        sred[rl * 2 + 1] = pd[i][r];
      }
  }
  __syncthreads();
  if (wn == 0 && lr == 0) {
    int hsel = n0 >> 7;
#pragma unroll
    for (int i = 0; i < 4; i++)
#pragma unroll
      for (int r = 0; r < 4; r++) {
        int rl = wm + i * 16 + lq * 4 + r;
        int row = m0 + rl;
        a_src_out[(size_t)row * astride + hsel] = ps[i][r] + sred[rl * 2];
        a_dst_out[(size_t)row * astride + hsel] = pd[i][r] + sred[rl * 2 + 1];
      }
  }
}

// ---------------------- CSR build -------------------------------------------
__global__ __launch_bounds__(256) void hist_kernel(const int* __restrict__ dst,
                                                   int* __restrict__ deg, int E) {
  int t = blockIdx.x * 256 + threadIdx.x;
  if (t < E) atomicAdd(&deg[dst[t]], 1);
}

// 3-phase parallel exclusive scan of (deg[i]+1)
__global__ __launch_bounds__(256) void scan_a(const int* __restrict__ deg,
                                              int* __restrict__ rowptr,
                                              int* __restrict__ bsum, int n) {
  __shared__ int sh[256];
  int b = blockIdx.x, t = threadIdx.x;
  int i = b * 256 + t;
  int v = (i < n) ? deg[i] + 1 : 0;
  sh[t] = v;
  __syncthreads();
  int x = v;
  for (int o = 1; o < 256; o <<= 1) {
    int y = (t >= o) ? sh[t - o] : 0;
    __syncthreads();
    x += y;
    sh[t] = x;
    __syncthreads();
  }
  if (i < n) rowptr[i] = x - v;  // exclusive within block
  if (t == 255) bsum[b] = x;     // block total
}

__global__ __launch_bounds__(256) void scan_b(int* __restrict__ bsum, int nb) {
  __shared__ int sh[256];
  int t = threadIdx.x;
  int v = (t < nb) ? bsum[t] : 0;
  sh[t] = v;
  __syncthreads();
  int x = v;
  for (int o = 1; o < 256; o <<= 1) {
    int y = (t >= o) ? sh[t - o] : 0;
    __syncthreads();
    x += y;
    sh[t] = x;
    __syncthreads();
  }
  if (t < nb) bsum[t] = x - v;  // exclusive block offsets
}

__global__ __launch_bounds__(256) void scan_c(int* __restrict__ rowptr,
                                              const int* __restrict__ bsum,
                                              int n, int total) {
  int i = blockIdx.x * 256 + threadIdx.x;
  if (i < n) rowptr[i] += bsum[blockIdx.x];
  else if (i == n) rowptr[n] = total;
}

__global__ __launch_bounds__(256) void fill_kernel(
    const int* __restrict__ src, const int* __restrict__ dst,
    const int* __restrict__ rowptr, int* __restrict__ cnt,
    int* __restrict__ csr_src, int E, int n) {
  int t = blockIdx.x * 256 + threadIdx.x;
  if (t < E) {
    int d = dst[t];
    int pos = rowptr[d] + atomicAdd(&cnt[d], 1);
    csr_src[pos] = src[t];
  } else if (t < E + n) {
    int i = t - E;
    csr_src[rowptr[i + 1] - 1] = i;  // self loop in the last slot
  }
}

// ---------------------- GAT aggregation (conv1: 4 heads x 128) --------------
__global__ __launch_bounds__(256) void gat1_agg(
    const _Float16* __restrict__ h1, const float* __restrict__ asrc,
    const float* __restrict__ adst, const int* __restrict__ rowptr,
    const int* __restrict__ csr_src, const float* __restrict__ bias,
    _Float16* __restrict__ out, int n) {
  int node = blockIdx.x * 4 + (threadIdx.x >> 6);
  if (node >= n) return;
  int l = threadIdx.x & 63;
  int hh = l >> 4;
  int li = l & 15;
  int r0 = rowptr[node];
  int deg = rowptr[node + 1] - r0;
  int cb = l * 8;

  float acc[8] = {};

  if (deg <= 64) {
    float adm = adst[node * 4 + hh];
    int s_reg[4];
    float ww[4];
    float m = -1e30f;
#pragma unroll
    for (int c = 0; c < 4; c++) {
      int k = c * 16 + li;
      int s = (k < deg) ? csr_src[r0 + k] : -1;
      s_reg[c] = s;
      float e = -1e30f;
      if (s >= 0) {
        float t = asrc[(size_t)s * 4 + hh] + adm;
        e = LEAKY(t);
      }
      ww[c] = e;
      m = fmaxf(m, e);
    }
#pragma unroll
    for (int o = 1; o < 16; o <<= 1) m = fmaxf(m, __shfl_xor(m, o));
    float sum = 0.f;
#pragma unroll
    for (int c = 0; c < 4; c++) {
      float w = (s_reg[c] >= 0) ? __expf(ww[c] - m) : 0.f;
      ww[c] = w;
      sum += w;
    }
#pragma unroll
    for (int o = 1; o < 16; o <<= 1) sum += __shfl_xor(sum, o);
    float sinv = 1.f / (sum + 1e-16f);
#pragma unroll
    for (int c = 0; c < 4; c++) ww[c] *= sinv;

#pragma unroll
    for (int c = 0; c < 4; c++) {
      int base = c * 16;
      if (base >= deg) break;
      int lim = min(16, deg - base);
      int jl = 0;
      for (; jl + 4 <= lim; jl += 4) {  // 4-wide: 4 gathers in flight
        int s0 = __shfl(s_reg[c], jl);
        int s1 = __shfl(s_reg[c], jl + 1);
        int s2 = __shfl(s_reg[c], jl + 2);
        int s3 = __shfl(s_reg[c], jl + 3);
        float w0 = __shfl(ww[c], hh * 16 + jl);
        float w1 = __shfl(ww[c], hh * 16 + jl + 1);
        float w2 = __shfl(ww[c], hh * 16 + jl + 2);
        float w3 = __shfl(ww[c], hh * 16 + jl + 3);
        const half8 hv0 = *(const half8*)(h1 + (size_t)s0 * 512 + cb);
        const half8 hv1 = *(const half8*)(h1 + (size_t)s1 * 512 + cb);
        const half8 hv2 = *(const half8*)(h1 + (size_t)s2 * 512 + cb);
        const half8 hv3 = *(const half8*)(h1 + (size_t)s3 * 512 + cb);
#pragma unroll
        for (int q = 0; q < 8; q++)
          acc[q] += w0 * (float)hv0[q] + w1 * (float)hv1[q] +
                    w2 * (float)hv2[q] + w3 * (float)hv3[q];
      }
      for (; jl < lim; jl++) {
        int s0 = __shfl(s_reg[c], jl);
        float w0 = __shfl(ww[c], hh * 16 + jl);
        const half8 hv0 = *(const half8*)(h1 + (size_t)s0 * 512 + cb);
#pragma unroll
        for (int q = 0; q < 8; q++) acc[q] += w0 * (float)hv0[q];
      }
    }
  } else {
    // fallback (deg>64, astronomically rare at E/N=10): 3-pass
    float4 ad4 = *(const float4*)(adst + node * 4);
    float adv[4] = {ad4.x, ad4.y, ad4.z, ad4.w};
    float m[4] = {-1e30f, -1e30f, -1e30f, -1e30f};
    for (int k = l; k < deg; k += 64) {
      int s = csr_src[r0 + k];
      float4 av = *(const float4*)(asrc + (size_t)s * 4);
      float e;
      e = LEAKY(av.x + adv[0]); m[0] = fmaxf(m[0], e);
      e = LEAKY(av.y + adv[1]); m[1] = fmaxf(m[1], e);
      e = LEAKY(av.z + adv[2]); m[2] = fmaxf(m[2], e);
      e = LEAKY(av.w + adv[3]); m[3] = fmaxf(m[3], e);
    }
    for (int o = 1; o < 64; o <<= 1) {
#pragma unroll
      for (int h = 0; h < 4; h++) m[h] = fmaxf(m[h], __shfl_xor(m[h], o));
    }
    float sum[4] = {0.f, 0.f, 0.f, 0.f};
    for (int k = l; k < deg; k += 64) {
      int s = csr_src[r0 + k];
      float4 av = *(const float4*)(asrc + (size_t)s * 4);
      float e;
      e = LEAKY(av.x + adv[0]); sum[0] += __expf(e - m[0]);
      e = LEAKY(av.y + adv[1]); sum[1] += __expf(e - m[1]);
      e = LEAKY(av.z + adv[2]); sum[2] += __expf(e - m[2]);
      e = LEAKY(av.w + adv[3]); sum[3] += __expf(e - m[3]);
    }
    for (int o = 1; o < 64; o <<= 1) {
#pragma unroll
      for (int h = 0; h < 4; h++) sum[h] += __shfl_xor(sum[h], o);
    }
    float mm = m[hh];
    float sinv = 1.f / (sum[hh] + 1e-16f);
    float adm = adv[hh];
    for (int k = 0; k < deg; k++) {
      int s = csr_src[r0 + k];
      float a = asrc[(size_t)s * 4 + hh];
      float e = LEAKY(a + adm);
      float w = __expf(e - mm) * sinv;
      const half8 hv = *(const half8*)(h1 + (size_t)s * 512 + cb);
#pragma unroll
      for (int q = 0; q < 8; q++) acc[q] += w * (float)hv[q];
    }
  }

  const float* bp = bias + cb;
  half8 ov;
#pragma unroll
  for (int j = 0; j < 8; j++) {
    float r = acc[j] + bp[j];
    ov[j] = (_Float16)(r > 0.f ? r : (__expf(r) - 1.f));  // ELU
  }
  *(half8*)(out + (size_t)node * 512 + cb) = ov;
}

// ---------------------- GAT aggregation (conv2: 1 head x 128) ---------------
__global__ __launch_bounds__(256) void gat2_agg(
    const _Float16* __restrict__ h2, const float* __restrict__ asrc,
    const float* __restrict__ adst, const int* __restrict__ rowptr,
    const int* __restrict__ csr_src, const float* __restrict__ bias,
    float* __restrict__ out, int n) {
  int node = blockIdx.x * 4 + (threadIdx.x >> 6);
  if (node >= n) return;
  int l = threadIdx.x & 63;
  int r0 = rowptr[node];
  int deg = rowptr[node + 1] - r0;
  int cb = l * 2;
  float a0 = 0.f, a1 = 0.f;

  if (deg <= 64) {
    float ad = adst[node];
    int s = (l < deg) ? csr_src[r0 + l] : -1;
    float e = -1e30f;
    if (s >= 0) {
      float t = asrc[s] + ad;
      e = LEAKY(t);
    }
    float m = e;
    for (int o = 1; o < 64; o <<= 1) m = fmaxf(m, __shfl_xor(m, o));
    float w = (s >= 0) ? __expf(e - m) : 0.f;
    float sum = w;
    for (int o = 1; o < 64; o <<= 1) sum += __shfl_xor(sum, o);
    w *= 1.f / (sum + 1e-16f);
    int j = 0;
    for (; j + 4 <= deg; j += 4) {  // 4-wide: 4 gathers in flight
      int s0 = __shfl(s, j);
      int s1 = __shfl(s, j + 1);
      int s2 = __shfl(s, j + 2);
      int s3 = __shfl(s, j + 3);
      float w0 = __shfl(w, j);
      float w1 = __shfl(w, j + 1);
      float w2 = __shfl(w, j + 2);
      float w3 = __shfl(w, j + 3);
      const _Float16* hp0 = h2 + (size_t)s0 * 128 + cb;
      const _Float16* hp1 = h2 + (size_t)s1 * 128 + cb;
      const _Float16* hp2 = h2 + (size_t)s2 * 128 + cb;
      const _Float16* hp3 = h2 + (size_t)s3 * 128 + cb;
      float p00 = (float)hp0[0], p01 = (float)hp0[1];
      float p10 = (float)hp1[0], p11 = (float)hp1[1];
      float p20 = (float)hp2[0], p21 = (float)hp2[1];
      float p30 = (float)hp3[0], p31 = (float)hp3[1];
      a0 += w0 * p00 + w1 * p10 + w2 * p20 + w3 * p30;
      a1 += w0 * p01 + w1 * p11 + w2 * p21 + w3 * p31;
    }
    for (; j < deg; j++) {
      int sj = __shfl(s, j);
      float wj = __shfl(w, j);
      const _Float16* hp = h2 + (size_t)sj * 128 + cb;
      a0 += wj * (float)hp[0];
      a1 += wj * (float)hp[1];
    }
  } else {
    float ad = adst[node];
    float m = -1e30f;
    for (int k = l; k < deg; k += 64) {
      int s = csr_src[r0 + k];
      float e = LEAKY(asrc[s] + ad);
      m = fmaxf(m, e);
    }
    for (int o = 1; o < 64; o <<= 1) m = fmaxf(m, __shfl_xor(m, o));
    float sum = 0.f;
    for (int k = l; k < deg; k += 64) {
      int s = csr_src[r0 + k];
      float e = LEAKY(asrc[s] + ad);
      sum += __expf(e - m);
    }
    for (int o = 1; o < 64; o <<= 1) sum += __shfl_xor(sum, o);
    float sinv = 1.f / (sum + 1e-16f);
    for (int k = 0; k < deg; k++) {
      int s = csr_src[r0 + k];
      float e = LEAKY(asrc[s] + ad);
      float w = __expf(e - m) * sinv;
      const _Float16* hp = h2 + (size_t)s * 128 + cb;
      a0 += w * (float)hp[0];
      a1 += w * (float)hp[1];
    }
  }

  float ra = a0 + bias[cb];
  float rb = a1 + bias[cb + 1];
  out[(size_t)node * 128 + cb]     = ra > 0.f ? ra : (__expf(ra) - 1.f);
  out[(size_t)node * 128 + cb + 1] = rb > 0.f ? rb : (__expf(rb) - 1.f);
}

// ---------------------- per-graph max pool (2-stage) ------------------------
__device__ inline int lower_bound_i(const int* a, int n, int v) {
  int lo = 0, hi = n;
  while (lo < hi) {
    int mid = (lo + hi) >> 1;
    if (a[mid] < v) lo = mid + 1; else hi = mid;
  }
  return lo;
}

__global__ __launch_bounds__(128) void pool_partial(
    const float* __restrict__ x2, const int* __restrict__ batch,
    float* __restrict__ partial, int n) {
  int g = blockIdx.y;
  int j = blockIdx.x;
  int t = threadIdx.x;
  int start = lower_bound_i(batch, n, g);
  int end = lower_bound_i(batch, n, g + 1);
  int len = end - start;
  int c0 = start + (int)((long long)len * j / POOL_CH);
  int c1 = start + (int)((long long)len * (j + 1) / POOL_CH);
  float m = -FLT_MAX;
  for (int i = c0; i < c1; i++) m = fmaxf(m, x2[(size_t)i * 128 + t]);
  partial[((size_t)g * POOL_CH + j) * 128 + t] = m;
}

__global__ __launch_bounds__(128) void pool_final(
    const float* __restrict__ partial, float* __restrict__ pool) {
  int g = blockIdx.x;
  int t = threadIdx.x;
  float m = -FLT_MAX;
#pragma unroll
  for (int j = 0; j < POOL_CH; j++)
    m = fmaxf(m, partial[((size_t)g * POOL_CH + j) * 128 + t]);
  pool[g * 128 + t] = m;
}

// ---------------------- classifier ------------------------------------------
__global__ __launch_bounds__(64) void classifier_kernel(
    const float* __restrict__ pool, const float* __restrict__ Wc1,
    const float* __restrict__ bc1, const float* __restrict__ Wc2,
    const float* __restrict__ bc2, float* __restrict__ out) {
  int g = blockIdx.x;
  int t = threadIdx.x;
  __shared__ float xp[128];
  __shared__ float hc[64];
  xp[t] = pool[g * 128 + t];
  xp[t + 64] = pool[g * 128 + 64 + t];
  __syncthreads();
  float s = bc1[t];
  for (int k = 0; k < 128; k++) s += xp[k] * Wc1[k * 64 + t];
  hc[t] = s > 0.f ? s : 0.f;
  __syncthreads();
  if (t < 5) {
    float o = bc2[t];
    for (int j = 0; j < 64; j++) o += hc[j] * Wc2[j * 5 + t];
    out[g * 5 + t] = o;
  }
}

// ---------------------------------------------------------------------------
extern "C" void kernel_launch(void* const* d_in, const int* in_sizes, int n_in,
                              void* d_out, int out_size, void* d_ws, size_t ws_size,
                              hipStream_t stream) {
  const float* x_scalar = (const float*)d_in[0];
  const int* x_opcode = (const int*)d_in[1];
  const int* x_source = (const int*)d_in[2];
  const int* x_sink = (const int*)d_in[3];
  const int* x_string = (const int*)d_in[4];
  const int* x_payload = (const int*)d_in[5];
  const int* edge_index = (const int*)d_in[6];
  const int* batch = (const int*)d_in[7];
  const float* emb_opcode = (const float*)d_in[8];
  const float* emb_source = (const float*)d_in[9];
  const float* emb_sink = (const float*)d_in[10];
  const float* emb_string = (const float*)d_in[11];
  const float* emb_payload = (const float*)d_in[12];
  const float* ln_g = (const float*)d_in[13];
  const float* ln_b = (const float*)d_in[14];
  const float* W1 = (const float*)d_in[15];
  const float* att_src1 = (const float*)d_in[16];
  const float* att_dst1 = (const float*)d_in[17];
  const float* b1 = (const float*)d_in[18];
  const float* W2 = (const float*)d_in[19];
  const float* att_src2 = (const float*)d_in[20];
  const float* att_dst2 = (const float*)d_in[21];
  const float* b2 = (const float*)d_in[22];
  const float* Wc1 = (const float*)d_in[23];
  const float* bc1 = (const float*)d_in[24];
  const float* Wc2 = (const float*)d_in[25];
  const float* bc2 = (const float*)d_in[26];
  float* out = (float*)d_out;

  const int N = in_sizes[0] / 96;
  const int E = in_sizes[6] / 2;
  const int G = out_size / 5;
  const int Npad = (N + 127) / 128 * 128;  // GEMM row padding

  const int* e_src = edge_index;
  const int* e_dst = edge_index + E;

  // ---- workspace layout with aliasing (lifetime-checked; ws ~171.6 MB) ----
  char* w = (char*)d_ws;
  size_t o = 0;
  auto take = [&](size_t bytes) -> void* {
    void* p = w + o;
    o += (bytes + 255) & ~(size_t)255;
    return p;
  };
  char* regionA = (char*)take((size_t)Npad * 256 * 2);
  char* regionB = (char*)take((size_t)Npad * 512 * 2);
  _Float16* x1 = (_Float16*)take((size_t)Npad * 512 * 2);
  _Float16* Wt1 = (_Float16*)take((size_t)512 * 256 * 2);
  _Float16* Wt2 = (_Float16*)take((size_t)128 * 512 * 2);
  float* a_src1 = (float*)take((size_t)Npad * 4 * 4);
  float* a_dst1 = (float*)take((size_t)Npad * 4 * 4);
  float* a_src2 = (float*)take((size_t)Npad * 4);
  float* a_dst2 = (float*)take((size_t)Npad * 4);
  int* deg = (int*)take((size_t)N * 2 * 4);  // deg + cnt contiguous
  int* cnt = deg + N;
  int* rowptr = (int*)take((size_t)(N + 1) * 4);
  int* csr_src = (int*)take((size_t)(E + N) * 4);
  int* bsum = (int*)take(256 * 4);
  // total ~133.3 MB < ws_size (bracketed by R3 pass / R4 fail)

  _Float16* feats = (_Float16*)regionA;
  _Float16* h2 = (_Float16*)regionA;  // feats dead after gemm1
  float* partial = (float*)(regionA + (((size_t)Npad * 128 * 2 + 255) & ~(size_t)255));
  float* pool = partial + (size_t)G * POOL_CH * 128;
  _Float16* h1 = (_Float16*)regionB;
  float* x2 = (float*)regionB;        // h1 dead after gat1_agg

  hipMemsetAsync(deg, 0, (size_t)N * 2 * 4, stream);

  // CSR build (independent of features)
  hist_kernel<<<(E + 255) / 256, 256, 0, stream>>>(e_dst, deg, E);
  int nb = (N + 255) / 256;
  scan_a<<<nb, 256, 0, stream>>>(deg, rowptr, bsum, N);
  scan_b<<<1, 256, 0, stream>>>(bsum, nb);
  scan_c<<<(N + 256) / 256, 256, 0, stream>>>(rowptr, bsum, N, E + N);
  fill_kernel<<<(E + N + 255) / 256, 256, 0, stream>>>(e_src, e_dst, rowptr, cnt,
                                                       csr_src, E, N);

  // weights -> transposed fp16 (one launch for both)
  transpose_both_f16<<<(256 * 512 + 512 * 128 + 255) / 256, 256, 0, stream>>>(
      W1, Wt1, W2, Wt2);

  // features + LN (fp16 out), wave-per-node
  feats_kernel<<<(N + 3) / 4, 256, 0, stream>>>(
      x_scalar, x_opcode, x_source, x_sink, x_string, x_payload, emb_opcode,
      emb_source, emb_sink, emb_string, emb_payload, ln_g, ln_b, feats, N);

  int mblocks = Npad / 128;
  // conv1: h1 = feats @ W1 (K=256, N=512) + fused a_src1/a_dst1 (4 heads)
  gemm_f16_att<<<dim3(512 / 128, mblocks), 256, 0, stream>>>(
      feats, Wt1, h1, att_src1, att_dst1, a_src1, a_dst1, 4, 256, 512);
  gat1_agg<<<(N + 3) / 4, 256, 0, stream>>>(h1, a_src1, a_dst1, rowptr, csr_src,
                                            b1, x1, N);

  // conv2: h2 = x1 @ W2 (K=512, N=128) + fused a_src2/a_dst2 (1 head)
  gemm_f16_att<<<dim3(128 / 128, mblocks), 256, 0, stream>>>(
      x1, Wt2, h2, att_src2, att_dst2, a_src2, a_dst2, 1, 512, 128);
  gat2_agg<<<(N + 3) / 4, 256, 0, stream>>>(h2, a_src2, a_dst2, rowptr, csr_src,
                                            b2, x2, N);

  // pool (2-stage) + classifier
  pool_partial<<<dim3(POOL_CH, G), 128, 0, stream>>>(x2, batch, partial, N);
  pool_final<<<G, 128, 0, stream>>>(partial, pool);
  classifier_kernel<<<G, 64, 0, stream>>>(pool, Wc1, bc1, Wc2, bc2, out);
}

// Round 9
// 440.430 us; speedup vs baseline: 2.5797x; 1.0031x over previous
//
#include <hip/hip_runtime.h>
#include <hip/hip_bf16.h>
#include <float.h>

// ---------------------------------------------------------------------------
// GlobalFeatureGAT: feature-build+LN -> GAT(4 heads,128) -> ELU -> GAT(1,128)
// -> ELU -> per-graph max pool -> MLP(128->64->5).
// R9: gat2_agg gather restructured (4 edges in flight, 16B half8 loads,
// cross-subgroup shfl reduce) — gat1-style; x2 stored fp16; scan_b folded
// into scan_c. gat1_agg measured at delivered-BW roofline (6.4 TB/s) — frozen.
// N=50000, E=500000 (+N self loops), G=64, IN_DIM=256, C=128, H1=4.
// ---------------------------------------------------------------------------

#define LEAKY(e) ((e) > 0.f ? (e) : 0.2f * (e))
#define POOL_CH 32  // chunks per graph in stage-1 pool

typedef _Float16 half8 __attribute__((ext_vector_type(8)));
typedef float floatx4 __attribute__((ext_vector_type(4)));

__device__ __forceinline__ void async_copy16(const _Float16* gsrc,
                                             const _Float16* ldst) {
  __builtin_amdgcn_global_load_lds(
      (const __attribute__((address_space(1))) unsigned int*)gsrc,
      (__attribute__((address_space(3))) unsigned int*)ldst, 16, 0, 0);
}

// ---------------------- feature build + layernorm (fp16 out) ----------------
// One wave per node. Lane l owns channels {l, 64+l, 128+l, 192+l}.
__global__ __launch_bounds__(256) void feats_kernel(
    const float* __restrict__ xs, const int* __restrict__ xo,
    const int* __restrict__ xsrc, const int* __restrict__ xsk,
    const int* __restrict__ xst, const int* __restrict__ xp,
    const float* __restrict__ eo, const float* __restrict__ es,
    const float* __restrict__ ek, const float* __restrict__ et,
    const float* __restrict__ ep, const float* __restrict__ lng,
    const float* __restrict__ lnb, _Float16* __restrict__ feats, int n) {
  int node = blockIdx.x * 4 + (threadIdx.x >> 6);
  if (node >= n) return;
  int l = threadIdx.x & 63;

  int myidx = 0;
  if (l < 16)      myidx = xo[node * 16 + l];
  else if (l < 24) myidx = xsrc[node * 8 + (l - 16)];
  else if (l < 32) myidx = xsk[node * 8 + (l - 24)];
  else if (l < 40) myidx = xst[node * 8 + (l - 32)];
  else if (l < 48) myidx = xp[node * 8 + (l - 40)];

  const float* xrow = xs + (size_t)node * 96;
  float v0 = xrow[l];
  float v1, v2, v3;

  bool hi = (l >= 32);
  int d = l & 31;

  {
    float s = 0.f, c = 0.f;
#pragma unroll
    for (int j = 0; j < 16; j++) {
      int id = __shfl(myidx, j);
      if (hi && id != 0) { s += eo[(size_t)id * 32 + d]; c += 1.f; }
    }
    float sc = hi ? 0.f : xrow[64 + l];
    v1 = hi ? (s / (c + 1e-9f)) : sc;
  }
  {
    const float* tab = hi ? ek : es;
    int base = hi ? 24 : 16;
    float s = 0.f, c = 0.f;
#pragma unroll
    for (int j = 0; j < 8; j++) {
      int id = __shfl(myidx, base + j);
      if (id != 0) { s += tab[(size_t)id * 32 + d]; c += 1.f; }
    }
    v2 = s / (c + 1e-9f);
  }
  {
    const float* tab = hi ? ep : et;
    int base = hi ? 40 : 32;
    float s = 0.f, c = 0.f;
#pragma unroll
    for (int j = 0; j < 8; j++) {
      int id = __shfl(myidx, base + j);
      if (id != 0) { s += tab[(size_t)id * 32 + d]; c += 1.f; }
    }
    v3 = s / (c + 1e-9f);
  }

  float sum = v0 + v1 + v2 + v3;
  for (int o = 32; o; o >>= 1) sum += __shfl_xor(sum, o);
  float mu = sum * (1.f / 256.f);

  float d0 = v0 - mu, d1 = v1 - mu, d2 = v2 - mu, d3 = v3 - mu;
  float q = d0 * d0 + d1 * d1 + d2 * d2 + d3 * d3;
  for (int o = 32; o; o >>= 1) q += __shfl_xor(q, o);
  float rstd = rsqrtf(q * (1.f / 256.f) + 1e-5f);

  _Float16* frow = feats + (size_t)node * 256;
  frow[l]       = (_Float16)(d0 * rstd * lng[l] + lnb[l]);
  frow[64 + l]  = (_Float16)(d1 * rstd * lng[64 + l] + lnb[64 + l]);
  frow[128 + l] = (_Float16)(d2 * rstd * lng[128 + l] + lnb[128 + l]);
  frow[192 + l] = (_Float16)(d3 * rstd * lng[192 + l] + lnb[192 + l]);
}

// ------------- weight transpose + fp16 convert (both weights, one launch) ---
__global__ __launch_bounds__(256) void transpose_both_f16(
    const float* __restrict__ W1, _Float16* __restrict__ Wt1,
    const float* __restrict__ W2, _Float16* __restrict__ Wt2) {
  int t = blockIdx.x * 256 + threadIdx.x;
  if (t < 256 * 512) {
    int n = t / 256, k = t - n * 256;      // Wt1[n*256+k] = W1[k*512+n]
    Wt1[t] = (_Float16)W1[(size_t)k * 512 + n];
  } else {
    int u = t - 256 * 512;                 // Wt2[n*512+k] = W2[k*128+n]
    int n = u / 512, k = u - n * 512;
    Wt2[u] = (_Float16)W2[(size_t)k * 128 + n];
  }
}

// ------------- fp16 MFMA GEMM + fused attention dots ------------------------
// A: Mpad x K (row-major fp16, padded rows garbage), Bt: N x K, C: Mpad x N.
// 128x128 tile, 4 waves of 64x64, 16x16x32 MFMA, fp32 accum.
// LDS tiles via global_load_lds(16B) with XOR swizzle (unpadded).
// Epilogue: per-head attention dots from the accumulators (fp32).
__global__ __launch_bounds__(256) void gemm_f16_att(
    const _Float16* __restrict__ A, const _Float16* __restrict__ Bt,
    _Float16* __restrict__ C, const float* __restrict__ att_src,
    const float* __restrict__ att_dst, float* __restrict__ a_src_out,
    float* __restrict__ a_dst_out, int astride, int K, int N) {
  __shared__ __attribute__((aligned(16))) _Float16 As[128 * 32];
  __shared__ __attribute__((aligned(16))) _Float16 Bs[128 * 32];
  int m0 = blockIdx.y * 128;
  int n0 = blockIdx.x * 128;
  int tid = threadIdx.x;
  int wave = tid >> 6, lane = tid & 63;
  int wm = (wave >> 1) * 64, wn = (wave & 1) * 64;
  int lr = lane & 15, lq = lane >> 4;
  int wbase = tid & ~63;  // wave*64

  floatx4 acc[4][4] = {};

  for (int k0 = 0; k0 < K; k0 += 32) {
#pragma unroll
    for (int c = 0; c < 2; c++) {
      int sid = c * 256 + tid;
      int row = sid >> 2;
      int cs = (sid & 3) ^ (row & 3);
      const _Float16* ga = A + (size_t)(m0 + row) * K + k0 + cs * 8;
      const _Float16* gb = Bt + (size_t)(n0 + row) * K + k0 + cs * 8;
      async_copy16(ga, As + (size_t)(c * 256 + wbase) * 8);
      async_copy16(gb, Bs + (size_t)(c * 256 + wbase) * 8);
    }
    __syncthreads();

    half8 af[4], bf[4];
#pragma unroll
    for (int i = 0; i < 4; i++) {
      int row = wm + i * 16 + lr;
      af[i] = *(const half8*)(As + ((row << 2) + (lq ^ (row & 3))) * 8);
    }
#pragma unroll
    for (int j = 0; j < 4; j++) {
      int row = wn + j * 16 + lr;
      bf[j] = *(const half8*)(Bs + ((row << 2) + (lq ^ (row & 3))) * 8);
    }
#pragma unroll
    for (int i = 0; i < 4; i++)
#pragma unroll
      for (int j = 0; j < 4; j++)
        acc[i][j] =
            __builtin_amdgcn_mfma_f32_16x16x32_f16(af[i], bf[j], acc[i][j], 0, 0, 0);
    __syncthreads();
  }

  // C store (padded rows exist in C, no guard needed)
#pragma unroll
  for (int i = 0; i < 4; i++) {
    int rbase = m0 + wm + i * 16 + lq * 4;
#pragma unroll
    for (int r = 0; r < 4; r++) {
      int row = rbase + r;
#pragma unroll
      for (int j = 0; j < 4; j++) {
        int col = n0 + wn + j * 16 + lr;
        C[(size_t)row * N + col] = (_Float16)acc[i][j][r];
      }
    }
  }

  // fused attention dots epilogue
  float asv[4], adv[4];
#pragma unroll
  for (int j = 0; j < 4; j++) {
    int col = n0 + wn + j * 16 + lr;
    asv[j] = att_src[col];
    adv[j] = att_dst[col];
  }
  float ps[4][4], pd[4][4];
#pragma unroll
  for (int i = 0; i < 4; i++)
#pragma unroll
    for (int r = 0; r < 4; r++) {
      float s = 0.f, d = 0.f;
#pragma unroll
      for (int j = 0; j < 4; j++) {
        s += acc[i][j][r] * asv[j];
        d += acc[i][j][r] * adv[j];
      }
#pragma unroll
      for (int o = 1; o < 16; o <<= 1) {
        s += __shfl_xor(s, o);
        d += __shfl_xor(d, o);
      }
      ps[i][r] = s;
      pd[i][r] = d;
    }
  float* sred = (float*)&As[0];  // reuse LDS (post-loop barrier already done)
  if (wn == 64 && lr == 0) {
#pragma unroll
    for (int i = 0; i < 4; i++)
#pragma unroll
      for (int r = 0; r < 4; r++) {
        int rl = wm + i * 16 + lq * 4 + r;
        sred[rl * 2] = ps[i][r];
        sred[rl * 2 + 1] = pd[i][r];
      }
  }
  __syncthreads();
  if (wn == 0 && lr == 0) {
    int hsel = n0 >> 7;
#pragma unroll
    for (int i = 0; i < 4; i++)
#pragma unroll
      for (int r = 0; r < 4; r++) {
        int rl = wm + i * 16 + lq * 4 + r;
        int row = m0 + rl;
        a_src_out[(size_t)row * astride + hsel] = ps[i][r] + sred[rl * 2];
        a_dst_out[(size_t)row * astride + hsel] = pd[i][r] + sred[rl * 2 + 1];
      }
  }
}

// ---------------------- CSR build -------------------------------------------
__global__ __launch_bounds__(256) void hist_kernel(const int* __restrict__ dst,
                                                   int* __restrict__ deg, int E) {
  int t = blockIdx.x * 256 + threadIdx.x;
  if (t < E) atomicAdd(&deg[dst[t]], 1);
}

// parallel exclusive scan of (deg[i]+1): scan_a per-block, scan_c adds block
// offsets (computed inline from raw block sums — no separate scan_b pass)
__global__ __launch_bounds__(256) void scan_a(const int* __restrict__ deg,
                                              int* __restrict__ rowptr,
                                              int* __restrict__ bsum, int n) {
  __shared__ int sh[256];
  int b = blockIdx.x, t = threadIdx.x;
  int i = b * 256 + t;
  int v = (i < n) ? deg[i] + 1 : 0;
  sh[t] = v;
  __syncthreads();
  int x = v;
  for (int o = 1; o < 256; o <<= 1) {
    int y = (t >= o) ? sh[t - o] : 0;
    __syncthreads();
    x += y;
    sh[t] = x;
    __syncthreads();
  }
  if (i < n) rowptr[i] = x - v;  // exclusive within block
  if (t == 255) bsum[b] = x;     // raw block total
}

__global__ __launch_bounds__(256) void scan_c(int* __restrict__ rowptr,
                                              const int* __restrict__ bsum,
                                              int n, int total) {
  int b = blockIdx.x;
  int off = 0;
  for (int j = 0; j < b; j++) off += bsum[j];  // uniform scalar loads
  int i = b * 256 + threadIdx.x;
  if (i < n) rowptr[i] += off;
  else if (i == n) rowptr[n] = total;
}

__global__ __launch_bounds__(256) void fill_kernel(
    const int* __restrict__ src, const int* __restrict__ dst,
    const int* __restrict__ rowptr, int* __restrict__ cnt,
    int* __restrict__ csr_src, int E, int n) {
  int t = blockIdx.x * 256 + threadIdx.x;
  if (t < E) {
    int d = dst[t];
    int pos = rowptr[d] + atomicAdd(&cnt[d], 1);
    csr_src[pos] = src[t];
  } else if (t < E + n) {
    int i = t - E;
    csr_src[rowptr[i + 1] - 1] = i;  // self loop in the last slot
  }
}

// ---------------------- GAT aggregation (conv1: 4 heads x 128) --------------
__global__ __launch_bounds__(256) void gat1_agg(
    const _Float16* __restrict__ h1, const float* __restrict__ asrc,
    const float* __restrict__ adst, const int* __restrict__ rowptr,
    const int* __restrict__ csr_src, const float* __restrict__ bias,
    _Float16* __restrict__ out, int n) {
  int node = blockIdx.x * 4 + (threadIdx.x >> 6);
  if (node >= n) return;
  int l = threadIdx.x & 63;
  int hh = l >> 4;
  int li = l & 15;
  int r0 = rowptr[node];
  int deg = rowptr[node + 1] - r0;
  int cb = l * 8;

  float acc[8] = {};

  if (deg <= 64) {
    float adm = adst[node * 4 + hh];
    int s_reg[4];
    float ww[4];
    float m = -1e30f;
#pragma unroll
    for (int c = 0; c < 4; c++) {
      int k = c * 16 + li;
      int s = (k < deg) ? csr_src[r0 + k] : -1;
      s_reg[c] = s;
      float e = -1e30f;
      if (s >= 0) {
        float t = asrc[(size_t)s * 4 + hh] + adm;
        e = LEAKY(t);
      }
      ww[c] = e;
      m = fmaxf(m, e);
    }
#pragma unroll
    for (int o = 1; o < 16; o <<= 1) m = fmaxf(m, __shfl_xor(m, o));
    float sum = 0.f;
#pragma unroll
    for (int c = 0; c < 4; c++) {
      float w = (s_reg[c] >= 0) ? __expf(ww[c] - m) : 0.f;
      ww[c] = w;
      sum += w;
    }
#pragma unroll
    for (int o = 1; o < 16; o <<= 1) sum += __shfl_xor(sum, o);
    float sinv = 1.f / (sum + 1e-16f);
#pragma unroll
    for (int c = 0; c < 4; c++) ww[c] *= sinv;

#pragma unroll
    for (int c = 0; c < 4; c++) {
      int base = c * 16;
      if (base >= deg) break;
      int lim = min(16, deg - base);
      int jl = 0;
      for (; jl + 4 <= lim; jl += 4) {  // 4-wide: 4 gathers in flight
        int s0 = __shfl(s_reg[c], jl);
        int s1 = __shfl(s_reg[c], jl + 1);
        int s2 = __shfl(s_reg[c], jl + 2);
        int s3 = __shfl(s_reg[c], jl + 3);
        float w0 = __shfl(ww[c], hh * 16 + jl);
        float w1 = __shfl(ww[c], hh * 16 + jl + 1);
        float w2 = __shfl(ww[c], hh * 16 + jl + 2);
        float w3 = __shfl(ww[c], hh * 16 + jl + 3);
        const half8 hv0 = *(const half8*)(h1 + (size_t)s0 * 512 + cb);
        const half8 hv1 = *(const half8*)(h1 + (size_t)s1 * 512 + cb);
        const half8 hv2 = *(const half8*)(h1 + (size_t)s2 * 512 + cb);
        const half8 hv3 = *(const half8*)(h1 + (size_t)s3 * 512 + cb);
#pragma unroll
        for (int q = 0; q < 8; q++)
          acc[q] += w0 * (float)hv0[q] + w1 * (float)hv1[q] +
                    w2 * (float)hv2[q] + w3 * (float)hv3[q];
      }
      for (; jl < lim; jl++) {
        int s0 = __shfl(s_reg[c], jl);
        float w0 = __shfl(ww[c], hh * 16 + jl);
        const half8 hv0 = *(const half8*)(h1 + (size_t)s0 * 512 + cb);
#pragma unroll
        for (int q = 0; q < 8; q++) acc[q] += w0 * (float)hv0[q];
      }
    }
  } else {
    // fallback (deg>64, rare): 3-pass
    float4 ad4 = *(const float4*)(adst + node * 4);
    float adv[4] = {ad4.x, ad4.y, ad4.z, ad4.w};
    float m[4] = {-1e30f, -1e30f, -1e30f, -1e30f};
    for (int k = l; k < deg; k += 64) {
      int s = csr_src[r0 + k];
      float4 av = *(const float4*)(asrc + (size_t)s * 4);
      float e;
      e = LEAKY(av.x + adv[0]); m[0] = fmaxf(m[0], e);
      e = LEAKY(av.y + adv[1]); m[1] = fmaxf(m[1], e);
      e = LEAKY(av.z + adv[2]); m[2] = fmaxf(m[2], e);
      e = LEAKY(av.w + adv[3]); m[3] = fmaxf(m[3], e);
    }
    for (int o = 1; o < 64; o <<= 1) {
#pragma unroll
      for (int h = 0; h < 4; h++) m[h] = fmaxf(m[h], __shfl_xor(m[h], o));
    }
    float sum[4] = {0.f, 0.f, 0.f, 0.f};
    for (int k = l; k < deg; k += 64) {
      int s = csr_src[r0 + k];
      float4 av = *(const float4*)(asrc + (size_t)s * 4);
      float e;
      e = LEAKY(av.x + adv[0]); sum[0] += __expf(e - m[0]);
      e = LEAKY(av.y + adv[1]); sum[1] += __expf(e - m[1]);
      e = LEAKY(av.z + adv[2]); sum[2] += __expf(e - m[2]);
      e = LEAKY(av.w + adv[3]); sum[3] += __expf(e - m[3]);
    }
    for (int o = 1; o < 64; o <<= 1) {
#pragma unroll
      for (int h = 0; h < 4; h++) sum[h] += __shfl_xor(sum[h], o);
    }
    float mm = m[hh];
    float sinv = 1.f / (sum[hh] + 1e-16f);
    float adm = adv[hh];
    for (int k = 0; k < deg; k++) {
      int s = csr_src[r0 + k];
      float a = asrc[(size_t)s * 4 + hh];
      float e = LEAKY(a + adm);
      float w = __expf(e - mm) * sinv;
      const half8 hv = *(const half8*)(h1 + (size_t)s * 512 + cb);
#pragma unroll
      for (int q = 0; q < 8; q++) acc[q] += w * (float)hv[q];
    }
  }

  const float* bp = bias + cb;
  half8 ov;
#pragma unroll
  for (int j = 0; j < 8; j++) {
    float r = acc[j] + bp[j];
    ov[j] = (_Float16)(r > 0.f ? r : (__expf(r) - 1.f));  // ELU
  }
  *(half8*)(out + (size_t)node * 512 + cb) = ov;
}

// ---------------------- GAT aggregation (conv2: 1 head x 128) ---------------
// Wave per node. Gather: lane group g4=l>>4 = edge subgroup (4 edges in
// flight), lane handles channels (l&15)*8..+8 via 16B half8 loads; 2-shfl
// cross-group reduce at the end. Output fp16.
__global__ __launch_bounds__(256) void gat2_agg(
    const _Float16* __restrict__ h2, const float* __restrict__ asrc,
    const float* __restrict__ adst, const int* __restrict__ rowptr,
    const int* __restrict__ csr_src, const float* __restrict__ bias,
    _Float16* __restrict__ out, int n) {
  int node = blockIdx.x * 4 + (threadIdx.x >> 6);
  if (node >= n) return;
  int l = threadIdx.x & 63;
  int r0 = rowptr[node];
  int deg = rowptr[node + 1] - r0;

  if (deg <= 64) {
    float ad = adst[node];
    int s = (l < deg) ? csr_src[r0 + l] : -1;
    float e = -1e30f;
    if (s >= 0) {
      float t = asrc[s] + ad;
      e = LEAKY(t);
    }
    float m = e;
    for (int o = 1; o < 64; o <<= 1) m = fmaxf(m, __shfl_xor(m, o));
    float w = (s >= 0) ? __expf(e - m) : 0.f;
    float sum = w;
    for (int o = 1; o < 64; o <<= 1) sum += __shfl_xor(sum, o);
    w *= 1.f / (sum + 1e-16f);

    int g4 = l >> 4;
    int ch = (l & 15) * 8;
    float acc[8] = {};
    for (int j = 0; j < deg; j += 4) {
      int je = j + g4;
      int jc = min(je, 63);
      int sj = __shfl(s, jc);
      float wj = (je < deg) ? __shfl(w, jc) : 0.f;
      if (sj < 0) sj = 0;  // masked lane: harmless load, wj==0
      const half8 hv = *(const half8*)(h2 + (size_t)sj * 128 + ch);
#pragma unroll
      for (int q = 0; q < 8; q++) acc[q] += wj * (float)hv[q];
    }
    // combine the 4 edge subgroups (lanes l, l^16, l^32, l^48)
#pragma unroll
    for (int q = 0; q < 8; q++) {
      acc[q] += __shfl_xor(acc[q], 16);
      acc[q] += __shfl_xor(acc[q], 32);
    }
    if (l < 16) {
      half8 ov;
#pragma unroll
      for (int q = 0; q < 8; q++) {
        float r = acc[q] + bias[ch + q];
        ov[q] = (_Float16)(r > 0.f ? r : (__expf(r) - 1.f));  // ELU
      }
      *(half8*)(out + (size_t)node * 128 + ch) = ov;
    }
  } else {
    float ad = adst[node];
    float m = -1e30f;
    for (int k = l; k < deg; k += 64) {
      int s = csr_src[r0 + k];
      float e = LEAKY(asrc[s] + ad);
      m = fmaxf(m, e);
    }
    for (int o = 1; o < 64; o <<= 1) m = fmaxf(m, __shfl_xor(m, o));
    float sum = 0.f;
    for (int k = l; k < deg; k += 64) {
      int s = csr_src[r0 + k];
      float e = LEAKY(asrc[s] + ad);
      sum += __expf(e - m);
    }
    for (int o = 1; o < 64; o <<= 1) sum += __shfl_xor(sum, o);
    float sinv = 1.f / (sum + 1e-16f);
    int cb = l * 2;
    float a0 = 0.f, a1 = 0.f;
    for (int k = 0; k < deg; k++) {
      int s = csr_src[r0 + k];
      float e = LEAKY(asrc[s] + ad);
      float w = __expf(e - m) * sinv;
      const _Float16* hp = h2 + (size_t)s * 128 + cb;
      a0 += w * (float)hp[0];
      a1 += w * (float)hp[1];
    }
    float ra = a0 + bias[cb];
    float rb = a1 + bias[cb + 1];
    out[(size_t)node * 128 + cb]     = (_Float16)(ra > 0.f ? ra : (__expf(ra) - 1.f));
    out[(size_t)node * 128 + cb + 1] = (_Float16)(rb > 0.f ? rb : (__expf(rb) - 1.f));
  }
}

// ---------------------- per-graph max pool (2-stage) ------------------------
__device__ inline int lower_bound_i(const int* a, int n, int v) {
  int lo = 0, hi = n;
  while (lo < hi) {
    int mid = (lo + hi) >> 1;
    if (a[mid] < v) lo = mid + 1; else hi = mid;
  }
  return lo;
}

__global__ __launch_bounds__(128) void pool_partial(
    const _Float16* __restrict__ x2, const int* __restrict__ batch,
    float* __restrict__ partial, int n) {
  int g = blockIdx.y;
  int j = blockIdx.x;
  int t = threadIdx.x;
  int start = lower_bound_i(batch, n, g);
  int end = lower_bound_i(batch, n, g + 1);
  int len = end - start;
  int c0 = start + (int)((long long)len * j / POOL_CH);
  int c1 = start + (int)((long long)len * (j + 1) / POOL_CH);
  float m = -FLT_MAX;
  for (int i = c0; i < c1; i++) m = fmaxf(m, (float)x2[(size_t)i * 128 + t]);
  partial[((size_t)g * POOL_CH + j) * 128 + t] = m;
}

__global__ __launch_bounds__(128) void pool_final(
    const float* __restrict__ partial, float* __restrict__ pool) {
  int g = blockIdx.x;
  int t = threadIdx.x;
  float m = -FLT_MAX;
#pragma unroll
  for (int j = 0; j < POOL_CH; j++)
    m = fmaxf(m, partial[((size_t)g * POOL_CH + j) * 128 + t]);
  pool[g * 128 + t] = m;
}

// ---------------------- classifier ------------------------------------------
__global__ __launch_bounds__(64) void classifier_kernel(
    const float* __restrict__ pool, const float* __restrict__ Wc1,
    const float* __restrict__ bc1, const float* __restrict__ Wc2,
    const float* __restrict__ bc2, float* __restrict__ out) {
  int g = blockIdx.x;
  int t = threadIdx.x;
  __shared__ float xp[128];
  __shared__ float hc[64];
  xp[t] = pool[g * 128 + t];
  xp[t + 64] = pool[g * 128 + 64 + t];
  __syncthreads();
  float s = bc1[t];
  for (int k = 0; k < 128; k++) s += xp[k] * Wc1[k * 64 + t];
  hc[t] = s > 0.f ? s : 0.f;
  __syncthreads();
  if (t < 5) {
    float o = bc2[t];
    for (int j = 0; j < 64; j++) o += hc[j] * Wc2[j * 5 + t];
    out[g * 5 + t] = o;
  }
}

// ---------------------------------------------------------------------------
extern "C" void kernel_launch(void* const* d_in, const int* in_sizes, int n_in,
                              void* d_out, int out_size, void* d_ws, size_t ws_size,
                              hipStream_t stream) {
  const float* x_scalar = (const float*)d_in[0];
  const int* x_opcode = (const int*)d_in[1];
  const int* x_source = (const int*)d_in[2];
  const int* x_sink = (const int*)d_in[3];
  const int* x_string = (const int*)d_in[4];
  const int* x_payload = (const int*)d_in[5];
  const int* edge_index = (const int*)d_in[6];
  const int* batch = (const int*)d_in[7];
  const float* emb_opcode = (const float*)d_in[8];
  const float* emb_source = (const float*)d_in[9];
  const float* emb_sink = (const float*)d_in[10];
  const float* emb_string = (const float*)d_in[11];
  const float* emb_payload = (const float*)d_in[12];
  const float* ln_g = (const float*)d_in[13];
  const float* ln_b = (const float*)d_in[14];
  const float* W1 = (const float*)d_in[15];
  const float* att_src1 = (const float*)d_in[16];
  const float* att_dst1 = (const float*)d_in[17];
  const float* b1 = (const float*)d_in[18];
  const float* W2 = (const float*)d_in[19];
  const float* att_src2 = (const float*)d_in[20];
  const float* att_dst2 = (const float*)d_in[21];
  const float* b2 = (const float*)d_in[22];
  const float* Wc1 = (const float*)d_in[23];
  const float* bc1 = (const float*)d_in[24];
  const float* Wc2 = (const float*)d_in[25];
  const float* bc2 = (const float*)d_in[26];
  float* out = (float*)d_out;

  const int N = in_sizes[0] / 96;
  const int E = in_sizes[6] / 2;
  const int G = out_size / 5;
  const int Npad = (N + 127) / 128 * 128;  // GEMM row padding

  const int* e_src = edge_index;
  const int* e_dst = edge_index + E;

  // ---- workspace layout with aliasing (lifetime-checked; ws ~171.6 MB) ----
  char* w = (char*)d_ws;
  size_t o = 0;
  auto take = [&](size_t bytes) -> void* {
    void* p = w + o;
    o += (bytes + 255) & ~(size_t)255;
    return p;
  };
  char* regionA = (char*)take((size_t)Npad * 256 * 2);
  char* regionB = (char*)take((size_t)Npad * 512 * 2);
  _Float16* x1 = (_Float16*)take((size_t)Npad * 512 * 2);
  _Float16* Wt1 = (_Float16*)take((size_t)512 * 256 * 2);
  _Float16* Wt2 = (_Float16*)take((size_t)128 * 512 * 2);
  float* a_src1 = (float*)take((size_t)Npad * 4 * 4);
  float* a_dst1 = (float*)take((size_t)Npad * 4 * 4);
  float* a_src2 = (float*)take((size_t)Npad * 4);
  float* a_dst2 = (float*)take((size_t)Npad * 4);
  int* deg = (int*)take((size_t)N * 2 * 4);  // deg + cnt contiguous
  int* cnt = deg + N;
  int* rowptr = (int*)take((size_t)(N + 1) * 4);
  int* csr_src = (int*)take((size_t)(E + N) * 4);
  int* bsum = (int*)take(256 * 4);
  // total ~133.3 MB < ws_size (bracketed by R3 pass / R4 fail)

  _Float16* feats = (_Float16*)regionA;
  _Float16* h2 = (_Float16*)regionA;  // feats dead after gemm1
  float* partial = (float*)(regionA + (((size_t)Npad * 128 * 2 + 255) & ~(size_t)255));
  float* pool = partial + (size_t)G * POOL_CH * 128;
  _Float16* h1 = (_Float16*)regionB;
  _Float16* x2 = (_Float16*)regionB;  // h1 dead after gat1_agg (fp16 now)

  hipMemsetAsync(deg, 0, (size_t)N * 2 * 4, stream);

  // CSR build (independent of features)
  hist_kernel<<<(E + 255) / 256, 256, 0, stream>>>(e_dst, deg, E);
  int nb = (N + 255) / 256;
  scan_a<<<nb, 256, 0, stream>>>(deg, rowptr, bsum, N);
  scan_c<<<(N + 256) / 256, 256, 0, stream>>>(rowptr, bsum, N, E + N);
  fill_kernel<<<(E + N + 255) / 256, 256, 0, stream>>>(e_src, e_dst, rowptr, cnt,
                                                       csr_src, E, N);

  // weights -> transposed fp16 (one launch for both)
  transpose_both_f16<<<(256 * 512 + 512 * 128 + 255) / 256, 256, 0, stream>>>(
      W1, Wt1, W2, Wt2);

  // features + LN (fp16 out), wave-per-node
  feats_kernel<<<(N + 3) / 4, 256, 0, stream>>>(
      x_scalar, x_opcode, x_source, x_sink, x_string, x_payload, emb_opcode,
      emb_source, emb_sink, emb_string, emb_payload, ln_g, ln_b, feats, N);

  int mblocks = Npad / 128;
  // conv1: h1 = feats @ W1 (K=256, N=512) + fused a_src1/a_dst1 (4 heads)
  gemm_f16_att<<<dim3(512 / 128, mblocks), 256, 0, stream>>>(
      feats, Wt1, h1, att_src1, att_dst1, a_src1, a_dst1, 4, 256, 512);
  gat1_agg<<<(N + 3) / 4, 256, 0, stream>>>(h1, a_src1, a_dst1, rowptr, csr_src,
                                            b1, x1, N);

  // conv2: h2 = x1 @ W2 (K=512, N=128) + fused a_src2/a_dst2 (1 head)
  gemm_f16_att<<<dim3(128 / 128, mblocks), 256, 0, stream>>>(
      x1, Wt2, h2, att_src2, att_dst2, a_src2, a_dst2, 1, 512, 128);
  gat2_agg<<<(N + 3) / 4, 256, 0, stream>>>(h2, a_src2, a_dst2, rowptr, csr_src,
                                            b2, x2, N);

  // pool (2-stage, fp16 in) + classifier
  pool_partial<<<dim3(POOL_CH, G), 128, 0, stream>>>(x2, batch, partial, N);
  pool_final<<<G, 128, 0, stream>>>(partial, pool);
  classifier_kernel<<<G, 64, 0, stream>>>(pool, Wc1, bc1, Wc2, bc2, out);
}